// Round 1
// baseline (611.601 us; speedup 1.0000x reference)
//
#include <hip/hip_runtime.h>
#include <hip/hip_bf16.h>
#include <cstdint>
#include <cstddef>

// TwoLayerGAT on MI355X — round 1: correct f32 baseline.
// Structure: one-time graph prep (deg, loop_attr, CSR by dst), then per layer:
//   GEMM (xh = X@W, f32 tiled), a_s/a_d reductions, Ve fold (We x att_e),
//   per-edge alpha (leaky_relu, written in CSR order), per-node softmax+aggregate.

#define HH 8
#define CC 128
#define EDD 32

// ---------------- graph prep ----------------

__global__ void deg_count_kernel(const int* __restrict__ ei, int* __restrict__ deg, int E) {
  int e = blockIdx.x * 256 + threadIdx.x;
  if (e < E) atomicAdd(&deg[ei[E + e]], 1);
}

__global__ void loop_accum_kernel(const int* __restrict__ ei, const float* __restrict__ edge_attr,
                                  float* __restrict__ loop_sum, int E) {
  int gid = blockIdx.x * 256 + threadIdx.x;
  if (gid >= E * EDD) return;
  int e = gid >> 5, d = gid & 31;
  atomicAdd(&loop_sum[(size_t)ei[E + e] * EDD + d], edge_attr[gid]);
}

__global__ void scan_kernel(const int* __restrict__ deg, int* __restrict__ rowptr,
                            int* __restrict__ cursor, int n) {
  __shared__ int sm[1024];
  __shared__ int carry_sm;
  int t = threadIdx.x;
  if (t == 0) carry_sm = 0;
  __syncthreads();
  for (int base = 0; base < n; base += 1024) {
    int i = base + t;
    int v = (i < n) ? deg[i] : 0;
    sm[t] = v;
    __syncthreads();
    for (int off = 1; off < 1024; off <<= 1) {
      int add = (t >= off) ? sm[t - off] : 0;
      __syncthreads();
      sm[t] += add;
      __syncthreads();
    }
    int excl = sm[t] - v + carry_sm;
    if (i < n) { rowptr[i] = excl; cursor[i] = excl; }
    __syncthreads();
    if (t == 0) carry_sm += sm[1023];
    __syncthreads();
  }
  if (t == 0) rowptr[n] = carry_sm;
}

__global__ void scatter_kernel(const int* __restrict__ ei, int* __restrict__ cursor,
                               int* __restrict__ csr_src, int* __restrict__ inv_pos, int E) {
  int e = blockIdx.x * 256 + threadIdx.x;
  if (e >= E) return;
  int d = ei[E + e];
  int pos = atomicAdd(&cursor[d], 1);
  csr_src[pos] = ei[e];
  inv_pos[e] = pos;
}

__global__ void loop_div_kernel(float* __restrict__ loop_attr, const int* __restrict__ deg, int n) {
  int gid = blockIdx.x * 256 + threadIdx.x;
  if (gid >= n * EDD) return;
  int node = gid >> 5;
  float dv = fmaxf((float)deg[node], 1.f);
  loop_attr[gid] = loop_attr[gid] / dv;
}

// ---------------- GEMM: C[M,1024] = A[M,K] @ B[K,1024], f32 ----------------

__global__ __launch_bounds__(256) void gemm_f32_kernel(const float* __restrict__ A,
    const float* __restrict__ B, float* __restrict__ C, int M, int K) {
  const int N = 1024;
  __shared__ float As[32][68];
  __shared__ float Bs[32][64];
  int tid = threadIdx.x;
  int tx = tid & 15;
  int ty = tid >> 4;
  int m0 = blockIdx.y * 64;
  int n0 = blockIdx.x * 64;
  float acc[4][4] = {};
  for (int k0 = 0; k0 < K; k0 += 32) {
#pragma unroll
    for (int p = 0; p < 2; ++p) {
      int ar = (tid >> 3) + p * 32;
      int ak = (tid & 7) * 4;
      int gm = m0 + ar; if (gm >= M) gm = M - 1;
      const float4 v = *(const float4*)&A[(size_t)gm * K + k0 + ak];
      As[ak + 0][ar] = v.x; As[ak + 1][ar] = v.y; As[ak + 2][ar] = v.z; As[ak + 3][ar] = v.w;
    }
#pragma unroll
    for (int p = 0; p < 2; ++p) {
      int br = (tid >> 4) + p * 16;
      int bc = (tid & 15) * 4;
      *(float4*)&Bs[br][bc] = *(const float4*)&B[(size_t)(k0 + br) * N + n0 + bc];
    }
    __syncthreads();
#pragma unroll
    for (int k = 0; k < 32; ++k) {
      float a[4], b[4];
      *(float4*)a = *(const float4*)&As[k][ty * 4];
      *(float4*)b = *(const float4*)&Bs[k][tx * 4];
#pragma unroll
      for (int i = 0; i < 4; ++i)
#pragma unroll
        for (int j = 0; j < 4; ++j)
          acc[i][j] = fmaf(a[i], b[j], acc[i][j]);
    }
    __syncthreads();
  }
#pragma unroll
  for (int i = 0; i < 4; ++i) {
    int gm = m0 + ty * 4 + i;
    if (gm < M) {
      float4 v = make_float4(acc[i][0], acc[i][1], acc[i][2], acc[i][3]);
      *(float4*)&C[(size_t)gm * N + n0 + tx * 4] = v;
    }
  }
}

// ---------------- attention scalars ----------------

__global__ __launch_bounds__(256) void asad_kernel(const float* __restrict__ xh,
    const float* __restrict__ att_s, const float* __restrict__ att_d,
    float* __restrict__ a_s, float* __restrict__ a_d) {
  int n = blockIdx.x, t = threadIdx.x;
  float4 v = ((const float4*)xh)[(size_t)n * 256 + t];
  float4 s4 = ((const float4*)att_s)[t];
  float4 d4 = ((const float4*)att_d)[t];
  float ps = v.x * s4.x + v.y * s4.y + v.z * s4.z + v.w * s4.w;
  float pd = v.x * d4.x + v.y * d4.y + v.z * d4.z + v.w * d4.w;
#pragma unroll
  for (int mask = 1; mask <= 16; mask <<= 1) {
    ps += __shfl_xor(ps, mask);
    pd += __shfl_xor(pd, mask);
  }
  if ((t & 31) == 0) {
    int h = t >> 5;
    a_s[(size_t)n * 8 + h] = ps;
    a_d[(size_t)n * 8 + h] = pd;
  }
}

// Ve[d*8+h] = sum_c We[d][h*128+c] * att_e[h][c]
__global__ void ve_kernel(const float* __restrict__ We, const float* __restrict__ att_e,
                          float* __restrict__ Ve) {
  int t = threadIdx.x;  // 256
  int d = t >> 3, h = t & 7;
  float s = 0.f;
  for (int c = 0; c < CC; ++c) s = fmaf(We[d * 1024 + h * CC + c], att_e[h * CC + c], s);
  Ve[t] = s;
}

__global__ __launch_bounds__(256) void edge_alpha_kernel(const int* __restrict__ ei,
    const float* __restrict__ edge_attr, const float* __restrict__ loop_attr,
    const float* __restrict__ a_s, const float* __restrict__ a_d,
    const float* __restrict__ Ve, const int* __restrict__ inv_pos,
    float* __restrict__ alpha_csr, float* __restrict__ alpha_self, int E, int n) {
  __shared__ float sVe[EDD][8];
  int t = threadIdx.x;
  sVe[t >> 3][t & 7] = Ve[t];
  __syncthreads();
  int e = blockIdx.x * 256 + t;
  if (e >= E + n) return;
  int s, d;
  const float* ea;
  float* outp;
  if (e < E) {
    s = ei[e]; d = ei[E + e];
    ea = edge_attr + (size_t)e * EDD;
    outp = alpha_csr + (size_t)inv_pos[e] * 8;
  } else {
    s = d = e - E;
    ea = loop_attr + (size_t)(e - E) * EDD;
    outp = alpha_self + (size_t)(e - E) * 8;
  }
  float ae[8] = {0.f, 0.f, 0.f, 0.f, 0.f, 0.f, 0.f, 0.f};
#pragma unroll
  for (int k = 0; k < EDD; k += 4) {
    float4 v = *(const float4*)&ea[k];
#pragma unroll
    for (int h = 0; h < 8; ++h) {
      ae[h] = fmaf(v.x, sVe[k][h], ae[h]);
      ae[h] = fmaf(v.y, sVe[k + 1][h], ae[h]);
      ae[h] = fmaf(v.z, sVe[k + 2][h], ae[h]);
      ae[h] = fmaf(v.w, sVe[k + 3][h], ae[h]);
    }
  }
#pragma unroll
  for (int h = 0; h < 8; ++h) {
    float a = a_s[(size_t)s * 8 + h] + a_d[(size_t)d * 8 + h] + ae[h];
    outp[h] = (a > 0.f) ? a : 0.2f * a;
  }
}

// ---------------- per-node softmax + aggregate ----------------
// LAYER==1: out[n,1024] = relu(agg + b1); LAYER==2: out[n,128] = mean_h(agg) + b2

template <int LAYER>
__global__ __launch_bounds__(256) void aggregate_kernel(const float* __restrict__ xh,
    const float* __restrict__ alpha_csr, const float* __restrict__ alpha_self,
    const int* __restrict__ rowptr, const int* __restrict__ csr_src,
    const float* __restrict__ bias, float* __restrict__ outp) {
  int n = blockIdx.x;
  int t = threadIdx.x;
  __shared__ float sm_m[8], sm_s[8];
  __shared__ int ls[64];
  __shared__ float pw[64][8];
  __shared__ float red[256][4];
  int row0 = rowptr[n];
  int deg = rowptr[n + 1] - row0;
  if (t < 64) {  // wave 0: online softmax stats, 8 slots per head
    int h = t & 7, slot = t >> 3;
    float m = -1e30f, s = 0.f;
    for (int i = slot; i < deg; i += 8) {
      float a = alpha_csr[(size_t)(row0 + i) * 8 + h];
      if (a <= m) {
        s += __expf(a - m);
      } else {
        s = s * __expf(m - a) + 1.f;
        m = a;
      }
    }
#pragma unroll
    for (int mask = 8; mask < 64; mask <<= 1) {
      float mo = __shfl_xor(m, mask);
      float so = __shfl_xor(s, mask);
      float mn = fmaxf(m, mo);
      s = s * __expf(m - mn) + so * __expf(mo - mn);
      m = mn;
    }
    if (t < 8) {
      float aself = alpha_self[(size_t)n * 8 + h];
      float mn = fmaxf(m, aself);
      s = s * __expf(m - mn) + __expf(aself - mn);
      sm_m[h] = mn;
      sm_s[h] = s + 1e-16f;
    }
  }
  __syncthreads();
  int h_t = t >> 5;
  float m_h = sm_m[h_t];
  float inv_s = 1.f / sm_s[h_t];
  const float4* xh4 = (const float4*)xh;
  float pself = __expf(alpha_self[(size_t)n * 8 + h_t] - m_h);
  float4 v = xh4[(size_t)n * 256 + t];
  float ax = pself * v.x, ay = pself * v.y, az = pself * v.z, aw = pself * v.w;
  for (int base = 0; base < deg; base += 64) {
    int cnt = min(64, deg - base);
    if (t < cnt) ls[t] = csr_src[row0 + base + t];
    for (int idx = t; idx < cnt * 8; idx += 256) {
      int j = idx >> 3, h = idx & 7;
      pw[j][h] = __expf(alpha_csr[(size_t)(row0 + base + j) * 8 + h] - sm_m[h]);
    }
    __syncthreads();
#pragma unroll 4
    for (int j = 0; j < cnt; ++j) {
      float w = pw[j][h_t];
      float4 u = xh4[(size_t)ls[j] * 256 + t];
      ax = fmaf(w, u.x, ax); ay = fmaf(w, u.y, ay);
      az = fmaf(w, u.z, az); aw = fmaf(w, u.w, aw);
    }
    __syncthreads();
  }
  ax *= inv_s; ay *= inv_s; az *= inv_s; aw *= inv_s;
  if (LAYER == 1) {
    float4 b = ((const float4*)bias)[t];
    float4 o;
    o.x = fmaxf(ax + b.x, 0.f);
    o.y = fmaxf(ay + b.y, 0.f);
    o.z = fmaxf(az + b.z, 0.f);
    o.w = fmaxf(aw + b.w, 0.f);
    ((float4*)outp)[(size_t)n * 256 + t] = o;
  } else {
    red[t][0] = ax; red[t][1] = ay; red[t][2] = az; red[t][3] = aw;
    __syncthreads();
    if (t < 32) {
      float sx = 0.f, sy = 0.f, sz = 0.f, sw = 0.f;
#pragma unroll
      for (int h = 0; h < 8; ++h) {
        sx += red[t + 32 * h][0];
        sy += red[t + 32 * h][1];
        sz += red[t + 32 * h][2];
        sw += red[t + 32 * h][3];
      }
      float4 b = ((const float4*)bias)[t];
      float4 o;
      o.x = sx * 0.125f + b.x;
      o.y = sy * 0.125f + b.y;
      o.z = sz * 0.125f + b.z;
      o.w = sw * 0.125f + b.w;
      ((float4*)outp)[(size_t)n * 32 + t] = o;
    }
  }
}

// ---------------- launch ----------------

extern "C" void kernel_launch(void* const* d_in, const int* in_sizes, int n_in,
                              void* d_out, int out_size, void* d_ws, size_t ws_size,
                              hipStream_t stream) {
  const float* x        = (const float*)d_in[0];
  const int*   ei       = (const int*)d_in[1];
  const float* edge_attr= (const float*)d_in[2];
  const float* W1       = (const float*)d_in[3];
  const float* We1      = (const float*)d_in[4];
  const float* as1      = (const float*)d_in[5];
  const float* ad1      = (const float*)d_in[6];
  const float* ae1      = (const float*)d_in[7];
  const float* b1       = (const float*)d_in[8];
  const float* W2       = (const float*)d_in[9];
  const float* We2      = (const float*)d_in[10];
  const float* as2      = (const float*)d_in[11];
  const float* ad2      = (const float*)d_in[12];
  const float* ae2      = (const float*)d_in[13];
  const float* b2       = (const float*)d_in[14];
  float* out = (float*)d_out;

  const int N = in_sizes[0] / 128;   // 10000 nodes
  const int E = in_sizes[2] / EDD;   // 160000 edges

  char* ws = (char*)d_ws;
  size_t off = 0;
  auto alloc = [&](size_t bytes) -> void* {
    void* p = ws + off;
    off = (off + bytes + 255) & ~(size_t)255;
    return p;
  };
  int*   deg       = (int*)alloc((size_t)N * 4);
  int*   rowptr    = (int*)alloc((size_t)(N + 1) * 4);
  int*   cursor    = (int*)alloc((size_t)N * 4);
  int*   csr_src   = (int*)alloc((size_t)E * 4);
  int*   inv_pos   = (int*)alloc((size_t)E * 4);
  float* loop_attr = (float*)alloc((size_t)N * EDD * 4);
  float* a_s       = (float*)alloc((size_t)N * 8 * 4);
  float* a_d       = (float*)alloc((size_t)N * 8 * 4);
  float* Ve        = (float*)alloc(256 * 4);
  float* alpha_csr = (float*)alloc((size_t)E * 8 * 4);
  float* alpha_self= (float*)alloc((size_t)N * 8 * 4);
  float* xh        = (float*)alloc((size_t)N * 1024 * 4);
  float* h1        = (float*)alloc((size_t)N * 1024 * 4);
  (void)ws_size; (void)n_in; (void)out_size;

  hipMemsetAsync(deg, 0, (size_t)N * 4, stream);
  hipMemsetAsync(loop_attr, 0, (size_t)N * EDD * 4, stream);

  int gE = (E + 255) / 256;
  deg_count_kernel<<<gE, 256, 0, stream>>>(ei, deg, E);
  loop_accum_kernel<<<(E * EDD + 255) / 256, 256, 0, stream>>>(ei, edge_attr, loop_attr, E);
  scan_kernel<<<1, 1024, 0, stream>>>(deg, rowptr, cursor, N);
  scatter_kernel<<<gE, 256, 0, stream>>>(ei, cursor, csr_src, inv_pos, E);
  loop_div_kernel<<<(N * EDD + 255) / 256, 256, 0, stream>>>(loop_attr, deg, N);

  dim3 ggrid(16, (N + 63) / 64);
  int gEA = (E + N + 255) / 256;

  // ---- layer 1 ----
  gemm_f32_kernel<<<ggrid, 256, 0, stream>>>(x, W1, xh, N, 128);
  asad_kernel<<<N, 256, 0, stream>>>(xh, as1, ad1, a_s, a_d);
  ve_kernel<<<1, 256, 0, stream>>>(We1, ae1, Ve);
  edge_alpha_kernel<<<gEA, 256, 0, stream>>>(ei, edge_attr, loop_attr, a_s, a_d, Ve,
                                             inv_pos, alpha_csr, alpha_self, E, N);
  aggregate_kernel<1><<<N, 256, 0, stream>>>(xh, alpha_csr, alpha_self, rowptr, csr_src, b1, h1);

  // ---- layer 2 ----
  gemm_f32_kernel<<<ggrid, 256, 0, stream>>>(h1, W2, xh, N, 1024);
  asad_kernel<<<N, 256, 0, stream>>>(xh, as2, ad2, a_s, a_d);
  ve_kernel<<<1, 256, 0, stream>>>(We2, ae2, Ve);
  edge_alpha_kernel<<<gEA, 256, 0, stream>>>(ei, edge_attr, loop_attr, a_s, a_d, Ve,
                                             inv_pos, alpha_csr, alpha_self, E, N);
  aggregate_kernel<2><<<N, 256, 0, stream>>>(xh, alpha_csr, alpha_self, rowptr, csr_src, b2, out);
}

// Round 2
// 607.480 us; speedup vs baseline: 1.0068x; 1.0068x over previous
//
#include <hip/hip_runtime.h>
#include <hip/hip_bf16.h>
#include <cstdint>
#include <cstddef>

// TwoLayerGAT on MI355X — round 2: split-bf16 MFMA GEMM (hi/lo, 3 products).
// C = Ahi*Bhi + Ahi*Blo + Alo*Bhi  -> ~2^-16 relative error, runs on matrix pipe.

#define EDD 32

typedef __attribute__((ext_vector_type(4))) float f32x4;
typedef __attribute__((ext_vector_type(8))) short bf16x8;

__device__ inline unsigned short f2bf_rn(float f) {
  uint32_t u = __float_as_uint(f);
  return (unsigned short)((u + 0x7FFFu + ((u >> 16) & 1u)) >> 16);
}

__device__ inline void split2(float x, unsigned short& h, unsigned short& l) {
  uint32_t u = __float_as_uint(x);
  h = (unsigned short)(u >> 16);                       // truncated hi
  float r = x - __uint_as_float(u & 0xFFFF0000u);      // exact residual
  l = f2bf_rn(r);
}

// ---------------- graph prep ----------------

__global__ void deg_count_kernel(const int* __restrict__ ei, int* __restrict__ deg, int E) {
  int e = blockIdx.x * 256 + threadIdx.x;
  if (e < E) atomicAdd(&deg[ei[E + e]], 1);
}

__global__ void loop_accum_kernel(const int* __restrict__ ei, const float* __restrict__ edge_attr,
                                  float* __restrict__ loop_sum, int E) {
  int gid = blockIdx.x * 256 + threadIdx.x;
  if (gid >= E * EDD) return;
  int e = gid >> 5, d = gid & 31;
  atomicAdd(&loop_sum[(size_t)ei[E + e] * EDD + d], edge_attr[gid]);
}

__global__ void scan_kernel(const int* __restrict__ deg, int* __restrict__ rowptr,
                            int* __restrict__ cursor, int n) {
  __shared__ int sm[1024];
  __shared__ int carry_sm;
  int t = threadIdx.x;
  if (t == 0) carry_sm = 0;
  __syncthreads();
  for (int base = 0; base < n; base += 1024) {
    int i = base + t;
    int v = (i < n) ? deg[i] : 0;
    sm[t] = v;
    __syncthreads();
    for (int off = 1; off < 1024; off <<= 1) {
      int add = (t >= off) ? sm[t - off] : 0;
      __syncthreads();
      sm[t] += add;
      __syncthreads();
    }
    int excl = sm[t] - v + carry_sm;
    if (i < n) { rowptr[i] = excl; cursor[i] = excl; }
    __syncthreads();
    if (t == 0) carry_sm += sm[1023];
    __syncthreads();
  }
  if (t == 0) rowptr[n] = carry_sm;
}

__global__ void scatter_kernel(const int* __restrict__ ei, int* __restrict__ cursor,
                               int* __restrict__ csr_src, int* __restrict__ inv_pos, int E) {
  int e = blockIdx.x * 256 + threadIdx.x;
  if (e >= E) return;
  int d = ei[E + e];
  int pos = atomicAdd(&cursor[d], 1);
  csr_src[pos] = ei[e];
  inv_pos[e] = pos;
}

__global__ void loop_div_kernel(float* __restrict__ loop_attr, const int* __restrict__ deg, int n) {
  int gid = blockIdx.x * 256 + threadIdx.x;
  if (gid >= n * EDD) return;
  int node = gid >> 5;
  float dv = fmaxf((float)deg[node], 1.f);
  loop_attr[gid] = loop_attr[gid] / dv;
}

// ---------------- conversions ----------------

// split f32 array -> bf16 hi/lo, 4 elements per thread
__global__ void split_f32_kernel(const float* __restrict__ in, unsigned short* __restrict__ hi,
                                 unsigned short* __restrict__ lo, int n4) {
  int i = blockIdx.x * 256 + threadIdx.x;
  if (i >= n4) return;
  float4 v = ((const float4*)in)[i];
  ushort4 h, l;
  split2(v.x, h.x, l.x); split2(v.y, h.y, l.y);
  split2(v.z, h.z, l.z); split2(v.w, h.w, l.w);
  ((ushort4*)hi)[i] = h;
  ((ushort4*)lo)[i] = l;
}

// W [K][1024] f32 -> Bt_hi/lo [1024][K] bf16 (transposed, K-contiguous)
__global__ void split_transpose_kernel(const float* __restrict__ W,
                                       unsigned short* __restrict__ Bthi,
                                       unsigned short* __restrict__ Btlo, int K) {
  __shared__ float tile[32][33];
  int bn = blockIdx.x * 32;  // n
  int bk = blockIdx.y * 32;  // k
  int tx = threadIdx.x & 31, ty = threadIdx.x >> 5;  // 32 x 8
  for (int r = ty; r < 32; r += 8)
    tile[r][tx] = W[(size_t)(bk + r) * 1024 + bn + tx];
  __syncthreads();
  for (int r = ty; r < 32; r += 8) {
    float v = tile[tx][r];  // = W[bk+tx][bn+r] -> Bt[bn+r][bk+tx]
    unsigned short h, l;
    split2(v, h, l);
    Bthi[(size_t)(bn + r) * K + bk + tx] = h;
    Btlo[(size_t)(bn + r) * K + bk + tx] = l;
  }
}

// ---------------- MFMA GEMM: C[M,1024] = A[M,K] @ B[K,1024] via split bf16 ----
// A as hi/lo [Mpad][K] bf16 (K-contig), B as hi/lo [1024][K] bf16 (K-contig = B^T)

__global__ __launch_bounds__(256) void gemm_mfma_split_kernel(
    const unsigned short* __restrict__ Ahi, const unsigned short* __restrict__ Alo,
    const unsigned short* __restrict__ Bthi, const unsigned short* __restrict__ Btlo,
    float* __restrict__ C, int M, int K) {
  __shared__ __align__(16) unsigned short As_hi[128 * 32];
  __shared__ __align__(16) unsigned short As_lo[128 * 32];
  __shared__ __align__(16) unsigned short Bs_hi[128 * 32];
  __shared__ __align__(16) unsigned short Bs_lo[128 * 32];
  const int t = threadIdx.x;
  const int lane = t & 63;
  const int wid = t >> 6;
  const int wr = wid >> 1, wc = wid & 1;
  const int m0 = blockIdx.y * 128;
  const int n0 = blockIdx.x * 128;

  f32x4 acc[4][4] = {};

  for (int k0 = 0; k0 < K; k0 += 32) {
    uint4 ra[2], la[2], rb[2], lb[2];
#pragma unroll
    for (int p = 0; p < 2; ++p) {
      int idx = p * 256 + t;
      int row = idx >> 2, g = idx & 3;
      size_t ga = (size_t)(m0 + row) * K + k0 + g * 8;
      size_t gb = (size_t)(n0 + row) * K + k0 + g * 8;
      ra[p] = *(const uint4*)(Ahi + ga);
      la[p] = *(const uint4*)(Alo + ga);
      rb[p] = *(const uint4*)(Bthi + gb);
      lb[p] = *(const uint4*)(Btlo + gb);
    }
    __syncthreads();  // all waves done reading LDS from previous step
#pragma unroll
    for (int p = 0; p < 2; ++p) {
      int idx = p * 256 + t;
      int row = idx >> 2, g = idx & 3;
      int off = row * 32 + ((g ^ ((row >> 1) & 3)) * 8);  // XOR swizzle
      *(uint4*)(As_hi + off) = ra[p];
      *(uint4*)(As_lo + off) = la[p];
      *(uint4*)(Bs_hi + off) = rb[p];
      *(uint4*)(Bs_lo + off) = lb[p];
    }
    __syncthreads();  // staged tile visible
    bf16x8 ah[4], al[4], bh[4], bl[4];
#pragma unroll
    for (int i = 0; i < 4; ++i) {
      int rowa = wr * 64 + i * 16 + (lane & 15);
      int offa = rowa * 32 + ((((lane >> 4) ^ ((rowa >> 1) & 3))) * 8);
      ah[i] = *(const bf16x8*)(As_hi + offa);
      al[i] = *(const bf16x8*)(As_lo + offa);
      int rowb = wc * 64 + i * 16 + (lane & 15);
      int offb = rowb * 32 + ((((lane >> 4) ^ ((rowb >> 1) & 3))) * 8);
      bh[i] = *(const bf16x8*)(Bs_hi + offb);
      bl[i] = *(const bf16x8*)(Bs_lo + offb);
    }
#pragma unroll
    for (int i = 0; i < 4; ++i)
#pragma unroll
      for (int j = 0; j < 4; ++j) {
        acc[i][j] = __builtin_amdgcn_mfma_f32_16x16x32_bf16(ah[i], bh[j], acc[i][j], 0, 0, 0);
        acc[i][j] = __builtin_amdgcn_mfma_f32_16x16x32_bf16(ah[i], bl[j], acc[i][j], 0, 0, 0);
        acc[i][j] = __builtin_amdgcn_mfma_f32_16x16x32_bf16(al[i], bh[j], acc[i][j], 0, 0, 0);
      }
  }
#pragma unroll
  for (int i = 0; i < 4; ++i)
#pragma unroll
    for (int j = 0; j < 4; ++j)
#pragma unroll
      for (int r = 0; r < 4; ++r) {
        int m = m0 + wr * 64 + i * 16 + (lane >> 4) * 4 + r;
        int n = n0 + wc * 64 + j * 16 + (lane & 15);
        if (m < M) C[(size_t)m * 1024 + n] = acc[i][j][r];
      }
}

// ---------------- attention scalars ----------------

__global__ __launch_bounds__(256) void asad_kernel(const float* __restrict__ xh,
    const float* __restrict__ att_s, const float* __restrict__ att_d,
    float* __restrict__ a_s, float* __restrict__ a_d) {
  int n = blockIdx.x, t = threadIdx.x;
  float4 v = ((const float4*)xh)[(size_t)n * 256 + t];
  float4 s4 = ((const float4*)att_s)[t];
  float4 d4 = ((const float4*)att_d)[t];
  float ps = v.x * s4.x + v.y * s4.y + v.z * s4.z + v.w * s4.w;
  float pd = v.x * d4.x + v.y * d4.y + v.z * d4.z + v.w * d4.w;
#pragma unroll
  for (int mask = 1; mask <= 16; mask <<= 1) {
    ps += __shfl_xor(ps, mask);
    pd += __shfl_xor(pd, mask);
  }
  if ((t & 31) == 0) {
    int h = t >> 5;
    a_s[(size_t)n * 8 + h] = ps;
    a_d[(size_t)n * 8 + h] = pd;
  }
}

__global__ void ve_kernel(const float* __restrict__ We, const float* __restrict__ att_e,
                          float* __restrict__ Ve) {
  int t = threadIdx.x;  // 256
  int d = t >> 3, h = t & 7;
  float s = 0.f;
  for (int c = 0; c < 128; ++c) s = fmaf(We[d * 1024 + h * 128 + c], att_e[h * 128 + c], s);
  Ve[t] = s;
}

__global__ __launch_bounds__(256) void edge_alpha_kernel(const int* __restrict__ ei,
    const float* __restrict__ edge_attr, const float* __restrict__ loop_attr,
    const float* __restrict__ a_s, const float* __restrict__ a_d,
    const float* __restrict__ Ve, const int* __restrict__ inv_pos,
    float* __restrict__ alpha_csr, float* __restrict__ alpha_self, int E, int n) {
  __shared__ float sVe[EDD][8];
  int t = threadIdx.x;
  sVe[t >> 3][t & 7] = Ve[t];
  __syncthreads();
  int e = blockIdx.x * 256 + t;
  if (e >= E + n) return;
  int s, d;
  const float* ea;
  float* outp;
  if (e < E) {
    s = ei[e]; d = ei[E + e];
    ea = edge_attr + (size_t)e * EDD;
    outp = alpha_csr + (size_t)inv_pos[e] * 8;
  } else {
    s = d = e - E;
    ea = loop_attr + (size_t)(e - E) * EDD;
    outp = alpha_self + (size_t)(e - E) * 8;
  }
  float ae[8] = {0.f, 0.f, 0.f, 0.f, 0.f, 0.f, 0.f, 0.f};
#pragma unroll
  for (int k = 0; k < EDD; k += 4) {
    float4 v = *(const float4*)&ea[k];
#pragma unroll
    for (int h = 0; h < 8; ++h) {
      ae[h] = fmaf(v.x, sVe[k][h], ae[h]);
      ae[h] = fmaf(v.y, sVe[k + 1][h], ae[h]);
      ae[h] = fmaf(v.z, sVe[k + 2][h], ae[h]);
      ae[h] = fmaf(v.w, sVe[k + 3][h], ae[h]);
    }
  }
#pragma unroll
  for (int h = 0; h < 8; ++h) {
    float a = a_s[(size_t)s * 8 + h] + a_d[(size_t)d * 8 + h] + ae[h];
    outp[h] = (a > 0.f) ? a : 0.2f * a;
  }
}

// ---------------- per-node softmax + aggregate ----------------
// LAYER==1: writes relu(agg+b1) split to bf16 hi/lo (feeds GEMM2)
// LAYER==2: writes mean_h(agg)+b2 to f32 out

template <int LAYER>
__global__ __launch_bounds__(256) void aggregate_kernel(const float* __restrict__ xh,
    const float* __restrict__ alpha_csr, const float* __restrict__ alpha_self,
    const int* __restrict__ rowptr, const int* __restrict__ csr_src,
    const float* __restrict__ bias, float* __restrict__ outp,
    unsigned short* __restrict__ ohi, unsigned short* __restrict__ olo) {
  int n = blockIdx.x;
  int t = threadIdx.x;
  __shared__ float sm_m[8], sm_s[8];
  __shared__ int ls[64];
  __shared__ float pw[64][8];
  __shared__ float red[256][4];
  int row0 = rowptr[n];
  int deg = rowptr[n + 1] - row0;
  if (t < 64) {  // wave 0: online softmax stats, 8 slots per head
    int h = t & 7, slot = t >> 3;
    float m = -1e30f, s = 0.f;
    for (int i = slot; i < deg; i += 8) {
      float a = alpha_csr[(size_t)(row0 + i) * 8 + h];
      if (a <= m) {
        s += __expf(a - m);
      } else {
        s = s * __expf(m - a) + 1.f;
        m = a;
      }
    }
#pragma unroll
    for (int mask = 8; mask < 64; mask <<= 1) {
      float mo = __shfl_xor(m, mask);
      float so = __shfl_xor(s, mask);
      float mn = fmaxf(m, mo);
      s = s * __expf(m - mn) + so * __expf(mo - mn);
      m = mn;
    }
    if (t < 8) {
      float aself = alpha_self[(size_t)n * 8 + h];
      float mn = fmaxf(m, aself);
      s = s * __expf(m - mn) + __expf(aself - mn);
      sm_m[h] = mn;
      sm_s[h] = s + 1e-16f;
    }
  }
  __syncthreads();
  int h_t = t >> 5;
  float m_h = sm_m[h_t];
  float inv_s = 1.f / sm_s[h_t];
  const float4* xh4 = (const float4*)xh;
  float pself = __expf(alpha_self[(size_t)n * 8 + h_t] - m_h);
  float4 v = xh4[(size_t)n * 256 + t];
  float ax = pself * v.x, ay = pself * v.y, az = pself * v.z, aw = pself * v.w;
  for (int base = 0; base < deg; base += 64) {
    int cnt = min(64, deg - base);
    if (t < cnt) ls[t] = csr_src[row0 + base + t];
    for (int idx = t; idx < cnt * 8; idx += 256) {
      int j = idx >> 3, h = idx & 7;
      pw[j][h] = __expf(alpha_csr[(size_t)(row0 + base + j) * 8 + h] - sm_m[h]);
    }
    __syncthreads();
#pragma unroll 4
    for (int j = 0; j < cnt; ++j) {
      float w = pw[j][h_t];
      float4 u = xh4[(size_t)ls[j] * 256 + t];
      ax = fmaf(w, u.x, ax); ay = fmaf(w, u.y, ay);
      az = fmaf(w, u.z, az); aw = fmaf(w, u.w, aw);
    }
    __syncthreads();
  }
  ax *= inv_s; ay *= inv_s; az *= inv_s; aw *= inv_s;
  if (LAYER == 1) {
    float4 b = ((const float4*)bias)[t];
    float ox = fmaxf(ax + b.x, 0.f);
    float oy = fmaxf(ay + b.y, 0.f);
    float oz = fmaxf(az + b.z, 0.f);
    float ow = fmaxf(aw + b.w, 0.f);
    ushort4 h4, l4;
    split2(ox, h4.x, l4.x); split2(oy, h4.y, l4.y);
    split2(oz, h4.z, l4.z); split2(ow, h4.w, l4.w);
    ((ushort4*)ohi)[(size_t)n * 256 + t] = h4;
    ((ushort4*)olo)[(size_t)n * 256 + t] = l4;
  } else {
    red[t][0] = ax; red[t][1] = ay; red[t][2] = az; red[t][3] = aw;
    __syncthreads();
    if (t < 32) {
      float sx = 0.f, sy = 0.f, sz = 0.f, sw = 0.f;
#pragma unroll
      for (int h = 0; h < 8; ++h) {
        sx += red[t + 32 * h][0];
        sy += red[t + 32 * h][1];
        sz += red[t + 32 * h][2];
        sw += red[t + 32 * h][3];
      }
      float4 b = ((const float4*)bias)[t];
      float4 o;
      o.x = sx * 0.125f + b.x;
      o.y = sy * 0.125f + b.y;
      o.z = sz * 0.125f + b.z;
      o.w = sw * 0.125f + b.w;
      ((float4*)outp)[(size_t)n * 32 + t] = o;
    }
  }
}

// ---------------- launch ----------------

extern "C" void kernel_launch(void* const* d_in, const int* in_sizes, int n_in,
                              void* d_out, int out_size, void* d_ws, size_t ws_size,
                              hipStream_t stream) {
  const float* x        = (const float*)d_in[0];
  const int*   ei       = (const int*)d_in[1];
  const float* edge_attr= (const float*)d_in[2];
  const float* W1       = (const float*)d_in[3];
  const float* We1      = (const float*)d_in[4];
  const float* as1      = (const float*)d_in[5];
  const float* ad1      = (const float*)d_in[6];
  const float* ae1      = (const float*)d_in[7];
  const float* b1       = (const float*)d_in[8];
  const float* W2       = (const float*)d_in[9];
  const float* We2      = (const float*)d_in[10];
  const float* as2      = (const float*)d_in[11];
  const float* ad2      = (const float*)d_in[12];
  const float* ae2      = (const float*)d_in[13];
  const float* b2       = (const float*)d_in[14];
  float* out = (float*)d_out;

  const int N = in_sizes[0] / 128;   // 10000 nodes
  const int E = in_sizes[2] / EDD;   // 160000 edges
  const int Mpad = ((N + 127) / 128) * 128;  // 10112

  char* ws = (char*)d_ws;
  size_t off = 0;
  auto alloc = [&](size_t bytes) -> void* {
    void* p = ws + off;
    off = (off + bytes + 255) & ~(size_t)255;
    return p;
  };
  int*   deg       = (int*)alloc((size_t)N * 4);
  int*   rowptr    = (int*)alloc((size_t)(N + 1) * 4);
  int*   cursor    = (int*)alloc((size_t)N * 4);
  int*   csr_src   = (int*)alloc((size_t)E * 4);
  int*   inv_pos   = (int*)alloc((size_t)E * 4);
  float* loop_attr = (float*)alloc((size_t)N * EDD * 4);
  float* a_s       = (float*)alloc((size_t)N * 8 * 4);
  float* a_d       = (float*)alloc((size_t)N * 8 * 4);
  float* Ve        = (float*)alloc(256 * 4);
  float* alpha_csr = (float*)alloc((size_t)E * 8 * 4);
  float* alpha_self= (float*)alloc((size_t)N * 8 * 4);
  float* xh        = (float*)alloc((size_t)N * 1024 * 4);          // GEMM out (both layers)
  unsigned short* xhi   = (unsigned short*)alloc((size_t)Mpad * 128 * 2);
  unsigned short* xlo   = (unsigned short*)alloc((size_t)Mpad * 128 * 2);
  unsigned short* Bt1hi = (unsigned short*)alloc((size_t)1024 * 128 * 2);
  unsigned short* Bt1lo = (unsigned short*)alloc((size_t)1024 * 128 * 2);
  unsigned short* Bt2hi = (unsigned short*)alloc((size_t)1024 * 1024 * 2);
  unsigned short* Bt2lo = (unsigned short*)alloc((size_t)1024 * 1024 * 2);
  unsigned short* h1hi  = (unsigned short*)alloc((size_t)Mpad * 1024 * 2);
  unsigned short* h1lo  = (unsigned short*)alloc((size_t)Mpad * 1024 * 2);
  (void)ws_size; (void)n_in; (void)out_size;

  hipMemsetAsync(deg, 0, (size_t)N * 4, stream);
  hipMemsetAsync(loop_attr, 0, (size_t)N * EDD * 4, stream);

  int gE = (E + 255) / 256;
  deg_count_kernel<<<gE, 256, 0, stream>>>(ei, deg, E);
  loop_accum_kernel<<<(E * EDD + 255) / 256, 256, 0, stream>>>(ei, edge_attr, loop_attr, E);
  scan_kernel<<<1, 1024, 0, stream>>>(deg, rowptr, cursor, N);
  scatter_kernel<<<gE, 256, 0, stream>>>(ei, cursor, csr_src, inv_pos, E);
  loop_div_kernel<<<(N * EDD + 255) / 256, 256, 0, stream>>>(loop_attr, deg, N);

  // conversions
  split_f32_kernel<<<(N * 128 / 4 + 255) / 256, 256, 0, stream>>>(x, xhi, xlo, N * 128 / 4);
  split_transpose_kernel<<<dim3(32, 4), 256, 0, stream>>>(W1, Bt1hi, Bt1lo, 128);
  split_transpose_kernel<<<dim3(32, 32), 256, 0, stream>>>(W2, Bt2hi, Bt2lo, 1024);

  dim3 ggrid(8, (N + 127) / 128);
  int gEA = (E + N + 255) / 256;

  // ---- layer 1 ----
  gemm_mfma_split_kernel<<<ggrid, 256, 0, stream>>>(xhi, xlo, Bt1hi, Bt1lo, xh, N, 128);
  asad_kernel<<<N, 256, 0, stream>>>(xh, as1, ad1, a_s, a_d);
  ve_kernel<<<1, 256, 0, stream>>>(We1, ae1, Ve);
  edge_alpha_kernel<<<gEA, 256, 0, stream>>>(ei, edge_attr, loop_attr, a_s, a_d, Ve,
                                             inv_pos, alpha_csr, alpha_self, E, N);
  aggregate_kernel<1><<<N, 256, 0, stream>>>(xh, alpha_csr, alpha_self, rowptr, csr_src,
                                             b1, nullptr, h1hi, h1lo);

  // ---- layer 2 ----
  gemm_mfma_split_kernel<<<ggrid, 256, 0, stream>>>(h1hi, h1lo, Bt2hi, Bt2lo, xh, N, 1024);
  asad_kernel<<<N, 256, 0, stream>>>(xh, as2, ad2, a_s, a_d);
  ve_kernel<<<1, 256, 0, stream>>>(We2, ae2, Ve);
  edge_alpha_kernel<<<gEA, 256, 0, stream>>>(ei, edge_attr, loop_attr, a_s, a_d, Ve,
                                             inv_pos, alpha_csr, alpha_self, E, N);
  aggregate_kernel<2><<<N, 256, 0, stream>>>(xh, alpha_csr, alpha_self, rowptr, csr_src,
                                             b2, out, nullptr, nullptr);
}

// Round 3
// 403.105 us; speedup vs baseline: 1.5172x; 1.5070x over previous
//
#include <hip/hip_runtime.h>
#include <hip/hip_bf16.h>
#include <cstdint>
#include <cstddef>

// TwoLayerGAT on MI355X — round 3:
//  - MFMA split-bf16 GEMM restructured to m97 pattern: global_load_lds staging
//    (no staging VGPRs -> no scratch spills), single-buffer LDS, swizzle moved
//    to the global source address (LDS dest stays linear).
//  - loop_accum atomics replaced by CSR gather (csr_eid).
//  - fast single-block scan.

#define EDD 32

typedef __attribute__((ext_vector_type(4))) float f32x4;
typedef __attribute__((ext_vector_type(8))) short bf16x8;

__device__ inline unsigned short f2bf_rn(float f) {
  uint32_t u = __float_as_uint(f);
  return (unsigned short)((u + 0x7FFFu + ((u >> 16) & 1u)) >> 16);
}

__device__ inline void split2(float x, unsigned short& h, unsigned short& l) {
  uint32_t u = __float_as_uint(x);
  h = (unsigned short)(u >> 16);                       // truncated hi
  float r = x - __uint_as_float(u & 0xFFFF0000u);      // exact residual
  l = f2bf_rn(r);
}

__device__ inline void gload_lds16(const void* g, void* l) {
  __builtin_amdgcn_global_load_lds((const __attribute__((address_space(1))) void*)g,
                                   (__attribute__((address_space(3))) void*)l, 16, 0, 0);
}

// ---------------- graph prep ----------------

__global__ void deg_count_kernel(const int* __restrict__ ei, int* __restrict__ deg, int E) {
  int e = blockIdx.x * 256 + threadIdx.x;
  if (e < E) atomicAdd(&deg[ei[E + e]], 1);
}

// single block, 1024 threads: exclusive scan of deg -> rowptr, cursor
__global__ void scan_kernel(const int* __restrict__ deg, int* __restrict__ rowptr,
                            int* __restrict__ cursor, int n) {
  __shared__ int wsum[16];
  int t = threadIdx.x;
  int chunk = (n + 1023) >> 10;
  int lo = min(t * chunk, n), hi = min(lo + chunk, n);
  int s = 0;
  for (int i = lo; i < hi; ++i) s += deg[i];
  int lane = t & 63, w = t >> 6;
  int v = s;
#pragma unroll
  for (int off = 1; off < 64; off <<= 1) {
    int u = __shfl_up(v, off);
    if (lane >= off) v += u;
  }
  if (lane == 63) wsum[w] = v;
  __syncthreads();
  if (t == 0) {
    int acc = 0;
#pragma unroll
    for (int i = 0; i < 16; ++i) { int x = wsum[i]; wsum[i] = acc; acc += x; }
  }
  __syncthreads();
  int excl = v - s + wsum[w];
  for (int i = lo; i < hi; ++i) {
    rowptr[i] = excl; cursor[i] = excl; excl += deg[i];
  }
  if (t == 1023) rowptr[n] = excl;
}

__global__ void scatter_kernel(const int* __restrict__ ei, int* __restrict__ cursor,
                               int* __restrict__ csr_src, int* __restrict__ csr_dst,
                               int* __restrict__ csr_eid, int E) {
  int e = blockIdx.x * 256 + threadIdx.x;
  if (e >= E) return;
  int d = ei[E + e];
  int pos = atomicAdd(&cursor[d], 1);
  csr_src[pos] = ei[e];
  csr_dst[pos] = d;
  csr_eid[pos] = e;
}

// loop_attr[n][d] = mean over incoming edges of edge_attr (CSR gather, no atomics)
__global__ void loop_attr_kernel(const int* __restrict__ rowptr, const int* __restrict__ csr_eid,
                                 const float* __restrict__ edge_attr,
                                 float* __restrict__ loop_attr, int N) {
  int n = blockIdx.x * 8 + (threadIdx.x >> 5);
  int lane = threadIdx.x & 31;
  if (n >= N) return;
  int r0 = rowptr[n], r1 = rowptr[n + 1];
  float s = 0.f;
  for (int p = r0; p < r1; ++p)
    s += edge_attr[(size_t)csr_eid[p] * EDD + lane];
  float dv = fmaxf((float)(r1 - r0), 1.f);
  loop_attr[(size_t)n * EDD + lane] = s / dv;
}

// ---------------- conversions ----------------

__global__ void split_f32_kernel(const float* __restrict__ in, unsigned short* __restrict__ hi,
                                 unsigned short* __restrict__ lo, int n4) {
  int i = blockIdx.x * 256 + threadIdx.x;
  if (i >= n4) return;
  float4 v = ((const float4*)in)[i];
  ushort4 h, l;
  split2(v.x, h.x, l.x); split2(v.y, h.y, l.y);
  split2(v.z, h.z, l.z); split2(v.w, h.w, l.w);
  ((ushort4*)hi)[i] = h;
  ((ushort4*)lo)[i] = l;
}

// W [K][1024] f32 -> Bt_hi/lo [1024][K] bf16 (transposed, K-contiguous)
__global__ void split_transpose_kernel(const float* __restrict__ W,
                                       unsigned short* __restrict__ Bthi,
                                       unsigned short* __restrict__ Btlo, int K) {
  __shared__ float tile[32][33];
  int bn = blockIdx.x * 32;
  int bk = blockIdx.y * 32;
  int tx = threadIdx.x & 31, ty = threadIdx.x >> 5;
  for (int r = ty; r < 32; r += 8)
    tile[r][tx] = W[(size_t)(bk + r) * 1024 + bn + tx];
  __syncthreads();
  for (int r = ty; r < 32; r += 8) {
    float v = tile[tx][r];
    unsigned short h, l;
    split2(v, h, l);
    Bthi[(size_t)(bn + r) * K + bk + tx] = h;
    Btlo[(size_t)(bn + r) * K + bk + tx] = l;
  }
}

// ---------------- MFMA GEMM (m97 structure): C[M,1024] = A @ B ----------------
// A hi/lo [Mpad][K] bf16 K-contig; B hi/lo [1024][K] bf16 K-contig (= B^T).
// 128x128 tile, 4 waves (2x2), BK=32. global_load_lds staging, LDS linear,
// swizzle applied on the GLOBAL source (involution g ^= (row>>1)&3) and on reads.

__global__ __launch_bounds__(256) void gemm_mfma_split_kernel(
    const unsigned short* __restrict__ Ahi, const unsigned short* __restrict__ Alo,
    const unsigned short* __restrict__ Bthi, const unsigned short* __restrict__ Btlo,
    float* __restrict__ C, int M, int K) {
  __shared__ __align__(16) unsigned short lds[4 * 128 * 32];
  unsigned short* As_hi = lds;
  unsigned short* As_lo = lds + 4096;
  unsigned short* Bs_hi = lds + 8192;
  unsigned short* Bs_lo = lds + 12288;
  const int t = threadIdx.x;
  const int lane = t & 63;
  const int wid = t >> 6;
  const int wr = wid >> 1, wc = wid & 1;
  const int m0 = blockIdx.y * 128;
  const int n0 = blockIdx.x * 128;

  // staging geometry: wave wid covers rows [wid*32, wid*32+32) of the 128-row tile
  const int srow = lane >> 2;     // 0..15
  const int sg = lane & 3;        // 16B group 0..3

  f32x4 acc[4][4] = {};

  for (int k0 = 0; k0 < K; k0 += 32) {
    __syncthreads();  // all waves done reading previous tile
#pragma unroll
    for (int q = 0; q < 2; ++q) {
      int rb = wid * 32 + q * 16;
      int row = rb + srow;
      int gsrc = sg ^ ((row >> 1) & 3);  // pre-swizzled global source
      size_t ga = (size_t)(m0 + row) * K + k0 + gsrc * 8;
      size_t gb = (size_t)(n0 + row) * K + k0 + gsrc * 8;
      gload_lds16(Ahi + ga, As_hi + rb * 32);
      gload_lds16(Alo + ga, As_lo + rb * 32);
      gload_lds16(Bthi + gb, Bs_hi + rb * 32);
      gload_lds16(Btlo + gb, Bs_lo + rb * 32);
    }
    __syncthreads();  // compiler drains vmcnt before barrier -> tile visible

    bf16x8 ah[4], al[4];
#pragma unroll
    for (int i = 0; i < 4; ++i) {
      int rowa = wr * 64 + i * 16 + (lane & 15);
      int offa = rowa * 32 + ((((lane >> 4) ^ ((rowa >> 1) & 3))) * 8);
      ah[i] = *(const bf16x8*)(As_hi + offa);
      al[i] = *(const bf16x8*)(As_lo + offa);
    }
#pragma unroll
    for (int j = 0; j < 4; ++j) {
      int rowb = wc * 64 + j * 16 + (lane & 15);
      int offb = rowb * 32 + ((((lane >> 4) ^ ((rowb >> 1) & 3))) * 8);
      bf16x8 bh = *(const bf16x8*)(Bs_hi + offb);
      bf16x8 bl = *(const bf16x8*)(Bs_lo + offb);
#pragma unroll
      for (int i = 0; i < 4; ++i) {
        acc[i][j] = __builtin_amdgcn_mfma_f32_16x16x32_bf16(ah[i], bh, acc[i][j], 0, 0, 0);
        acc[i][j] = __builtin_amdgcn_mfma_f32_16x16x32_bf16(ah[i], bl, acc[i][j], 0, 0, 0);
        acc[i][j] = __builtin_amdgcn_mfma_f32_16x16x32_bf16(al[i], bh, acc[i][j], 0, 0, 0);
      }
    }
  }
#pragma unroll
  for (int i = 0; i < 4; ++i)
#pragma unroll
    for (int j = 0; j < 4; ++j)
#pragma unroll
      for (int r = 0; r < 4; ++r) {
        int m = m0 + wr * 64 + i * 16 + (lane >> 4) * 4 + r;
        int n = n0 + wc * 64 + j * 16 + (lane & 15);
        if (m < M) C[(size_t)m * 1024 + n] = acc[i][j][r];
      }
}

// ---------------- attention scalars ----------------

__global__ __launch_bounds__(256) void asad_kernel(const float* __restrict__ xh,
    const float* __restrict__ att_s, const float* __restrict__ att_d,
    float* __restrict__ a_s, float* __restrict__ a_d) {
  int n = blockIdx.x, t = threadIdx.x;
  float4 v = ((const float4*)xh)[(size_t)n * 256 + t];
  float4 s4 = ((const float4*)att_s)[t];
  float4 d4 = ((const float4*)att_d)[t];
  float ps = v.x * s4.x + v.y * s4.y + v.z * s4.z + v.w * s4.w;
  float pd = v.x * d4.x + v.y * d4.y + v.z * d4.z + v.w * d4.w;
#pragma unroll
  for (int mask = 1; mask <= 16; mask <<= 1) {
    ps += __shfl_xor(ps, mask);
    pd += __shfl_xor(pd, mask);
  }
  if ((t & 31) == 0) {
    int h = t >> 5;
    a_s[(size_t)n * 8 + h] = ps;
    a_d[(size_t)n * 8 + h] = pd;
  }
}

__global__ void ve_kernel(const float* __restrict__ We, const float* __restrict__ att_e,
                          float* __restrict__ Ve) {
  int t = threadIdx.x;  // 256
  int d = t >> 3, h = t & 7;
  float s = 0.f;
  for (int c = 0; c < 128; ++c) s = fmaf(We[d * 1024 + h * 128 + c], att_e[h * 128 + c], s);
  Ve[t] = s;
}

// alpha in CSR position order (coalesced writes); self-loop alphas separate.
__global__ __launch_bounds__(256) void edge_alpha_kernel(
    const int* __restrict__ csr_src, const int* __restrict__ csr_dst,
    const int* __restrict__ csr_eid,
    const float* __restrict__ edge_attr, const float* __restrict__ loop_attr,
    const float* __restrict__ a_s, const float* __restrict__ a_d,
    const float* __restrict__ Ve,
    float* __restrict__ alpha_csr, float* __restrict__ alpha_self, int E, int n) {
  __shared__ float sVe[EDD][8];
  int t = threadIdx.x;
  sVe[t >> 3][t & 7] = Ve[t];
  __syncthreads();
  int idx = blockIdx.x * 256 + t;
  if (idx >= E + n) return;
  int s, d;
  const float* ea;
  float* outp;
  if (idx < E) {
    s = csr_src[idx]; d = csr_dst[idx];
    ea = edge_attr + (size_t)csr_eid[idx] * EDD;
    outp = alpha_csr + (size_t)idx * 8;
  } else {
    s = d = idx - E;
    ea = loop_attr + (size_t)(idx - E) * EDD;
    outp = alpha_self + (size_t)(idx - E) * 8;
  }
  float ae[8] = {0.f, 0.f, 0.f, 0.f, 0.f, 0.f, 0.f, 0.f};
#pragma unroll
  for (int k = 0; k < EDD; k += 4) {
    float4 v = *(const float4*)&ea[k];
#pragma unroll
    for (int h = 0; h < 8; ++h) {
      ae[h] = fmaf(v.x, sVe[k][h], ae[h]);
      ae[h] = fmaf(v.y, sVe[k + 1][h], ae[h]);
      ae[h] = fmaf(v.z, sVe[k + 2][h], ae[h]);
      ae[h] = fmaf(v.w, sVe[k + 3][h], ae[h]);
    }
  }
#pragma unroll
  for (int h = 0; h < 8; ++h) {
    float a = a_s[(size_t)s * 8 + h] + a_d[(size_t)d * 8 + h] + ae[h];
    outp[h] = (a > 0.f) ? a : 0.2f * a;
  }
}

// ---------------- per-node softmax + aggregate ----------------
// LAYER==1: writes relu(agg+b1) split to bf16 hi/lo (feeds GEMM2)
// LAYER==2: writes mean_h(agg)+b2 to f32 out

template <int LAYER>
__global__ __launch_bounds__(256) void aggregate_kernel(const float* __restrict__ xh,
    const float* __restrict__ alpha_csr, const float* __restrict__ alpha_self,
    const int* __restrict__ rowptr, const int* __restrict__ csr_src,
    const float* __restrict__ bias, float* __restrict__ outp,
    unsigned short* __restrict__ ohi, unsigned short* __restrict__ olo) {
  int n = blockIdx.x;
  int t = threadIdx.x;
  __shared__ float sm_m[8], sm_s[8];
  __shared__ int ls[64];
  __shared__ float pw[64][8];
  __shared__ float red[256][4];
  int row0 = rowptr[n];
  int deg = rowptr[n + 1] - row0;
  if (t < 64) {  // wave 0: online softmax stats, 8 slots per head
    int h = t & 7, slot = t >> 3;
    float m = -1e30f, s = 0.f;
    for (int i = slot; i < deg; i += 8) {
      float a = alpha_csr[(size_t)(row0 + i) * 8 + h];
      if (a <= m) {
        s += __expf(a - m);
      } else {
        s = s * __expf(m - a) + 1.f;
        m = a;
      }
    }
#pragma unroll
    for (int mask = 8; mask < 64; mask <<= 1) {
      float mo = __shfl_xor(m, mask);
      float so = __shfl_xor(s, mask);
      float mn = fmaxf(m, mo);
      s = s * __expf(m - mn) + so * __expf(mo - mn);
      m = mn;
    }
    if (t < 8) {
      float aself = alpha_self[(size_t)n * 8 + h];
      float mn = fmaxf(m, aself);
      s = s * __expf(m - mn) + __expf(aself - mn);
      sm_m[h] = mn;
      sm_s[h] = s + 1e-16f;
    }
  }
  __syncthreads();
  int h_t = t >> 5;
  float m_h = sm_m[h_t];
  float inv_s = 1.f / sm_s[h_t];
  const float4* xh4 = (const float4*)xh;
  float pself = __expf(alpha_self[(size_t)n * 8 + h_t] - m_h);
  float4 v = xh4[(size_t)n * 256 + t];
  float ax = pself * v.x, ay = pself * v.y, az = pself * v.z, aw = pself * v.w;
  for (int base = 0; base < deg; base += 64) {
    int cnt = min(64, deg - base);
    if (t < cnt) ls[t] = csr_src[row0 + base + t];
    for (int idx = t; idx < cnt * 8; idx += 256) {
      int j = idx >> 3, h = idx & 7;
      pw[j][h] = __expf(alpha_csr[(size_t)(row0 + base + j) * 8 + h] - sm_m[h]);
    }
    __syncthreads();
#pragma unroll 4
    for (int j = 0; j < cnt; ++j) {
      float w = pw[j][h_t];
      float4 u = xh4[(size_t)ls[j] * 256 + t];
      ax = fmaf(w, u.x, ax); ay = fmaf(w, u.y, ay);
      az = fmaf(w, u.z, az); aw = fmaf(w, u.w, aw);
    }
    __syncthreads();
  }
  ax *= inv_s; ay *= inv_s; az *= inv_s; aw *= inv_s;
  if (LAYER == 1) {
    float4 b = ((const float4*)bias)[t];
    float ox = fmaxf(ax + b.x, 0.f);
    float oy = fmaxf(ay + b.y, 0.f);
    float oz = fmaxf(az + b.z, 0.f);
    float ow = fmaxf(aw + b.w, 0.f);
    ushort4 h4, l4;
    split2(ox, h4.x, l4.x); split2(oy, h4.y, l4.y);
    split2(oz, h4.z, l4.z); split2(ow, h4.w, l4.w);
    ((ushort4*)ohi)[(size_t)n * 256 + t] = h4;
    ((ushort4*)olo)[(size_t)n * 256 + t] = l4;
  } else {
    red[t][0] = ax; red[t][1] = ay; red[t][2] = az; red[t][3] = aw;
    __syncthreads();
    if (t < 32) {
      float sx = 0.f, sy = 0.f, sz = 0.f, sw = 0.f;
#pragma unroll
      for (int h = 0; h < 8; ++h) {
        sx += red[t + 32 * h][0];
        sy += red[t + 32 * h][1];
        sz += red[t + 32 * h][2];
        sw += red[t + 32 * h][3];
      }
      float4 b = ((const float4*)bias)[t];
      float4 o;
      o.x = sx * 0.125f + b.x;
      o.y = sy * 0.125f + b.y;
      o.z = sz * 0.125f + b.z;
      o.w = sw * 0.125f + b.w;
      ((float4*)outp)[(size_t)n * 32 + t] = o;
    }
  }
}

// ---------------- launch ----------------

extern "C" void kernel_launch(void* const* d_in, const int* in_sizes, int n_in,
                              void* d_out, int out_size, void* d_ws, size_t ws_size,
                              hipStream_t stream) {
  const float* x        = (const float*)d_in[0];
  const int*   ei       = (const int*)d_in[1];
  const float* edge_attr= (const float*)d_in[2];
  const float* W1       = (const float*)d_in[3];
  const float* We1      = (const float*)d_in[4];
  const float* as1      = (const float*)d_in[5];
  const float* ad1      = (const float*)d_in[6];
  const float* ae1      = (const float*)d_in[7];
  const float* b1       = (const float*)d_in[8];
  const float* W2       = (const float*)d_in[9];
  const float* We2      = (const float*)d_in[10];
  const float* as2      = (const float*)d_in[11];
  const float* ad2      = (const float*)d_in[12];
  const float* ae2      = (const float*)d_in[13];
  const float* b2       = (const float*)d_in[14];
  float* out = (float*)d_out;

  const int N = in_sizes[0] / 128;   // 10000 nodes
  const int E = in_sizes[2] / EDD;   // 160000 edges
  const int Mpad = ((N + 127) / 128) * 128;  // 10112

  char* ws = (char*)d_ws;
  size_t off = 0;
  auto alloc = [&](size_t bytes) -> void* {
    void* p = ws + off;
    off = (off + bytes + 255) & ~(size_t)255;
    return p;
  };
  int*   deg       = (int*)alloc((size_t)N * 4);
  int*   rowptr    = (int*)alloc((size_t)(N + 1) * 4);
  int*   cursor    = (int*)alloc((size_t)N * 4);
  int*   csr_src   = (int*)alloc((size_t)E * 4);
  int*   csr_dst   = (int*)alloc((size_t)E * 4);
  int*   csr_eid   = (int*)alloc((size_t)E * 4);
  float* loop_attr = (float*)alloc((size_t)N * EDD * 4);
  float* a_s       = (float*)alloc((size_t)N * 8 * 4);
  float* a_d       = (float*)alloc((size_t)N * 8 * 4);
  float* Ve        = (float*)alloc(256 * 4);
  float* alpha_csr = (float*)alloc((size_t)E * 8 * 4);
  float* alpha_self= (float*)alloc((size_t)N * 8 * 4);
  float* xh        = (float*)alloc((size_t)N * 1024 * 4);
  unsigned short* xhi   = (unsigned short*)alloc((size_t)Mpad * 128 * 2);
  unsigned short* xlo   = (unsigned short*)alloc((size_t)Mpad * 128 * 2);
  unsigned short* Bt1hi = (unsigned short*)alloc((size_t)1024 * 128 * 2);
  unsigned short* Bt1lo = (unsigned short*)alloc((size_t)1024 * 128 * 2);
  unsigned short* Bt2hi = (unsigned short*)alloc((size_t)1024 * 1024 * 2);
  unsigned short* Bt2lo = (unsigned short*)alloc((size_t)1024 * 1024 * 2);
  unsigned short* h1hi  = (unsigned short*)alloc((size_t)Mpad * 1024 * 2);
  unsigned short* h1lo  = (unsigned short*)alloc((size_t)Mpad * 1024 * 2);
  (void)ws_size; (void)n_in; (void)out_size;

  hipMemsetAsync(deg, 0, (size_t)N * 4, stream);

  int gE = (E + 255) / 256;
  deg_count_kernel<<<gE, 256, 0, stream>>>(ei, deg, E);
  scan_kernel<<<1, 1024, 0, stream>>>(deg, rowptr, cursor, N);
  scatter_kernel<<<gE, 256, 0, stream>>>(ei, cursor, csr_src, csr_dst, csr_eid, E);
  loop_attr_kernel<<<(N + 7) / 8, 256, 0, stream>>>(rowptr, csr_eid, edge_attr, loop_attr, N);

  // conversions
  split_f32_kernel<<<(N * 128 / 4 + 255) / 256, 256, 0, stream>>>(x, xhi, xlo, N * 128 / 4);
  split_transpose_kernel<<<dim3(32, 4), 256, 0, stream>>>(W1, Bt1hi, Bt1lo, 128);
  split_transpose_kernel<<<dim3(32, 32), 256, 0, stream>>>(W2, Bt2hi, Bt2lo, 1024);

  dim3 ggrid(8, Mpad / 128);
  int gEA = (E + N + 255) / 256;

  // ---- layer 1 ----
  gemm_mfma_split_kernel<<<ggrid, 256, 0, stream>>>(xhi, xlo, Bt1hi, Bt1lo, xh, N, 128);
  asad_kernel<<<N, 256, 0, stream>>>(xh, as1, ad1, a_s, a_d);
  ve_kernel<<<1, 256, 0, stream>>>(We1, ae1, Ve);
  edge_alpha_kernel<<<gEA, 256, 0, stream>>>(csr_src, csr_dst, csr_eid, edge_attr, loop_attr,
                                             a_s, a_d, Ve, alpha_csr, alpha_self, E, N);
  aggregate_kernel<1><<<N, 256, 0, stream>>>(xh, alpha_csr, alpha_self, rowptr, csr_src,
                                             b1, nullptr, h1hi, h1lo);

  // ---- layer 2 ----
  gemm_mfma_split_kernel<<<ggrid, 256, 0, stream>>>(h1hi, h1lo, Bt2hi, Bt2lo, xh, N, 1024);
  asad_kernel<<<N, 256, 0, stream>>>(xh, as2, ad2, a_s, a_d);
  ve_kernel<<<1, 256, 0, stream>>>(We2, ae2, Ve);
  edge_alpha_kernel<<<gEA, 256, 0, stream>>>(csr_src, csr_dst, csr_eid, edge_attr, loop_attr,
                                             a_s, a_d, Ve, alpha_csr, alpha_self, E, N);
  aggregate_kernel<2><<<N, 256, 0, stream>>>(xh, alpha_csr, alpha_self, rowptr, csr_src,
                                             b2, out, nullptr, nullptr);
}

// Round 4
// 403.074 us; speedup vs baseline: 1.5173x; 1.0001x over previous
//
#include <hip/hip_runtime.h>
#include <hip/hip_bf16.h>
#include <cstdint>
#include <cstddef>

// TwoLayerGAT on MI355X — round 4:
//  - softmax weights precomputed (in-place over alpha_csr) -> gather kernels do no stats
//  - layer-1 aggregation: one wave per (node, head), blockIdx = head + 8*group so
//    round-robin dispatch pins head h -> XCD h; per-XCD L2 working set = 5 MB slice
//  - layer-2 aggregation: bf16 gather (GEMM2 epilogue writes bf16-hi copy), halves bytes
//  - GEMM unchanged (m97-style global_load_lds, split-bf16 3-product)

#define EDD 32

typedef __attribute__((ext_vector_type(4))) float f32x4;
typedef __attribute__((ext_vector_type(8))) short bf16x8;

__device__ inline unsigned short f2bf_rn(float f) {
  uint32_t u = __float_as_uint(f);
  return (unsigned short)((u + 0x7FFFu + ((u >> 16) & 1u)) >> 16);
}

__device__ inline void split2(float x, unsigned short& h, unsigned short& l) {
  uint32_t u = __float_as_uint(x);
  h = (unsigned short)(u >> 16);                       // truncated hi
  float r = x - __uint_as_float(u & 0xFFFF0000u);      // exact residual
  l = f2bf_rn(r);
}

__device__ inline float bf2f(unsigned short b) {
  return __uint_as_float(((uint32_t)b) << 16);
}

__device__ inline void gload_lds16(const void* g, void* l) {
  __builtin_amdgcn_global_load_lds((const __attribute__((address_space(1))) void*)g,
                                   (__attribute__((address_space(3))) void*)l, 16, 0, 0);
}

// ---------------- graph prep ----------------

__global__ void deg_count_kernel(const int* __restrict__ ei, int* __restrict__ deg, int E) {
  int e = blockIdx.x * 256 + threadIdx.x;
  if (e < E) atomicAdd(&deg[ei[E + e]], 1);
}

// single block, 1024 threads: exclusive scan of deg -> rowptr, cursor
__global__ void scan_kernel(const int* __restrict__ deg, int* __restrict__ rowptr,
                            int* __restrict__ cursor, int n) {
  __shared__ int wsum[16];
  int t = threadIdx.x;
  int chunk = (n + 1023) >> 10;
  int lo = min(t * chunk, n), hi = min(lo + chunk, n);
  int s = 0;
  for (int i = lo; i < hi; ++i) s += deg[i];
  int lane = t & 63, w = t >> 6;
  int v = s;
#pragma unroll
  for (int off = 1; off < 64; off <<= 1) {
    int u = __shfl_up(v, off);
    if (lane >= off) v += u;
  }
  if (lane == 63) wsum[w] = v;
  __syncthreads();
  if (t == 0) {
    int acc = 0;
#pragma unroll
    for (int i = 0; i < 16; ++i) { int x = wsum[i]; wsum[i] = acc; acc += x; }
  }
  __syncthreads();
  int excl = v - s + wsum[w];
  for (int i = lo; i < hi; ++i) {
    rowptr[i] = excl; cursor[i] = excl; excl += deg[i];
  }
  if (t == 1023) rowptr[n] = excl;
}

__global__ void scatter_kernel(const int* __restrict__ ei, int* __restrict__ cursor,
                               int* __restrict__ csr_src, int* __restrict__ csr_dst,
                               int* __restrict__ csr_eid, int E) {
  int e = blockIdx.x * 256 + threadIdx.x;
  if (e >= E) return;
  int d = ei[E + e];
  int pos = atomicAdd(&cursor[d], 1);
  csr_src[pos] = ei[e];
  csr_dst[pos] = d;
  csr_eid[pos] = e;
}

// loop_attr[n][d] = mean over incoming edges of edge_attr (CSR gather)
__global__ void loop_attr_kernel(const int* __restrict__ rowptr, const int* __restrict__ csr_eid,
                                 const float* __restrict__ edge_attr,
                                 float* __restrict__ loop_attr, int N) {
  int n = blockIdx.x * 8 + (threadIdx.x >> 5);
  int lane = threadIdx.x & 31;
  if (n >= N) return;
  int r0 = rowptr[n], r1 = rowptr[n + 1];
  float s = 0.f;
  for (int p = r0; p < r1; ++p)
    s += edge_attr[(size_t)csr_eid[p] * EDD + lane];
  float dv = fmaxf((float)(r1 - r0), 1.f);
  loop_attr[(size_t)n * EDD + lane] = s / dv;
}

// ---------------- conversions ----------------

__global__ void split_f32_kernel(const float* __restrict__ in, unsigned short* __restrict__ hi,
                                 unsigned short* __restrict__ lo, int n4) {
  int i = blockIdx.x * 256 + threadIdx.x;
  if (i >= n4) return;
  float4 v = ((const float4*)in)[i];
  ushort4 h, l;
  split2(v.x, h.x, l.x); split2(v.y, h.y, l.y);
  split2(v.z, h.z, l.z); split2(v.w, h.w, l.w);
  ((ushort4*)hi)[i] = h;
  ((ushort4*)lo)[i] = l;
}

// W [K][1024] f32 -> Bt_hi/lo [1024][K] bf16 (transposed, K-contiguous)
__global__ void split_transpose_kernel(const float* __restrict__ W,
                                       unsigned short* __restrict__ Bthi,
                                       unsigned short* __restrict__ Btlo, int K) {
  __shared__ float tile[32][33];
  int bn = blockIdx.x * 32;
  int bk = blockIdx.y * 32;
  int tx = threadIdx.x & 31, ty = threadIdx.x >> 5;
  for (int r = ty; r < 32; r += 8)
    tile[r][tx] = W[(size_t)(bk + r) * 1024 + bn + tx];
  __syncthreads();
  for (int r = ty; r < 32; r += 8) {
    float v = tile[tx][r];
    unsigned short h, l;
    split2(v, h, l);
    Bthi[(size_t)(bn + r) * K + bk + tx] = h;
    Btlo[(size_t)(bn + r) * K + bk + tx] = l;
  }
}

// ---------------- MFMA GEMM (m97 structure): C[M,1024] = A @ B ----------------
// Optionally also writes bf16-hi copy of C (for the layer-2 bf16 gather).

__global__ __launch_bounds__(256) void gemm_mfma_split_kernel(
    const unsigned short* __restrict__ Ahi, const unsigned short* __restrict__ Alo,
    const unsigned short* __restrict__ Bthi, const unsigned short* __restrict__ Btlo,
    float* __restrict__ C, unsigned short* __restrict__ Chi, int M, int K) {
  __shared__ __align__(16) unsigned short lds[4 * 128 * 32];
  unsigned short* As_hi = lds;
  unsigned short* As_lo = lds + 4096;
  unsigned short* Bs_hi = lds + 8192;
  unsigned short* Bs_lo = lds + 12288;
  const int t = threadIdx.x;
  const int lane = t & 63;
  const int wid = t >> 6;
  const int wr = wid >> 1, wc = wid & 1;
  const int m0 = blockIdx.y * 128;
  const int n0 = blockIdx.x * 128;

  const int srow = lane >> 2;     // 0..15
  const int sg = lane & 3;        // 16B group 0..3

  f32x4 acc[4][4] = {};

  for (int k0 = 0; k0 < K; k0 += 32) {
    __syncthreads();  // all waves done reading previous tile
#pragma unroll
    for (int q = 0; q < 2; ++q) {
      int rb = wid * 32 + q * 16;
      int row = rb + srow;
      int gsrc = sg ^ ((row >> 1) & 3);  // pre-swizzled global source
      size_t ga = (size_t)(m0 + row) * K + k0 + gsrc * 8;
      size_t gb = (size_t)(n0 + row) * K + k0 + gsrc * 8;
      gload_lds16(Ahi + ga, As_hi + rb * 32);
      gload_lds16(Alo + ga, As_lo + rb * 32);
      gload_lds16(Bthi + gb, Bs_hi + rb * 32);
      gload_lds16(Btlo + gb, Bs_lo + rb * 32);
    }
    __syncthreads();

    bf16x8 ah[4], al[4];
#pragma unroll
    for (int i = 0; i < 4; ++i) {
      int rowa = wr * 64 + i * 16 + (lane & 15);
      int offa = rowa * 32 + ((((lane >> 4) ^ ((rowa >> 1) & 3))) * 8);
      ah[i] = *(const bf16x8*)(As_hi + offa);
      al[i] = *(const bf16x8*)(As_lo + offa);
    }
#pragma unroll
    for (int j = 0; j < 4; ++j) {
      int rowb = wc * 64 + j * 16 + (lane & 15);
      int offb = rowb * 32 + ((((lane >> 4) ^ ((rowb >> 1) & 3))) * 8);
      bf16x8 bh = *(const bf16x8*)(Bs_hi + offb);
      bf16x8 bl = *(const bf16x8*)(Bs_lo + offb);
#pragma unroll
      for (int i = 0; i < 4; ++i) {
        acc[i][j] = __builtin_amdgcn_mfma_f32_16x16x32_bf16(ah[i], bh, acc[i][j], 0, 0, 0);
        acc[i][j] = __builtin_amdgcn_mfma_f32_16x16x32_bf16(ah[i], bl, acc[i][j], 0, 0, 0);
        acc[i][j] = __builtin_amdgcn_mfma_f32_16x16x32_bf16(al[i], bh, acc[i][j], 0, 0, 0);
      }
    }
  }
#pragma unroll
  for (int i = 0; i < 4; ++i)
#pragma unroll
    for (int j = 0; j < 4; ++j)
#pragma unroll
      for (int r = 0; r < 4; ++r) {
        int m = m0 + wr * 64 + i * 16 + (lane >> 4) * 4 + r;
        int n = n0 + wc * 64 + j * 16 + (lane & 15);
        if (m < M) {
          C[(size_t)m * 1024 + n] = acc[i][j][r];
          if (Chi) Chi[(size_t)m * 1024 + n] = f2bf_rn(acc[i][j][r]);
        }
      }
}

// ---------------- attention scalars ----------------

__global__ __launch_bounds__(256) void asad_kernel(const float* __restrict__ xh,
    const float* __restrict__ att_s, const float* __restrict__ att_d,
    float* __restrict__ a_s, float* __restrict__ a_d) {
  int n = blockIdx.x, t = threadIdx.x;
  float4 v = ((const float4*)xh)[(size_t)n * 256 + t];
  float4 s4 = ((const float4*)att_s)[t];
  float4 d4 = ((const float4*)att_d)[t];
  float ps = v.x * s4.x + v.y * s4.y + v.z * s4.z + v.w * s4.w;
  float pd = v.x * d4.x + v.y * d4.y + v.z * d4.z + v.w * d4.w;
#pragma unroll
  for (int mask = 1; mask <= 16; mask <<= 1) {
    ps += __shfl_xor(ps, mask);
    pd += __shfl_xor(pd, mask);
  }
  if ((t & 31) == 0) {
    int h = t >> 5;
    a_s[(size_t)n * 8 + h] = ps;
    a_d[(size_t)n * 8 + h] = pd;
  }
}

__global__ void ve_kernel(const float* __restrict__ We, const float* __restrict__ att_e,
                          float* __restrict__ Ve) {
  int t = threadIdx.x;  // 256
  int d = t >> 3, h = t & 7;
  float s = 0.f;
  for (int c = 0; c < 128; ++c) s = fmaf(We[d * 1024 + h * 128 + c], att_e[h * 128 + c], s);
  Ve[t] = s;
}

// raw alpha (leaky_relu) in CSR order; self-loop alphas separate.
__global__ __launch_bounds__(256) void edge_alpha_kernel(
    const int* __restrict__ csr_src, const int* __restrict__ csr_dst,
    const int* __restrict__ csr_eid,
    const float* __restrict__ edge_attr, const float* __restrict__ loop_attr,
    const float* __restrict__ a_s, const float* __restrict__ a_d,
    const float* __restrict__ Ve,
    float* __restrict__ alpha_csr, float* __restrict__ alpha_self, int E, int n) {
  __shared__ float sVe[EDD][8];
  int t = threadIdx.x;
  sVe[t >> 3][t & 7] = Ve[t];
  __syncthreads();
  int idx = blockIdx.x * 256 + t;
  if (idx >= E + n) return;
  int s, d;
  const float* ea;
  float* outp;
  if (idx < E) {
    s = csr_src[idx]; d = csr_dst[idx];
    ea = edge_attr + (size_t)csr_eid[idx] * EDD;
    outp = alpha_csr + (size_t)idx * 8;
  } else {
    s = d = idx - E;
    ea = loop_attr + (size_t)(idx - E) * EDD;
    outp = alpha_self + (size_t)(idx - E) * 8;
  }
  float ae[8] = {0.f, 0.f, 0.f, 0.f, 0.f, 0.f, 0.f, 0.f};
#pragma unroll
  for (int k = 0; k < EDD; k += 4) {
    float4 v = *(const float4*)&ea[k];
#pragma unroll
    for (int h = 0; h < 8; ++h) {
      ae[h] = fmaf(v.x, sVe[k][h], ae[h]);
      ae[h] = fmaf(v.y, sVe[k + 1][h], ae[h]);
      ae[h] = fmaf(v.z, sVe[k + 2][h], ae[h]);
      ae[h] = fmaf(v.w, sVe[k + 3][h], ae[h]);
    }
  }
#pragma unroll
  for (int h = 0; h < 8; ++h) {
    float a = a_s[(size_t)s * 8 + h] + a_d[(size_t)d * 8 + h] + ae[h];
    outp[h] = (a > 0.f) ? a : 0.2f * a;
  }
}

// ---------------- softmax weights (in-place over alpha_csr) ----------------
// One wave per node: stats (8 slots x 8 heads), then overwrite alpha_csr with
// normalized weights; pself[n][h] = normalized self weight.

__global__ __launch_bounds__(256) void sm_weights_kernel(
    float* __restrict__ alpha_csr, const float* __restrict__ alpha_self,
    float* __restrict__ pself, const int* __restrict__ rowptr, int N) {
  int n = blockIdx.x * 4 + (threadIdx.x >> 6);
  int lane = threadIdx.x & 63;
  if (n >= N) return;
  int r0 = rowptr[n], deg = rowptr[n + 1] - r0;
  int h = lane & 7, slot = lane >> 3;
  float m = -1e30f, s = 0.f;
  for (int i = slot; i < deg; i += 8) {
    float a = alpha_csr[(size_t)(r0 + i) * 8 + h];
    if (a <= m) {
      s += __expf(a - m);
    } else {
      s = s * __expf(m - a) + 1.f;
      m = a;
    }
  }
#pragma unroll
  for (int mask = 8; mask < 64; mask <<= 1) {
    float mo = __shfl_xor(m, mask);
    float so = __shfl_xor(s, mask);
    float mn = fmaxf(m, mo);
    s = s * __expf(m - mn) + so * __expf(mo - mn);
    m = mn;
  }
  float aself = alpha_self[(size_t)n * 8 + h];
  float mn = fmaxf(m, aself);
  s = s * __expf(m - mn) + __expf(aself - mn);
  float inv = 1.f / (s + 1e-16f);
  if (lane < 8) pself[(size_t)n * 8 + lane] = __expf(aself - mn) * inv;
  for (int idx = lane; idx < deg * 8; idx += 64) {
    // idx & 7 == lane & 7 == h  (64 % 8 == 0)
    size_t p = (size_t)(r0 + (idx >> 3)) * 8 + h;
    alpha_csr[p] = __expf(alpha_csr[p] - mn) * inv;
  }
}

// ---------------- layer-1 aggregation: one wave per (node, head) ------------
// blockIdx.x = head + 8*group  ->  head h lands on XCD h (round-robin dispatch).
// Gathers f32 head-slices (512B rows); writes relu(agg+b1) split to bf16 hi/lo.

__global__ __launch_bounds__(256) void agg_head_kernel(
    const float* __restrict__ xh, const float* __restrict__ pw,
    const float* __restrict__ pself, const int* __restrict__ rowptr,
    const int* __restrict__ csr_src, const float* __restrict__ bias,
    unsigned short* __restrict__ ohi, unsigned short* __restrict__ olo, int N) {
  int head = blockIdx.x & 7;
  int grp = blockIdx.x >> 3;
  int n = grp * 4 + (threadIdx.x >> 6);
  int lane = threadIdx.x & 63;
  if (n >= N) return;
  int r0 = rowptr[n], r1 = rowptr[n + 1];
  const float2* x2 = (const float2*)xh;
  size_t coff = (size_t)head * 64 + lane;  // float2 offset within a row
  float wself = pself[(size_t)n * 8 + head];
  float2 v = x2[(size_t)n * 512 + coff];
  float ax = wself * v.x, ay = wself * v.y;
  for (int p = r0; p < r1; ++p) {
    float w = pw[(size_t)p * 8 + head];   // wave-uniform
    int s = csr_src[p];                   // wave-uniform
    float2 u = x2[(size_t)s * 512 + coff];
    ax = fmaf(w, u.x, ax);
    ay = fmaf(w, u.y, ay);
  }
  float2 b = ((const float2*)bias)[coff];
  float ox = fmaxf(ax + b.x, 0.f);
  float oy = fmaxf(ay + b.y, 0.f);
  ushort2 h2, l2;
  split2(ox, h2.x, l2.x);
  split2(oy, h2.y, l2.y);
  size_t o = (size_t)n * 512 + coff;
  ((ushort2*)ohi)[o] = h2;
  ((ushort2*)olo)[o] = l2;
}

// ---------------- layer-2 aggregation: per-node block, bf16 gather ----------
// out[n, c] = mean_h(agg[h][c]) + b2[c]

__global__ __launch_bounds__(256) void agg_node_kernel(
    const unsigned short* __restrict__ xhi, const float* __restrict__ pw,
    const float* __restrict__ pself, const int* __restrict__ rowptr,
    const int* __restrict__ csr_src, const float* __restrict__ bias,
    float* __restrict__ outp, int N) {
  int n = blockIdx.x;
  int t = threadIdx.x;
  int h = t >> 5;
  __shared__ int ls[64];
  __shared__ float pws[64 * 8];
  __shared__ float red[256][4];
  int r0 = rowptr[n];
  int deg = rowptr[n + 1] - r0;
  const ushort4* xv = (const ushort4*)xhi;
  float wself = pself[(size_t)n * 8 + h];
  ushort4 sv = xv[(size_t)n * 256 + t];
  float ax = wself * bf2f(sv.x), ay = wself * bf2f(sv.y);
  float az = wself * bf2f(sv.z), aw = wself * bf2f(sv.w);
  for (int base = 0; base < deg; base += 64) {
    int cnt = min(64, deg - base);
    if (t < cnt) ls[t] = csr_src[r0 + base + t];
    for (int idx = t; idx < cnt * 8; idx += 256)
      pws[idx] = pw[(size_t)(r0 + base) * 8 + idx];
    __syncthreads();
#pragma unroll 4
    for (int j = 0; j < cnt; ++j) {
      float w = pws[j * 8 + h];
      ushort4 u = xv[(size_t)ls[j] * 256 + t];
      ax = fmaf(w, bf2f(u.x), ax);
      ay = fmaf(w, bf2f(u.y), ay);
      az = fmaf(w, bf2f(u.z), az);
      aw = fmaf(w, bf2f(u.w), aw);
    }
    __syncthreads();
  }
  red[t][0] = ax; red[t][1] = ay; red[t][2] = az; red[t][3] = aw;
  __syncthreads();
  if (t < 32) {
    float sx = 0.f, sy = 0.f, sz = 0.f, sw = 0.f;
#pragma unroll
    for (int k = 0; k < 8; ++k) {
      sx += red[t + 32 * k][0];
      sy += red[t + 32 * k][1];
      sz += red[t + 32 * k][2];
      sw += red[t + 32 * k][3];
    }
    float4 b = ((const float4*)bias)[t];
    float4 o;
    o.x = sx * 0.125f + b.x;
    o.y = sy * 0.125f + b.y;
    o.z = sz * 0.125f + b.z;
    o.w = sw * 0.125f + b.w;
    ((float4*)outp)[(size_t)n * 32 + t] = o;
  }
}

// ---------------- launch ----------------

extern "C" void kernel_launch(void* const* d_in, const int* in_sizes, int n_in,
                              void* d_out, int out_size, void* d_ws, size_t ws_size,
                              hipStream_t stream) {
  const float* x        = (const float*)d_in[0];
  const int*   ei       = (const int*)d_in[1];
  const float* edge_attr= (const float*)d_in[2];
  const float* W1       = (const float*)d_in[3];
  const float* We1      = (const float*)d_in[4];
  const float* as1      = (const float*)d_in[5];
  const float* ad1      = (const float*)d_in[6];
  const float* ae1      = (const float*)d_in[7];
  const float* b1       = (const float*)d_in[8];
  const float* W2       = (const float*)d_in[9];
  const float* We2      = (const float*)d_in[10];
  const float* as2      = (const float*)d_in[11];
  const float* ad2      = (const float*)d_in[12];
  const float* ae2      = (const float*)d_in[13];
  const float* b2       = (const float*)d_in[14];
  float* out = (float*)d_out;

  const int N = in_sizes[0] / 128;   // 10000 nodes
  const int E = in_sizes[2] / EDD;   // 160000 edges
  const int Mpad = ((N + 127) / 128) * 128;  // 10112

  char* ws = (char*)d_ws;
  size_t off = 0;
  auto alloc = [&](size_t bytes) -> void* {
    void* p = ws + off;
    off = (off + bytes + 255) & ~(size_t)255;
    return p;
  };
  int*   deg       = (int*)alloc((size_t)N * 4);
  int*   rowptr    = (int*)alloc((size_t)(N + 1) * 4);
  int*   cursor    = (int*)alloc((size_t)N * 4);
  int*   csr_src   = (int*)alloc((size_t)E * 4);
  int*   csr_dst   = (int*)alloc((size_t)E * 4);
  int*   csr_eid   = (int*)alloc((size_t)E * 4);
  float* loop_attr = (float*)alloc((size_t)N * EDD * 4);
  float* a_s       = (float*)alloc((size_t)N * 8 * 4);
  float* a_d       = (float*)alloc((size_t)N * 8 * 4);
  float* Ve        = (float*)alloc(256 * 4);
  float* alpha_csr = (float*)alloc((size_t)E * 8 * 4);   // becomes pw after sm_weights
  float* alpha_self= (float*)alloc((size_t)N * 8 * 4);
  float* pself     = (float*)alloc((size_t)N * 8 * 4);
  float* xh        = (float*)alloc((size_t)N * 1024 * 4);
  unsigned short* xh2hi = (unsigned short*)alloc((size_t)N * 1024 * 2);
  unsigned short* xhi   = (unsigned short*)alloc((size_t)Mpad * 128 * 2);
  unsigned short* xlo   = (unsigned short*)alloc((size_t)Mpad * 128 * 2);
  unsigned short* Bt1hi = (unsigned short*)alloc((size_t)1024 * 128 * 2);
  unsigned short* Bt1lo = (unsigned short*)alloc((size_t)1024 * 128 * 2);
  unsigned short* Bt2hi = (unsigned short*)alloc((size_t)1024 * 1024 * 2);
  unsigned short* Bt2lo = (unsigned short*)alloc((size_t)1024 * 1024 * 2);
  unsigned short* h1hi  = (unsigned short*)alloc((size_t)Mpad * 1024 * 2);
  unsigned short* h1lo  = (unsigned short*)alloc((size_t)Mpad * 1024 * 2);
  (void)ws_size; (void)n_in; (void)out_size;

  hipMemsetAsync(deg, 0, (size_t)N * 4, stream);

  int gE = (E + 255) / 256;
  deg_count_kernel<<<gE, 256, 0, stream>>>(ei, deg, E);
  scan_kernel<<<1, 1024, 0, stream>>>(deg, rowptr, cursor, N);
  scatter_kernel<<<gE, 256, 0, stream>>>(ei, cursor, csr_src, csr_dst, csr_eid, E);
  loop_attr_kernel<<<(N + 7) / 8, 256, 0, stream>>>(rowptr, csr_eid, edge_attr, loop_attr, N);

  split_f32_kernel<<<(N * 128 / 4 + 255) / 256, 256, 0, stream>>>(x, xhi, xlo, N * 128 / 4);
  split_transpose_kernel<<<dim3(32, 4), 256, 0, stream>>>(W1, Bt1hi, Bt1lo, 128);
  split_transpose_kernel<<<dim3(32, 32), 256, 0, stream>>>(W2, Bt2hi, Bt2lo, 1024);

  dim3 ggrid(8, Mpad / 128);
  int gEA = (E + N + 255) / 256;
  int gSM = (N + 3) / 4;

  // ---- layer 1 ----
  gemm_mfma_split_kernel<<<ggrid, 256, 0, stream>>>(xhi, xlo, Bt1hi, Bt1lo, xh, nullptr, N, 128);
  asad_kernel<<<N, 256, 0, stream>>>(xh, as1, ad1, a_s, a_d);
  ve_kernel<<<1, 256, 0, stream>>>(We1, ae1, Ve);
  edge_alpha_kernel<<<gEA, 256, 0, stream>>>(csr_src, csr_dst, csr_eid, edge_attr, loop_attr,
                                             a_s, a_d, Ve, alpha_csr, alpha_self, E, N);
  sm_weights_kernel<<<gSM, 256, 0, stream>>>(alpha_csr, alpha_self, pself, rowptr, N);
  agg_head_kernel<<<8 * ((N + 3) / 4), 256, 0, stream>>>(xh, alpha_csr, pself, rowptr, csr_src,
                                                         b1, h1hi, h1lo, N);

  // ---- layer 2 ----
  gemm_mfma_split_kernel<<<ggrid, 256, 0, stream>>>(h1hi, h1lo, Bt2hi, Bt2lo, xh, xh2hi, N, 1024);
  asad_kernel<<<N, 256, 0, stream>>>(xh, as2, ad2, a_s, a_d);
  ve_kernel<<<1, 256, 0, stream>>>(We2, ae2, Ve);
  edge_alpha_kernel<<<gEA, 256, 0, stream>>>(csr_src, csr_dst, csr_eid, edge_attr, loop_attr,
                                             a_s, a_d, Ve, alpha_csr, alpha_self, E, N);
  sm_weights_kernel<<<gSM, 256, 0, stream>>>(alpha_csr, alpha_self, pself, rowptr, N);
  agg_node_kernel<<<N, 256, 0, stream>>>(xh2hi, alpha_csr, pself, rowptr, csr_src, b2, out, N);
}

// Round 5
// 333.856 us; speedup vs baseline: 1.8319x; 1.2073x over previous
//
#include <hip/hip_runtime.h>
#include <hip/hip_bf16.h>
#include <cstdint>
#include <cstddef>

// TwoLayerGAT on MI355X — round 5:
//  - aggregation back to block-per-node LDS-staged gather (high MLP), but bf16 rows
//  - a_s/a_d fused into GEMM epilogue (each C-block = exactly one head) -> asad gone,
//    GEMM writes only bf16 activations (20 MB instead of 60 MB)
//  - edge_attr pre-permuted to CSR order (coalesced loop_attr + edge_alpha)

#define EDD 32

typedef __attribute__((ext_vector_type(4))) float f32x4;
typedef __attribute__((ext_vector_type(8))) short bf16x8;

__device__ inline unsigned short f2bf_rn(float f) {
  uint32_t u = __float_as_uint(f);
  return (unsigned short)((u + 0x7FFFu + ((u >> 16) & 1u)) >> 16);
}

__device__ inline void split2(float x, unsigned short& h, unsigned short& l) {
  uint32_t u = __float_as_uint(x);
  h = (unsigned short)(u >> 16);                       // truncated hi
  float r = x - __uint_as_float(u & 0xFFFF0000u);      // exact residual
  l = f2bf_rn(r);
}

__device__ inline float bf2f(unsigned short b) {
  return __uint_as_float(((uint32_t)b) << 16);
}

__device__ inline void gload_lds16(const void* g, void* l) {
  __builtin_amdgcn_global_load_lds((const __attribute__((address_space(1))) void*)g,
                                   (__attribute__((address_space(3))) void*)l, 16, 0, 0);
}

// ---------------- graph prep ----------------

__global__ void deg_count_kernel(const int* __restrict__ ei, int* __restrict__ deg, int E) {
  int e = blockIdx.x * 256 + threadIdx.x;
  if (e < E) atomicAdd(&deg[ei[E + e]], 1);
}

// single block, 1024 threads: exclusive scan of deg -> rowptr, cursor
__global__ void scan_kernel(const int* __restrict__ deg, int* __restrict__ rowptr,
                            int* __restrict__ cursor, int n) {
  __shared__ int wsum[16];
  int t = threadIdx.x;
  int chunk = (n + 1023) >> 10;
  int lo = min(t * chunk, n), hi = min(lo + chunk, n);
  int s = 0;
  for (int i = lo; i < hi; ++i) s += deg[i];
  int lane = t & 63, w = t >> 6;
  int v = s;
#pragma unroll
  for (int off = 1; off < 64; off <<= 1) {
    int u = __shfl_up(v, off);
    if (lane >= off) v += u;
  }
  if (lane == 63) wsum[w] = v;
  __syncthreads();
  if (t == 0) {
    int acc = 0;
#pragma unroll
    for (int i = 0; i < 16; ++i) { int x = wsum[i]; wsum[i] = acc; acc += x; }
  }
  __syncthreads();
  int excl = v - s + wsum[w];
  for (int i = lo; i < hi; ++i) {
    rowptr[i] = excl; cursor[i] = excl; excl += deg[i];
  }
  if (t == 1023) rowptr[n] = excl;
}

__global__ void scatter_kernel(const int* __restrict__ ei, int* __restrict__ cursor,
                               int* __restrict__ csr_src, int* __restrict__ csr_dst,
                               int* __restrict__ csr_eid, int E) {
  int e = blockIdx.x * 256 + threadIdx.x;
  if (e >= E) return;
  int d = ei[E + e];
  int pos = atomicAdd(&cursor[d], 1);
  csr_src[pos] = ei[e];
  csr_dst[pos] = d;
  csr_eid[pos] = e;
}

// edge_attr -> CSR order (one float4 per thread)
__global__ void permute_ea_kernel(const int* __restrict__ csr_eid,
                                  const float* __restrict__ edge_attr,
                                  float* __restrict__ ea_csr, int E) {
  int gid = blockIdx.x * 256 + threadIdx.x;
  if (gid >= E * 8) return;
  int p = gid >> 3, q = gid & 7;
  int e = csr_eid[p];
  ((float4*)ea_csr)[(size_t)p * 8 + q] = ((const float4*)edge_attr)[(size_t)e * 8 + q];
}

// loop_attr[n][d] = mean over incoming edges (contiguous CSR reads)
__global__ void loop_attr_kernel(const int* __restrict__ rowptr,
                                 const float* __restrict__ ea_csr,
                                 float* __restrict__ loop_attr, int N) {
  int n = blockIdx.x * 8 + (threadIdx.x >> 5);
  int lane = threadIdx.x & 31;
  if (n >= N) return;
  int r0 = rowptr[n], r1 = rowptr[n + 1];
  float s = 0.f;
  for (int p = r0; p < r1; ++p)
    s += ea_csr[(size_t)p * EDD + lane];
  float dv = fmaxf((float)(r1 - r0), 1.f);
  loop_attr[(size_t)n * EDD + lane] = s / dv;
}

// ---------------- conversions ----------------

__global__ void split_f32_kernel(const float* __restrict__ in, unsigned short* __restrict__ hi,
                                 unsigned short* __restrict__ lo, int n4) {
  int i = blockIdx.x * 256 + threadIdx.x;
  if (i >= n4) return;
  float4 v = ((const float4*)in)[i];
  ushort4 h, l;
  split2(v.x, h.x, l.x); split2(v.y, h.y, l.y);
  split2(v.z, h.z, l.z); split2(v.w, h.w, l.w);
  ((ushort4*)hi)[i] = h;
  ((ushort4*)lo)[i] = l;
}

// W [K][1024] f32 -> Bt_hi/lo [1024][K] bf16 (transposed, K-contiguous)
__global__ void split_transpose_kernel(const float* __restrict__ W,
                                       unsigned short* __restrict__ Bthi,
                                       unsigned short* __restrict__ Btlo, int K) {
  __shared__ float tile[32][33];
  int bn = blockIdx.x * 32;
  int bk = blockIdx.y * 32;
  int tx = threadIdx.x & 31, ty = threadIdx.x >> 5;
  for (int r = ty; r < 32; r += 8)
    tile[r][tx] = W[(size_t)(bk + r) * 1024 + bn + tx];
  __syncthreads();
  for (int r = ty; r < 32; r += 8) {
    float v = tile[tx][r];
    unsigned short h, l;
    split2(v, h, l);
    Bthi[(size_t)(bn + r) * K + bk + tx] = h;
    Btlo[(size_t)(bn + r) * K + bk + tx] = l;
  }
}

// ---------------- MFMA GEMM + fused a_s/a_d epilogue ----------------
// C[M,1024] = A @ B (split-bf16 3-product). Each block's 128 cols = one head hb.
// Writes Cbf (bf16) and a_s/a_d[m, hb] = sum_c C[m][c]*att[hb][c] (exact, f32 acc).

__global__ __launch_bounds__(256) void gemm_mfma_split_kernel(
    const unsigned short* __restrict__ Ahi, const unsigned short* __restrict__ Alo,
    const unsigned short* __restrict__ Bthi, const unsigned short* __restrict__ Btlo,
    unsigned short* __restrict__ Cbf, float* __restrict__ a_s, float* __restrict__ a_d,
    const float* __restrict__ att_s, const float* __restrict__ att_d, int M, int K) {
  __shared__ __align__(16) unsigned short lds[4 * 128 * 32];
  __shared__ float redS[128][2];
  __shared__ float redD[128][2];
  unsigned short* As_hi = lds;
  unsigned short* As_lo = lds + 4096;
  unsigned short* Bs_hi = lds + 8192;
  unsigned short* Bs_lo = lds + 12288;
  const int t = threadIdx.x;
  const int lane = t & 63;
  const int wid = t >> 6;
  const int wr = wid >> 1, wc = wid & 1;
  const int m0 = blockIdx.y * 128;
  const int n0 = blockIdx.x * 128;
  const int hb = blockIdx.x;  // head index of this 128-col stripe

  const int srow = lane >> 2;
  const int sg = lane & 3;

  f32x4 acc[4][4] = {};

  for (int k0 = 0; k0 < K; k0 += 32) {
    __syncthreads();
#pragma unroll
    for (int q = 0; q < 2; ++q) {
      int rb = wid * 32 + q * 16;
      int row = rb + srow;
      int gsrc = sg ^ ((row >> 1) & 3);
      size_t ga = (size_t)(m0 + row) * K + k0 + gsrc * 8;
      size_t gb = (size_t)(n0 + row) * K + k0 + gsrc * 8;
      gload_lds16(Ahi + ga, As_hi + rb * 32);
      gload_lds16(Alo + ga, As_lo + rb * 32);
      gload_lds16(Bthi + gb, Bs_hi + rb * 32);
      gload_lds16(Btlo + gb, Bs_lo + rb * 32);
    }
    __syncthreads();

    bf16x8 ah[4], al[4];
#pragma unroll
    for (int i = 0; i < 4; ++i) {
      int rowa = wr * 64 + i * 16 + (lane & 15);
      int offa = rowa * 32 + ((((lane >> 4) ^ ((rowa >> 1) & 3))) * 8);
      ah[i] = *(const bf16x8*)(As_hi + offa);
      al[i] = *(const bf16x8*)(As_lo + offa);
    }
#pragma unroll
    for (int j = 0; j < 4; ++j) {
      int rowb = wc * 64 + j * 16 + (lane & 15);
      int offb = rowb * 32 + ((((lane >> 4) ^ ((rowb >> 1) & 3))) * 8);
      bf16x8 bh = *(const bf16x8*)(Bs_hi + offb);
      bf16x8 bl = *(const bf16x8*)(Bs_lo + offb);
#pragma unroll
      for (int i = 0; i < 4; ++i) {
        acc[i][j] = __builtin_amdgcn_mfma_f32_16x16x32_bf16(ah[i], bh, acc[i][j], 0, 0, 0);
        acc[i][j] = __builtin_amdgcn_mfma_f32_16x16x32_bf16(ah[i], bl, acc[i][j], 0, 0, 0);
        acc[i][j] = __builtin_amdgcn_mfma_f32_16x16x32_bf16(al[i], bh, acc[i][j], 0, 0, 0);
      }
    }
  }

  // attention vectors for this head (4 cols per lane)
  float as_v[4], ad_v[4];
#pragma unroll
  for (int j = 0; j < 4; ++j) {
    int c = n0 + wc * 64 + j * 16 + (lane & 15);
    as_v[j] = att_s[c];
    ad_v[j] = att_d[c];
  }

#pragma unroll
  for (int i = 0; i < 4; ++i) {
#pragma unroll
    for (int r = 0; r < 4; ++r) {
      float sA = 0.f, sD = 0.f;
#pragma unroll
      for (int j = 0; j < 4; ++j) {
        sA = fmaf(acc[i][j][r], as_v[j], sA);
        sD = fmaf(acc[i][j][r], ad_v[j], sD);
      }
#pragma unroll
      for (int mask = 1; mask <= 8; mask <<= 1) {
        sA += __shfl_xor(sA, mask);
        sD += __shfl_xor(sD, mask);
      }
      if ((lane & 15) == 0) {
        int ml = wr * 64 + i * 16 + (lane >> 4) * 4 + r;
        redS[ml][wc] = sA;
        redD[ml][wc] = sD;
      }
      // C write (bf16 only)
      int m = m0 + wr * 64 + i * 16 + (lane >> 4) * 4 + r;
      if (m < M) {
#pragma unroll
        for (int j = 0; j < 4; ++j) {
          int n = n0 + wc * 64 + j * 16 + (lane & 15);
          Cbf[(size_t)m * 1024 + n] = f2bf_rn(acc[i][j][r]);
        }
      }
    }
  }
  __syncthreads();
  if (t < 128) {
    int m = m0 + t;
    if (m < M) {
      a_s[(size_t)m * 8 + hb] = redS[t][0] + redS[t][1];
      a_d[(size_t)m * 8 + hb] = redD[t][0] + redD[t][1];
    }
  }
}

// ---------------- attention scalars ----------------

__global__ void ve_kernel(const float* __restrict__ We, const float* __restrict__ att_e,
                          float* __restrict__ Ve) {
  int t = threadIdx.x;  // 256
  int d = t >> 3, h = t & 7;
  float s = 0.f;
  for (int c = 0; c < 128; ++c) s = fmaf(We[d * 1024 + h * 128 + c], att_e[h * 128 + c], s);
  Ve[t] = s;
}

// raw alpha (leaky_relu) in CSR order; self-loop alphas separate.
__global__ __launch_bounds__(256) void edge_alpha_kernel(
    const int* __restrict__ csr_src, const int* __restrict__ csr_dst,
    const float* __restrict__ ea_csr, const float* __restrict__ loop_attr,
    const float* __restrict__ a_s, const float* __restrict__ a_d,
    const float* __restrict__ Ve,
    float* __restrict__ alpha_csr, float* __restrict__ alpha_self, int E, int n) {
  __shared__ float sVe[EDD][8];
  int t = threadIdx.x;
  sVe[t >> 3][t & 7] = Ve[t];
  __syncthreads();
  int idx = blockIdx.x * 256 + t;
  if (idx >= E + n) return;
  int s, d;
  const float* ea;
  float* outp;
  if (idx < E) {
    s = csr_src[idx]; d = csr_dst[idx];
    ea = ea_csr + (size_t)idx * EDD;
    outp = alpha_csr + (size_t)idx * 8;
  } else {
    s = d = idx - E;
    ea = loop_attr + (size_t)(idx - E) * EDD;
    outp = alpha_self + (size_t)(idx - E) * 8;
  }
  float ae[8] = {0.f, 0.f, 0.f, 0.f, 0.f, 0.f, 0.f, 0.f};
#pragma unroll
  for (int k = 0; k < EDD; k += 4) {
    float4 v = *(const float4*)&ea[k];
#pragma unroll
    for (int h = 0; h < 8; ++h) {
      ae[h] = fmaf(v.x, sVe[k][h], ae[h]);
      ae[h] = fmaf(v.y, sVe[k + 1][h], ae[h]);
      ae[h] = fmaf(v.z, sVe[k + 2][h], ae[h]);
      ae[h] = fmaf(v.w, sVe[k + 3][h], ae[h]);
    }
  }
#pragma unroll
  for (int h = 0; h < 8; ++h) {
    float a = a_s[(size_t)s * 8 + h] + a_d[(size_t)d * 8 + h] + ae[h];
    outp[h] = (a > 0.f) ? a : 0.2f * a;
  }
}

// ---------------- softmax weights (in-place over alpha_csr) ----------------

__global__ __launch_bounds__(256) void sm_weights_kernel(
    float* __restrict__ alpha_csr, const float* __restrict__ alpha_self,
    float* __restrict__ pself, const int* __restrict__ rowptr, int N) {
  int n = blockIdx.x * 4 + (threadIdx.x >> 6);
  int lane = threadIdx.x & 63;
  if (n >= N) return;
  int r0 = rowptr[n], deg = rowptr[n + 1] - r0;
  int h = lane & 7, slot = lane >> 3;
  float m = -1e30f, s = 0.f;
  for (int i = slot; i < deg; i += 8) {
    float a = alpha_csr[(size_t)(r0 + i) * 8 + h];
    if (a <= m) {
      s += __expf(a - m);
    } else {
      s = s * __expf(m - a) + 1.f;
      m = a;
    }
  }
#pragma unroll
  for (int mask = 8; mask < 64; mask <<= 1) {
    float mo = __shfl_xor(m, mask);
    float so = __shfl_xor(s, mask);
    float mn = fmaxf(m, mo);
    s = s * __expf(m - mn) + so * __expf(mo - mn);
    m = mn;
  }
  float aself = alpha_self[(size_t)n * 8 + h];
  float mn = fmaxf(m, aself);
  s = s * __expf(m - mn) + __expf(aself - mn);
  float inv = 1.f / (s + 1e-16f);
  if (lane < 8) pself[(size_t)n * 8 + lane] = __expf(aself - mn) * inv;
  for (int idx = lane; idx < deg * 8; idx += 64) {
    size_t p = (size_t)(r0 + (idx >> 3)) * 8 + h;
    alpha_csr[p] = __expf(alpha_csr[p] - mn) * inv;
  }
}

// ---------------- aggregation: block-per-node, bf16 row gather --------------
// LAYER==1: write relu(agg+b1) split hi/lo (feeds GEMM2)
// LAYER==2: write mean_h(agg)+b2 to f32 out

template <int LAYER>
__global__ __launch_bounds__(256) void agg_gather_kernel(
    const unsigned short* __restrict__ xbf, const float* __restrict__ pw,
    const float* __restrict__ pself, const int* __restrict__ rowptr,
    const int* __restrict__ csr_src, const float* __restrict__ bias,
    unsigned short* __restrict__ ohi, unsigned short* __restrict__ olo,
    float* __restrict__ outp, int N) {
  int n = blockIdx.x;
  int t = threadIdx.x;
  int h = t >> 5;
  __shared__ int ls[64];
  __shared__ float pws[64 * 8];
  __shared__ float red[256][4];
  int r0 = rowptr[n];
  int deg = rowptr[n + 1] - r0;
  const ushort4* xv = (const ushort4*)xbf;
  float wself = pself[(size_t)n * 8 + h];
  ushort4 sv = xv[(size_t)n * 256 + t];
  float ax = wself * bf2f(sv.x), ay = wself * bf2f(sv.y);
  float az = wself * bf2f(sv.z), aw = wself * bf2f(sv.w);
  for (int base = 0; base < deg; base += 64) {
    int cnt = min(64, deg - base);
    if (t < cnt) ls[t] = csr_src[r0 + base + t];
    for (int idx = t; idx < cnt * 8; idx += 256)
      pws[idx] = pw[(size_t)(r0 + base) * 8 + idx];
    __syncthreads();
#pragma unroll 4
    for (int j = 0; j < cnt; ++j) {
      float w = pws[j * 8 + h];
      ushort4 u = xv[(size_t)ls[j] * 256 + t];
      ax = fmaf(w, bf2f(u.x), ax);
      ay = fmaf(w, bf2f(u.y), ay);
      az = fmaf(w, bf2f(u.z), az);
      aw = fmaf(w, bf2f(u.w), aw);
    }
    __syncthreads();
  }
  if (LAYER == 1) {
    float4 b = ((const float4*)bias)[t];
    float ox = fmaxf(ax + b.x, 0.f);
    float oy = fmaxf(ay + b.y, 0.f);
    float oz = fmaxf(az + b.z, 0.f);
    float ow = fmaxf(aw + b.w, 0.f);
    ushort4 h4, l4;
    split2(ox, h4.x, l4.x); split2(oy, h4.y, l4.y);
    split2(oz, h4.z, l4.z); split2(ow, h4.w, l4.w);
    ((ushort4*)ohi)[(size_t)n * 256 + t] = h4;
    ((ushort4*)olo)[(size_t)n * 256 + t] = l4;
  } else {
    red[t][0] = ax; red[t][1] = ay; red[t][2] = az; red[t][3] = aw;
    __syncthreads();
    if (t < 32) {
      float sx = 0.f, sy = 0.f, sz = 0.f, sw = 0.f;
#pragma unroll
      for (int k = 0; k < 8; ++k) {
        sx += red[t + 32 * k][0];
        sy += red[t + 32 * k][1];
        sz += red[t + 32 * k][2];
        sw += red[t + 32 * k][3];
      }
      float4 b = ((const float4*)bias)[t];
      float4 o;
      o.x = sx * 0.125f + b.x;
      o.y = sy * 0.125f + b.y;
      o.z = sz * 0.125f + b.z;
      o.w = sw * 0.125f + b.w;
      ((float4*)outp)[(size_t)n * 32 + t] = o;
    }
  }
}

// ---------------- launch ----------------

extern "C" void kernel_launch(void* const* d_in, const int* in_sizes, int n_in,
                              void* d_out, int out_size, void* d_ws, size_t ws_size,
                              hipStream_t stream) {
  const float* x        = (const float*)d_in[0];
  const int*   ei       = (const int*)d_in[1];
  const float* edge_attr= (const float*)d_in[2];
  const float* W1       = (const float*)d_in[3];
  const float* We1      = (const float*)d_in[4];
  const float* as1      = (const float*)d_in[5];
  const float* ad1      = (const float*)d_in[6];
  const float* ae1      = (const float*)d_in[7];
  const float* b1       = (const float*)d_in[8];
  const float* W2       = (const float*)d_in[9];
  const float* We2      = (const float*)d_in[10];
  const float* as2      = (const float*)d_in[11];
  const float* ad2      = (const float*)d_in[12];
  const float* ae2      = (const float*)d_in[13];
  const float* b2       = (const float*)d_in[14];
  float* out = (float*)d_out;

  const int N = in_sizes[0] / 128;   // 10000 nodes
  const int E = in_sizes[2] / EDD;   // 160000 edges
  const int Mpad = ((N + 127) / 128) * 128;  // 10112

  char* ws = (char*)d_ws;
  size_t off = 0;
  auto alloc = [&](size_t bytes) -> void* {
    void* p = ws + off;
    off = (off + bytes + 255) & ~(size_t)255;
    return p;
  };
  int*   deg       = (int*)alloc((size_t)N * 4);
  int*   rowptr    = (int*)alloc((size_t)(N + 1) * 4);
  int*   cursor    = (int*)alloc((size_t)N * 4);
  int*   csr_src   = (int*)alloc((size_t)E * 4);
  int*   csr_dst   = (int*)alloc((size_t)E * 4);
  int*   csr_eid   = (int*)alloc((size_t)E * 4);
  float* ea_csr    = (float*)alloc((size_t)E * EDD * 4);
  float* loop_attr = (float*)alloc((size_t)N * EDD * 4);
  float* a_s       = (float*)alloc((size_t)N * 8 * 4);
  float* a_d       = (float*)alloc((size_t)N * 8 * 4);
  float* Ve        = (float*)alloc(256 * 4);
  float* alpha_csr = (float*)alloc((size_t)E * 8 * 4);   // becomes pw after sm_weights
  float* alpha_self= (float*)alloc((size_t)N * 8 * 4);
  float* pself     = (float*)alloc((size_t)N * 8 * 4);
  unsigned short* xh1bf = (unsigned short*)alloc((size_t)N * 1024 * 2);
  unsigned short* xh2bf = (unsigned short*)alloc((size_t)N * 1024 * 2);
  unsigned short* xhi   = (unsigned short*)alloc((size_t)Mpad * 128 * 2);
  unsigned short* xlo   = (unsigned short*)alloc((size_t)Mpad * 128 * 2);
  unsigned short* Bt1hi = (unsigned short*)alloc((size_t)1024 * 128 * 2);
  unsigned short* Bt1lo = (unsigned short*)alloc((size_t)1024 * 128 * 2);
  unsigned short* Bt2hi = (unsigned short*)alloc((size_t)1024 * 1024 * 2);
  unsigned short* Bt2lo = (unsigned short*)alloc((size_t)1024 * 1024 * 2);
  unsigned short* h1hi  = (unsigned short*)alloc((size_t)Mpad * 1024 * 2);
  unsigned short* h1lo  = (unsigned short*)alloc((size_t)Mpad * 1024 * 2);
  (void)ws_size; (void)n_in; (void)out_size;

  hipMemsetAsync(deg, 0, (size_t)N * 4, stream);

  int gE = (E + 255) / 256;
  deg_count_kernel<<<gE, 256, 0, stream>>>(ei, deg, E);
  scan_kernel<<<1, 1024, 0, stream>>>(deg, rowptr, cursor, N);
  scatter_kernel<<<gE, 256, 0, stream>>>(ei, cursor, csr_src, csr_dst, csr_eid, E);
  permute_ea_kernel<<<(E * 8 + 255) / 256, 256, 0, stream>>>(csr_eid, edge_attr, ea_csr, E);
  loop_attr_kernel<<<(N + 7) / 8, 256, 0, stream>>>(rowptr, ea_csr, loop_attr, N);

  split_f32_kernel<<<(N * 128 / 4 + 255) / 256, 256, 0, stream>>>(x, xhi, xlo, N * 128 / 4);
  split_transpose_kernel<<<dim3(32, 4), 256, 0, stream>>>(W1, Bt1hi, Bt1lo, 128);
  split_transpose_kernel<<<dim3(32, 32), 256, 0, stream>>>(W2, Bt2hi, Bt2lo, 1024);

  dim3 ggrid(8, Mpad / 128);
  int gEA = (E + N + 255) / 256;
  int gSM = (N + 3) / 4;

  // ---- layer 1 ----
  gemm_mfma_split_kernel<<<ggrid, 256, 0, stream>>>(xhi, xlo, Bt1hi, Bt1lo, xh1bf,
                                                    a_s, a_d, as1, ad1, N, 128);
  ve_kernel<<<1, 256, 0, stream>>>(We1, ae1, Ve);
  edge_alpha_kernel<<<gEA, 256, 0, stream>>>(csr_src, csr_dst, ea_csr, loop_attr,
                                             a_s, a_d, Ve, alpha_csr, alpha_self, E, N);
  sm_weights_kernel<<<gSM, 256, 0, stream>>>(alpha_csr, alpha_self, pself, rowptr, N);
  agg_gather_kernel<1><<<N, 256, 0, stream>>>(xh1bf, alpha_csr, pself, rowptr, csr_src,
                                              b1, h1hi, h1lo, nullptr, N);

  // ---- layer 2 ----
  gemm_mfma_split_kernel<<<ggrid, 256, 0, stream>>>(h1hi, h1lo, Bt2hi, Bt2lo, xh2bf,
                                                    a_s, a_d, as2, ad2, N, 1024);
  ve_kernel<<<1, 256, 0, stream>>>(We2, ae2, Ve);
  edge_alpha_kernel<<<gEA, 256, 0, stream>>>(csr_src, csr_dst, ea_csr, loop_attr,
                                             a_s, a_d, Ve, alpha_csr, alpha_self, E, N);
  sm_weights_kernel<<<gSM, 256, 0, stream>>>(alpha_csr, alpha_self, pself, rowptr, N);
  agg_gather_kernel<2><<<N, 256, 0, stream>>>(xh2bf, alpha_csr, pself, rowptr, csr_src,
                                              b2, nullptr, nullptr, out, N);
}

// Round 6
// 315.712 us; speedup vs baseline: 1.9372x; 1.0575x over previous
//
#include <hip/hip_runtime.h>
#include <hip/hip_bf16.h>
#include <cstdint>
#include <cstddef>

// TwoLayerGAT on MI355X — round 6:
//  - GEMM2 -> 2-product split (A = bf16(h1) single, B = hi/lo): 1/3 less MFMA,
//    3 staged tiles instead of 4 (24KB LDS), h1lo buffer+write eliminated.
//    Error adds ~2e-4 to out (averaging over ~17 neighbors x 8 heads washes it).
//  - GEMM1 stays 3-product (error amplified through layer 2; cheap at K=128).
//  - everything else unchanged from round 5.

#define EDD 32

typedef __attribute__((ext_vector_type(4))) float f32x4;
typedef __attribute__((ext_vector_type(8))) short bf16x8;

__device__ inline unsigned short f2bf_rn(float f) {
  uint32_t u = __float_as_uint(f);
  return (unsigned short)((u + 0x7FFFu + ((u >> 16) & 1u)) >> 16);
}

__device__ inline void split2(float x, unsigned short& h, unsigned short& l) {
  uint32_t u = __float_as_uint(x);
  h = (unsigned short)(u >> 16);                       // truncated hi
  float r = x - __uint_as_float(u & 0xFFFF0000u);      // exact residual
  l = f2bf_rn(r);
}

__device__ inline float bf2f(unsigned short b) {
  return __uint_as_float(((uint32_t)b) << 16);
}

__device__ inline void gload_lds16(const void* g, void* l) {
  __builtin_amdgcn_global_load_lds((const __attribute__((address_space(1))) void*)g,
                                   (__attribute__((address_space(3))) void*)l, 16, 0, 0);
}

// ---------------- graph prep ----------------

__global__ void deg_count_kernel(const int* __restrict__ ei, int* __restrict__ deg, int E) {
  int e = blockIdx.x * 256 + threadIdx.x;
  if (e < E) atomicAdd(&deg[ei[E + e]], 1);
}

// single block, 1024 threads: exclusive scan of deg -> rowptr, cursor
__global__ void scan_kernel(const int* __restrict__ deg, int* __restrict__ rowptr,
                            int* __restrict__ cursor, int n) {
  __shared__ int wsum[16];
  int t = threadIdx.x;
  int chunk = (n + 1023) >> 10;
  int lo = min(t * chunk, n), hi = min(lo + chunk, n);
  int s = 0;
  for (int i = lo; i < hi; ++i) s += deg[i];
  int lane = t & 63, w = t >> 6;
  int v = s;
#pragma unroll
  for (int off = 1; off < 64; off <<= 1) {
    int u = __shfl_up(v, off);
    if (lane >= off) v += u;
  }
  if (lane == 63) wsum[w] = v;
  __syncthreads();
  if (t == 0) {
    int acc = 0;
#pragma unroll
    for (int i = 0; i < 16; ++i) { int x = wsum[i]; wsum[i] = acc; acc += x; }
  }
  __syncthreads();
  int excl = v - s + wsum[w];
  for (int i = lo; i < hi; ++i) {
    rowptr[i] = excl; cursor[i] = excl; excl += deg[i];
  }
  if (t == 1023) rowptr[n] = excl;
}

__global__ void scatter_kernel(const int* __restrict__ ei, int* __restrict__ cursor,
                               int* __restrict__ csr_src, int* __restrict__ csr_dst,
                               int* __restrict__ csr_eid, int E) {
  int e = blockIdx.x * 256 + threadIdx.x;
  if (e >= E) return;
  int d = ei[E + e];
  int pos = atomicAdd(&cursor[d], 1);
  csr_src[pos] = ei[e];
  csr_dst[pos] = d;
  csr_eid[pos] = e;
}

// edge_attr -> CSR order (one float4 per thread)
__global__ void permute_ea_kernel(const int* __restrict__ csr_eid,
                                  const float* __restrict__ edge_attr,
                                  float* __restrict__ ea_csr, int E) {
  int gid = blockIdx.x * 256 + threadIdx.x;
  if (gid >= E * 8) return;
  int p = gid >> 3, q = gid & 7;
  int e = csr_eid[p];
  ((float4*)ea_csr)[(size_t)p * 8 + q] = ((const float4*)edge_attr)[(size_t)e * 8 + q];
}

// loop_attr[n][d] = mean over incoming edges (contiguous CSR reads)
__global__ void loop_attr_kernel(const int* __restrict__ rowptr,
                                 const float* __restrict__ ea_csr,
                                 float* __restrict__ loop_attr, int N) {
  int n = blockIdx.x * 8 + (threadIdx.x >> 5);
  int lane = threadIdx.x & 31;
  if (n >= N) return;
  int r0 = rowptr[n], r1 = rowptr[n + 1];
  float s = 0.f;
  for (int p = r0; p < r1; ++p)
    s += ea_csr[(size_t)p * EDD + lane];
  float dv = fmaxf((float)(r1 - r0), 1.f);
  loop_attr[(size_t)n * EDD + lane] = s / dv;
}

// ---------------- conversions ----------------

__global__ void split_f32_kernel(const float* __restrict__ in, unsigned short* __restrict__ hi,
                                 unsigned short* __restrict__ lo, int n4) {
  int i = blockIdx.x * 256 + threadIdx.x;
  if (i >= n4) return;
  float4 v = ((const float4*)in)[i];
  ushort4 h, l;
  split2(v.x, h.x, l.x); split2(v.y, h.y, l.y);
  split2(v.z, h.z, l.z); split2(v.w, h.w, l.w);
  ((ushort4*)hi)[i] = h;
  ((ushort4*)lo)[i] = l;
}

// W [K][1024] f32 -> Bt_hi/lo [1024][K] bf16 (transposed, K-contiguous)
__global__ void split_transpose_kernel(const float* __restrict__ W,
                                       unsigned short* __restrict__ Bthi,
                                       unsigned short* __restrict__ Btlo, int K) {
  __shared__ float tile[32][33];
  int bn = blockIdx.x * 32;
  int bk = blockIdx.y * 32;
  int tx = threadIdx.x & 31, ty = threadIdx.x >> 5;
  for (int r = ty; r < 32; r += 8)
    tile[r][tx] = W[(size_t)(bk + r) * 1024 + bn + tx];
  __syncthreads();
  for (int r = ty; r < 32; r += 8) {
    float v = tile[tx][r];
    unsigned short h, l;
    split2(v, h, l);
    Bthi[(size_t)(bn + r) * K + bk + tx] = h;
    Btlo[(size_t)(bn + r) * K + bk + tx] = l;
  }
}

// ---------------- GEMM1: 3-product split + fused a_s/a_d epilogue -----------

__global__ __launch_bounds__(256) void gemm_mfma_split_kernel(
    const unsigned short* __restrict__ Ahi, const unsigned short* __restrict__ Alo,
    const unsigned short* __restrict__ Bthi, const unsigned short* __restrict__ Btlo,
    unsigned short* __restrict__ Cbf, float* __restrict__ a_s, float* __restrict__ a_d,
    const float* __restrict__ att_s, const float* __restrict__ att_d, int M, int K) {
  __shared__ __align__(16) unsigned short lds[4 * 128 * 32];
  __shared__ float redS[128][2];
  __shared__ float redD[128][2];
  unsigned short* As_hi = lds;
  unsigned short* As_lo = lds + 4096;
  unsigned short* Bs_hi = lds + 8192;
  unsigned short* Bs_lo = lds + 12288;
  const int t = threadIdx.x;
  const int lane = t & 63;
  const int wid = t >> 6;
  const int wr = wid >> 1, wc = wid & 1;
  const int m0 = blockIdx.y * 128;
  const int n0 = blockIdx.x * 128;
  const int hb = blockIdx.x;

  const int srow = lane >> 2;
  const int sg = lane & 3;

  f32x4 acc[4][4] = {};

  for (int k0 = 0; k0 < K; k0 += 32) {
    __syncthreads();
#pragma unroll
    for (int q = 0; q < 2; ++q) {
      int rb = wid * 32 + q * 16;
      int row = rb + srow;
      int gsrc = sg ^ ((row >> 1) & 3);
      size_t ga = (size_t)(m0 + row) * K + k0 + gsrc * 8;
      size_t gb = (size_t)(n0 + row) * K + k0 + gsrc * 8;
      gload_lds16(Ahi + ga, As_hi + rb * 32);
      gload_lds16(Alo + ga, As_lo + rb * 32);
      gload_lds16(Bthi + gb, Bs_hi + rb * 32);
      gload_lds16(Btlo + gb, Bs_lo + rb * 32);
    }
    __syncthreads();

    bf16x8 ah[4], al[4];
#pragma unroll
    for (int i = 0; i < 4; ++i) {
      int rowa = wr * 64 + i * 16 + (lane & 15);
      int offa = rowa * 32 + ((((lane >> 4) ^ ((rowa >> 1) & 3))) * 8);
      ah[i] = *(const bf16x8*)(As_hi + offa);
      al[i] = *(const bf16x8*)(As_lo + offa);
    }
#pragma unroll
    for (int j = 0; j < 4; ++j) {
      int rowb = wc * 64 + j * 16 + (lane & 15);
      int offb = rowb * 32 + ((((lane >> 4) ^ ((rowb >> 1) & 3))) * 8);
      bf16x8 bh = *(const bf16x8*)(Bs_hi + offb);
      bf16x8 bl = *(const bf16x8*)(Bs_lo + offb);
#pragma unroll
      for (int i = 0; i < 4; ++i) {
        acc[i][j] = __builtin_amdgcn_mfma_f32_16x16x32_bf16(ah[i], bh, acc[i][j], 0, 0, 0);
        acc[i][j] = __builtin_amdgcn_mfma_f32_16x16x32_bf16(ah[i], bl, acc[i][j], 0, 0, 0);
        acc[i][j] = __builtin_amdgcn_mfma_f32_16x16x32_bf16(al[i], bh, acc[i][j], 0, 0, 0);
      }
    }
  }

  float as_v[4], ad_v[4];
#pragma unroll
  for (int j = 0; j < 4; ++j) {
    int c = n0 + wc * 64 + j * 16 + (lane & 15);
    as_v[j] = att_s[c];
    ad_v[j] = att_d[c];
  }

#pragma unroll
  for (int i = 0; i < 4; ++i) {
#pragma unroll
    for (int r = 0; r < 4; ++r) {
      float sA = 0.f, sD = 0.f;
#pragma unroll
      for (int j = 0; j < 4; ++j) {
        sA = fmaf(acc[i][j][r], as_v[j], sA);
        sD = fmaf(acc[i][j][r], ad_v[j], sD);
      }
#pragma unroll
      for (int mask = 1; mask <= 8; mask <<= 1) {
        sA += __shfl_xor(sA, mask);
        sD += __shfl_xor(sD, mask);
      }
      if ((lane & 15) == 0) {
        int ml = wr * 64 + i * 16 + (lane >> 4) * 4 + r;
        redS[ml][wc] = sA;
        redD[ml][wc] = sD;
      }
      int m = m0 + wr * 64 + i * 16 + (lane >> 4) * 4 + r;
      if (m < M) {
#pragma unroll
        for (int j = 0; j < 4; ++j) {
          int n = n0 + wc * 64 + j * 16 + (lane & 15);
          Cbf[(size_t)m * 1024 + n] = f2bf_rn(acc[i][j][r]);
        }
      }
    }
  }
  __syncthreads();
  if (t < 128) {
    int m = m0 + t;
    if (m < M) {
      a_s[(size_t)m * 8 + hb] = redS[t][0] + redS[t][1];
      a_d[(size_t)m * 8 + hb] = redD[t][0] + redD[t][1];
    }
  }
}

// ---------------- GEMM2: 2-product (A single bf16, B hi/lo) ----------------

__global__ __launch_bounds__(256) void gemm_mfma_a1b2_kernel(
    const unsigned short* __restrict__ Abf,
    const unsigned short* __restrict__ Bthi, const unsigned short* __restrict__ Btlo,
    unsigned short* __restrict__ Cbf, float* __restrict__ a_s, float* __restrict__ a_d,
    const float* __restrict__ att_s, const float* __restrict__ att_d, int M, int K) {
  __shared__ __align__(16) unsigned short lds[3 * 128 * 32];
  __shared__ float redS[128][2];
  __shared__ float redD[128][2];
  unsigned short* As = lds;
  unsigned short* Bs_hi = lds + 4096;
  unsigned short* Bs_lo = lds + 8192;
  const int t = threadIdx.x;
  const int lane = t & 63;
  const int wid = t >> 6;
  const int wr = wid >> 1, wc = wid & 1;
  const int m0 = blockIdx.y * 128;
  const int n0 = blockIdx.x * 128;
  const int hb = blockIdx.x;

  const int srow = lane >> 2;
  const int sg = lane & 3;

  f32x4 acc[4][4] = {};

  for (int k0 = 0; k0 < K; k0 += 32) {
    __syncthreads();
#pragma unroll
    for (int q = 0; q < 2; ++q) {
      int rb = wid * 32 + q * 16;
      int row = rb + srow;
      int gsrc = sg ^ ((row >> 1) & 3);
      size_t ga = (size_t)(m0 + row) * K + k0 + gsrc * 8;
      size_t gb = (size_t)(n0 + row) * K + k0 + gsrc * 8;
      gload_lds16(Abf + ga, As + rb * 32);
      gload_lds16(Bthi + gb, Bs_hi + rb * 32);
      gload_lds16(Btlo + gb, Bs_lo + rb * 32);
    }
    __syncthreads();

    bf16x8 ah[4];
#pragma unroll
    for (int i = 0; i < 4; ++i) {
      int rowa = wr * 64 + i * 16 + (lane & 15);
      int offa = rowa * 32 + ((((lane >> 4) ^ ((rowa >> 1) & 3))) * 8);
      ah[i] = *(const bf16x8*)(As + offa);
    }
#pragma unroll
    for (int j = 0; j < 4; ++j) {
      int rowb = wc * 64 + j * 16 + (lane & 15);
      int offb = rowb * 32 + ((((lane >> 4) ^ ((rowb >> 1) & 3))) * 8);
      bf16x8 bh = *(const bf16x8*)(Bs_hi + offb);
      bf16x8 bl = *(const bf16x8*)(Bs_lo + offb);
#pragma unroll
      for (int i = 0; i < 4; ++i) {
        acc[i][j] = __builtin_amdgcn_mfma_f32_16x16x32_bf16(ah[i], bh, acc[i][j], 0, 0, 0);
        acc[i][j] = __builtin_amdgcn_mfma_f32_16x16x32_bf16(ah[i], bl, acc[i][j], 0, 0, 0);
      }
    }
  }

  float as_v[4], ad_v[4];
#pragma unroll
  for (int j = 0; j < 4; ++j) {
    int c = n0 + wc * 64 + j * 16 + (lane & 15);
    as_v[j] = att_s[c];
    ad_v[j] = att_d[c];
  }

#pragma unroll
  for (int i = 0; i < 4; ++i) {
#pragma unroll
    for (int r = 0; r < 4; ++r) {
      float sA = 0.f, sD = 0.f;
#pragma unroll
      for (int j = 0; j < 4; ++j) {
        sA = fmaf(acc[i][j][r], as_v[j], sA);
        sD = fmaf(acc[i][j][r], ad_v[j], sD);
      }
#pragma unroll
      for (int mask = 1; mask <= 8; mask <<= 1) {
        sA += __shfl_xor(sA, mask);
        sD += __shfl_xor(sD, mask);
      }
      if ((lane & 15) == 0) {
        int ml = wr * 64 + i * 16 + (lane >> 4) * 4 + r;
        redS[ml][wc] = sA;
        redD[ml][wc] = sD;
      }
      int m = m0 + wr * 64 + i * 16 + (lane >> 4) * 4 + r;
      if (m < M) {
#pragma unroll
        for (int j = 0; j < 4; ++j) {
          int n = n0 + wc * 64 + j * 16 + (lane & 15);
          Cbf[(size_t)m * 1024 + n] = f2bf_rn(acc[i][j][r]);
        }
      }
    }
  }
  __syncthreads();
  if (t < 128) {
    int m = m0 + t;
    if (m < M) {
      a_s[(size_t)m * 8 + hb] = redS[t][0] + redS[t][1];
      a_d[(size_t)m * 8 + hb] = redD[t][0] + redD[t][1];
    }
  }
}

// ---------------- attention scalars ----------------

__global__ void ve_kernel(const float* __restrict__ We, const float* __restrict__ att_e,
                          float* __restrict__ Ve) {
  int t = threadIdx.x;  // 256
  int d = t >> 3, h = t & 7;
  float s = 0.f;
  for (int c = 0; c < 128; ++c) s = fmaf(We[d * 1024 + h * 128 + c], att_e[h * 128 + c], s);
  Ve[t] = s;
}

// raw alpha (leaky_relu) in CSR order; self-loop alphas separate.
__global__ __launch_bounds__(256) void edge_alpha_kernel(
    const int* __restrict__ csr_src, const int* __restrict__ csr_dst,
    const float* __restrict__ ea_csr, const float* __restrict__ loop_attr,
    const float* __restrict__ a_s, const float* __restrict__ a_d,
    const float* __restrict__ Ve,
    float* __restrict__ alpha_csr, float* __restrict__ alpha_self, int E, int n) {
  __shared__ float sVe[EDD][8];
  int t = threadIdx.x;
  sVe[t >> 3][t & 7] = Ve[t];
  __syncthreads();
  int idx = blockIdx.x * 256 + t;
  if (idx >= E + n) return;
  int s, d;
  const float* ea;
  float* outp;
  if (idx < E) {
    s = csr_src[idx]; d = csr_dst[idx];
    ea = ea_csr + (size_t)idx * EDD;
    outp = alpha_csr + (size_t)idx * 8;
  } else {
    s = d = idx - E;
    ea = loop_attr + (size_t)(idx - E) * EDD;
    outp = alpha_self + (size_t)(idx - E) * 8;
  }
  float ae[8] = {0.f, 0.f, 0.f, 0.f, 0.f, 0.f, 0.f, 0.f};
#pragma unroll
  for (int k = 0; k < EDD; k += 4) {
    float4 v = *(const float4*)&ea[k];
#pragma unroll
    for (int h = 0; h < 8; ++h) {
      ae[h] = fmaf(v.x, sVe[k][h], ae[h]);
      ae[h] = fmaf(v.y, sVe[k + 1][h], ae[h]);
      ae[h] = fmaf(v.z, sVe[k + 2][h], ae[h]);
      ae[h] = fmaf(v.w, sVe[k + 3][h], ae[h]);
    }
  }
#pragma unroll
  for (int h = 0; h < 8; ++h) {
    float a = a_s[(size_t)s * 8 + h] + a_d[(size_t)d * 8 + h] + ae[h];
    outp[h] = (a > 0.f) ? a : 0.2f * a;
  }
}

// ---------------- softmax weights (in-place over alpha_csr) ----------------

__global__ __launch_bounds__(256) void sm_weights_kernel(
    float* __restrict__ alpha_csr, const float* __restrict__ alpha_self,
    float* __restrict__ pself, const int* __restrict__ rowptr, int N) {
  int n = blockIdx.x * 4 + (threadIdx.x >> 6);
  int lane = threadIdx.x & 63;
  if (n >= N) return;
  int r0 = rowptr[n], deg = rowptr[n + 1] - r0;
  int h = lane & 7, slot = lane >> 3;
  float m = -1e30f, s = 0.f;
  for (int i = slot; i < deg; i += 8) {
    float a = alpha_csr[(size_t)(r0 + i) * 8 + h];
    if (a <= m) {
      s += __expf(a - m);
    } else {
      s = s * __expf(m - a) + 1.f;
      m = a;
    }
  }
#pragma unroll
  for (int mask = 8; mask < 64; mask <<= 1) {
    float mo = __shfl_xor(m, mask);
    float so = __shfl_xor(s, mask);
    float mn = fmaxf(m, mo);
    s = s * __expf(m - mn) + so * __expf(mo - mn);
    m = mn;
  }
  float aself = alpha_self[(size_t)n * 8 + h];
  float mn = fmaxf(m, aself);
  s = s * __expf(m - mn) + __expf(aself - mn);
  float inv = 1.f / (s + 1e-16f);
  if (lane < 8) pself[(size_t)n * 8 + lane] = __expf(aself - mn) * inv;
  for (int idx = lane; idx < deg * 8; idx += 64) {
    size_t p = (size_t)(r0 + (idx >> 3)) * 8 + h;
    alpha_csr[p] = __expf(alpha_csr[p] - mn) * inv;
  }
}

// ---------------- aggregation: block-per-node, bf16 row gather --------------
// LAYER==1: write relu(agg+b1) as single bf16 (feeds 2-product GEMM2)
// LAYER==2: write mean_h(agg)+b2 to f32 out

template <int LAYER>
__global__ __launch_bounds__(256) void agg_gather_kernel(
    const unsigned short* __restrict__ xbf, const float* __restrict__ pw,
    const float* __restrict__ pself, const int* __restrict__ rowptr,
    const int* __restrict__ csr_src, const float* __restrict__ bias,
    unsigned short* __restrict__ obf, float* __restrict__ outp, int N) {
  int n = blockIdx.x;
  int t = threadIdx.x;
  int h = t >> 5;
  __shared__ int ls[64];
  __shared__ float pws[64 * 8];
  __shared__ float red[256][4];
  int r0 = rowptr[n];
  int deg = rowptr[n + 1] - r0;
  const ushort4* xv = (const ushort4*)xbf;
  float wself = pself[(size_t)n * 8 + h];
  ushort4 sv = xv[(size_t)n * 256 + t];
  float ax = wself * bf2f(sv.x), ay = wself * bf2f(sv.y);
  float az = wself * bf2f(sv.z), aw = wself * bf2f(sv.w);
  for (int base = 0; base < deg; base += 64) {
    int cnt = min(64, deg - base);
    if (t < cnt) ls[t] = csr_src[r0 + base + t];
    for (int idx = t; idx < cnt * 8; idx += 256)
      pws[idx] = pw[(size_t)(r0 + base) * 8 + idx];
    __syncthreads();
#pragma unroll 4
    for (int j = 0; j < cnt; ++j) {
      float w = pws[j * 8 + h];
      ushort4 u = xv[(size_t)ls[j] * 256 + t];
      ax = fmaf(w, bf2f(u.x), ax);
      ay = fmaf(w, bf2f(u.y), ay);
      az = fmaf(w, bf2f(u.z), az);
      aw = fmaf(w, bf2f(u.w), aw);
    }
    __syncthreads();
  }
  if (LAYER == 1) {
    float4 b = ((const float4*)bias)[t];
    ushort4 o4;
    o4.x = f2bf_rn(fmaxf(ax + b.x, 0.f));
    o4.y = f2bf_rn(fmaxf(ay + b.y, 0.f));
    o4.z = f2bf_rn(fmaxf(az + b.z, 0.f));
    o4.w = f2bf_rn(fmaxf(aw + b.w, 0.f));
    ((ushort4*)obf)[(size_t)n * 256 + t] = o4;
  } else {
    red[t][0] = ax; red[t][1] = ay; red[t][2] = az; red[t][3] = aw;
    __syncthreads();
    if (t < 32) {
      float sx = 0.f, sy = 0.f, sz = 0.f, sw = 0.f;
#pragma unroll
      for (int k = 0; k < 8; ++k) {
        sx += red[t + 32 * k][0];
        sy += red[t + 32 * k][1];
        sz += red[t + 32 * k][2];
        sw += red[t + 32 * k][3];
      }
      float4 b = ((const float4*)bias)[t];
      float4 o;
      o.x = sx * 0.125f + b.x;
      o.y = sy * 0.125f + b.y;
      o.z = sz * 0.125f + b.z;
      o.w = sw * 0.125f + b.w;
      ((float4*)outp)[(size_t)n * 32 + t] = o;
    }
  }
}

// ---------------- launch ----------------

extern "C" void kernel_launch(void* const* d_in, const int* in_sizes, int n_in,
                              void* d_out, int out_size, void* d_ws, size_t ws_size,
                              hipStream_t stream) {
  const float* x        = (const float*)d_in[0];
  const int*   ei       = (const int*)d_in[1];
  const float* edge_attr= (const float*)d_in[2];
  const float* W1       = (const float*)d_in[3];
  const float* We1      = (const float*)d_in[4];
  const float* as1      = (const float*)d_in[5];
  const float* ad1      = (const float*)d_in[6];
  const float* ae1      = (const float*)d_in[7];
  const float* b1       = (const float*)d_in[8];
  const float* W2       = (const float*)d_in[9];
  const float* We2      = (const float*)d_in[10];
  const float* as2      = (const float*)d_in[11];
  const float* ad2      = (const float*)d_in[12];
  const float* ae2      = (const float*)d_in[13];
  const float* b2       = (const float*)d_in[14];
  float* out = (float*)d_out;

  const int N = in_sizes[0] / 128;   // 10000 nodes
  const int E = in_sizes[2] / EDD;   // 160000 edges
  const int Mpad = ((N + 127) / 128) * 128;  // 10112

  char* ws = (char*)d_ws;
  size_t off = 0;
  auto alloc = [&](size_t bytes) -> void* {
    void* p = ws + off;
    off = (off + bytes + 255) & ~(size_t)255;
    return p;
  };
  int*   deg       = (int*)alloc((size_t)N * 4);
  int*   rowptr    = (int*)alloc((size_t)(N + 1) * 4);
  int*   cursor    = (int*)alloc((size_t)N * 4);
  int*   csr_src   = (int*)alloc((size_t)E * 4);
  int*   csr_dst   = (int*)alloc((size_t)E * 4);
  int*   csr_eid   = (int*)alloc((size_t)E * 4);
  float* ea_csr    = (float*)alloc((size_t)E * EDD * 4);
  float* loop_attr = (float*)alloc((size_t)N * EDD * 4);
  float* a_s       = (float*)alloc((size_t)N * 8 * 4);
  float* a_d       = (float*)alloc((size_t)N * 8 * 4);
  float* Ve        = (float*)alloc(256 * 4);
  float* alpha_csr = (float*)alloc((size_t)E * 8 * 4);   // becomes pw after sm_weights
  float* alpha_self= (float*)alloc((size_t)N * 8 * 4);
  float* pself     = (float*)alloc((size_t)N * 8 * 4);
  unsigned short* xh1bf = (unsigned short*)alloc((size_t)N * 1024 * 2);
  unsigned short* xh2bf = (unsigned short*)alloc((size_t)N * 1024 * 2);
  unsigned short* xhi   = (unsigned short*)alloc((size_t)Mpad * 128 * 2);
  unsigned short* xlo   = (unsigned short*)alloc((size_t)Mpad * 128 * 2);
  unsigned short* Bt1hi = (unsigned short*)alloc((size_t)1024 * 128 * 2);
  unsigned short* Bt1lo = (unsigned short*)alloc((size_t)1024 * 128 * 2);
  unsigned short* Bt2hi = (unsigned short*)alloc((size_t)1024 * 1024 * 2);
  unsigned short* Bt2lo = (unsigned short*)alloc((size_t)1024 * 1024 * 2);
  unsigned short* h1bf  = (unsigned short*)alloc((size_t)Mpad * 1024 * 2);
  (void)ws_size; (void)n_in; (void)out_size;

  hipMemsetAsync(deg, 0, (size_t)N * 4, stream);

  int gE = (E + 255) / 256;
  deg_count_kernel<<<gE, 256, 0, stream>>>(ei, deg, E);
  scan_kernel<<<1, 1024, 0, stream>>>(deg, rowptr, cursor, N);
  scatter_kernel<<<gE, 256, 0, stream>>>(ei, cursor, csr_src, csr_dst, csr_eid, E);
  permute_ea_kernel<<<(E * 8 + 255) / 256, 256, 0, stream>>>(csr_eid, edge_attr, ea_csr, E);
  loop_attr_kernel<<<(N + 7) / 8, 256, 0, stream>>>(rowptr, ea_csr, loop_attr, N);

  split_f32_kernel<<<(N * 128 / 4 + 255) / 256, 256, 0, stream>>>(x, xhi, xlo, N * 128 / 4);
  split_transpose_kernel<<<dim3(32, 4), 256, 0, stream>>>(W1, Bt1hi, Bt1lo, 128);
  split_transpose_kernel<<<dim3(32, 32), 256, 0, stream>>>(W2, Bt2hi, Bt2lo, 1024);

  dim3 ggrid(8, Mpad / 128);
  int gEA = (E + N + 255) / 256;
  int gSM = (N + 3) / 4;

  // ---- layer 1 ----
  gemm_mfma_split_kernel<<<ggrid, 256, 0, stream>>>(xhi, xlo, Bt1hi, Bt1lo, xh1bf,
                                                    a_s, a_d, as1, ad1, N, 128);
  ve_kernel<<<1, 256, 0, stream>>>(We1, ae1, Ve);
  edge_alpha_kernel<<<gEA, 256, 0, stream>>>(csr_src, csr_dst, ea_csr, loop_attr,
                                             a_s, a_d, Ve, alpha_csr, alpha_self, E, N);
  sm_weights_kernel<<<gSM, 256, 0, stream>>>(alpha_csr, alpha_self, pself, rowptr, N);
  agg_gather_kernel<1><<<N, 256, 0, stream>>>(xh1bf, alpha_csr, pself, rowptr, csr_src,
                                              b1, h1bf, nullptr, N);

  // ---- layer 2 ----
  gemm_mfma_a1b2_kernel<<<ggrid, 256, 0, stream>>>(h1bf, Bt2hi, Bt2lo, xh2bf,
                                                   a_s, a_d, as2, ad2, N, 1024);
  ve_kernel<<<1, 256, 0, stream>>>(We2, ae2, Ve);
  edge_alpha_kernel<<<gEA, 256, 0, stream>>>(csr_src, csr_dst, ea_csr, loop_attr,
                                             a_s, a_d, Ve, alpha_csr, alpha_self, E, N);
  sm_weights_kernel<<<gSM, 256, 0, stream>>>(alpha_csr, alpha_self, pself, rowptr, N);
  agg_gather_kernel<2><<<N, 256, 0, stream>>>(xh2bf, alpha_csr, pself, rowptr, csr_src,
                                              b2, nullptr, out, N);
}

// Round 7
// 299.553 us; speedup vs baseline: 2.0417x; 1.0539x over previous
//
#include <hip/hip_runtime.h>
#include <hip/hip_bf16.h>
#include <cstdint>
#include <cstddef>

// TwoLayerGAT on MI355X — round 7:
//  - GEMM2 software-pipelined: 3 LDS buffers, 2-deep global_load_lds prefetch,
//    counted s_waitcnt vmcnt(6) + raw s_barrier (one barrier per K-step, loads
//    stay in flight across it). Attacks the per-step vmcnt(0) drain that left
//    round-6's GEMM2 latency-bound at 16.7% MfmaUtil.
//  - everything else unchanged from round 6.

#define EDD 32

typedef __attribute__((ext_vector_type(4))) float f32x4;
typedef __attribute__((ext_vector_type(8))) short bf16x8;

__device__ inline unsigned short f2bf_rn(float f) {
  uint32_t u = __float_as_uint(f);
  return (unsigned short)((u + 0x7FFFu + ((u >> 16) & 1u)) >> 16);
}

__device__ inline void split2(float x, unsigned short& h, unsigned short& l) {
  uint32_t u = __float_as_uint(x);
  h = (unsigned short)(u >> 16);                       // truncated hi
  float r = x - __uint_as_float(u & 0xFFFF0000u);      // exact residual
  l = f2bf_rn(r);
}

__device__ inline float bf2f(unsigned short b) {
  return __uint_as_float(((uint32_t)b) << 16);
}

__device__ inline void gload_lds16(const void* g, void* l) {
  __builtin_amdgcn_global_load_lds((const __attribute__((address_space(1))) void*)g,
                                   (__attribute__((address_space(3))) void*)l, 16, 0, 0);
}

// ---------------- graph prep ----------------

__global__ void deg_count_kernel(const int* __restrict__ ei, int* __restrict__ deg, int E) {
  int e = blockIdx.x * 256 + threadIdx.x;
  if (e < E) atomicAdd(&deg[ei[E + e]], 1);
}

// single block, 1024 threads: exclusive scan of deg -> rowptr, cursor
__global__ void scan_kernel(const int* __restrict__ deg, int* __restrict__ rowptr,
                            int* __restrict__ cursor, int n) {
  __shared__ int wsum[16];
  int t = threadIdx.x;
  int chunk = (n + 1023) >> 10;
  int lo = min(t * chunk, n), hi = min(lo + chunk, n);
  int s = 0;
  for (int i = lo; i < hi; ++i) s += deg[i];
  int lane = t & 63, w = t >> 6;
  int v = s;
#pragma unroll
  for (int off = 1; off < 64; off <<= 1) {
    int u = __shfl_up(v, off);
    if (lane >= off) v += u;
  }
  if (lane == 63) wsum[w] = v;
  __syncthreads();
  if (t == 0) {
    int acc = 0;
#pragma unroll
    for (int i = 0; i < 16; ++i) { int x = wsum[i]; wsum[i] = acc; acc += x; }
  }
  __syncthreads();
  int excl = v - s + wsum[w];
  for (int i = lo; i < hi; ++i) {
    rowptr[i] = excl; cursor[i] = excl; excl += deg[i];
  }
  if (t == 1023) rowptr[n] = excl;
}

__global__ void scatter_kernel(const int* __restrict__ ei, int* __restrict__ cursor,
                               int* __restrict__ csr_src, int* __restrict__ csr_dst,
                               int* __restrict__ csr_eid, int E) {
  int e = blockIdx.x * 256 + threadIdx.x;
  if (e >= E) return;
  int d = ei[E + e];
  int pos = atomicAdd(&cursor[d], 1);
  csr_src[pos] = ei[e];
  csr_dst[pos] = d;
  csr_eid[pos] = e;
}

// edge_attr -> CSR order (one float4 per thread)
__global__ void permute_ea_kernel(const int* __restrict__ csr_eid,
                                  const float* __restrict__ edge_attr,
                                  float* __restrict__ ea_csr, int E) {
  int gid = blockIdx.x * 256 + threadIdx.x;
  if (gid >= E * 8) return;
  int p = gid >> 3, q = gid & 7;
  int e = csr_eid[p];
  ((float4*)ea_csr)[(size_t)p * 8 + q] = ((const float4*)edge_attr)[(size_t)e * 8 + q];
}

// loop_attr[n][d] = mean over incoming edges (contiguous CSR reads)
__global__ void loop_attr_kernel(const int* __restrict__ rowptr,
                                 const float* __restrict__ ea_csr,
                                 float* __restrict__ loop_attr, int N) {
  int n = blockIdx.x * 8 + (threadIdx.x >> 5);
  int lane = threadIdx.x & 31;
  if (n >= N) return;
  int r0 = rowptr[n], r1 = rowptr[n + 1];
  float s = 0.f;
  for (int p = r0; p < r1; ++p)
    s += ea_csr[(size_t)p * EDD + lane];
  float dv = fmaxf((float)(r1 - r0), 1.f);
  loop_attr[(size_t)n * EDD + lane] = s / dv;
}

// ---------------- conversions ----------------

__global__ void split_f32_kernel(const float* __restrict__ in, unsigned short* __restrict__ hi,
                                 unsigned short* __restrict__ lo, int n4) {
  int i = blockIdx.x * 256 + threadIdx.x;
  if (i >= n4) return;
  float4 v = ((const float4*)in)[i];
  ushort4 h, l;
  split2(v.x, h.x, l.x); split2(v.y, h.y, l.y);
  split2(v.z, h.z, l.z); split2(v.w, h.w, l.w);
  ((ushort4*)hi)[i] = h;
  ((ushort4*)lo)[i] = l;
}

// W [K][1024] f32 -> Bt_hi/lo [1024][K] bf16 (transposed, K-contiguous)
__global__ void split_transpose_kernel(const float* __restrict__ W,
                                       unsigned short* __restrict__ Bthi,
                                       unsigned short* __restrict__ Btlo, int K) {
  __shared__ float tile[32][33];
  int bn = blockIdx.x * 32;
  int bk = blockIdx.y * 32;
  int tx = threadIdx.x & 31, ty = threadIdx.x >> 5;
  for (int r = ty; r < 32; r += 8)
    tile[r][tx] = W[(size_t)(bk + r) * 1024 + bn + tx];
  __syncthreads();
  for (int r = ty; r < 32; r += 8) {
    float v = tile[tx][r];
    unsigned short h, l;
    split2(v, h, l);
    Bthi[(size_t)(bn + r) * K + bk + tx] = h;
    Btlo[(size_t)(bn + r) * K + bk + tx] = l;
  }
}

// ---------------- GEMM1: 3-product split + fused a_s/a_d epilogue -----------

__global__ __launch_bounds__(256) void gemm_mfma_split_kernel(
    const unsigned short* __restrict__ Ahi, const unsigned short* __restrict__ Alo,
    const unsigned short* __restrict__ Bthi, const unsigned short* __restrict__ Btlo,
    unsigned short* __restrict__ Cbf, float* __restrict__ a_s, float* __restrict__ a_d,
    const float* __restrict__ att_s, const float* __restrict__ att_d, int M, int K) {
  __shared__ __align__(16) unsigned short lds[4 * 128 * 32];
  __shared__ float redS[128][2];
  __shared__ float redD[128][2];
  unsigned short* As_hi = lds;
  unsigned short* As_lo = lds + 4096;
  unsigned short* Bs_hi = lds + 8192;
  unsigned short* Bs_lo = lds + 12288;
  const int t = threadIdx.x;
  const int lane = t & 63;
  const int wid = t >> 6;
  const int wr = wid >> 1, wc = wid & 1;
  const int m0 = blockIdx.y * 128;
  const int n0 = blockIdx.x * 128;
  const int hb = blockIdx.x;

  const int srow = lane >> 2;
  const int sg = lane & 3;

  f32x4 acc[4][4] = {};

  for (int k0 = 0; k0 < K; k0 += 32) {
    __syncthreads();
#pragma unroll
    for (int q = 0; q < 2; ++q) {
      int rb = wid * 32 + q * 16;
      int row = rb + srow;
      int gsrc = sg ^ ((row >> 1) & 3);
      size_t ga = (size_t)(m0 + row) * K + k0 + gsrc * 8;
      size_t gb = (size_t)(n0 + row) * K + k0 + gsrc * 8;
      gload_lds16(Ahi + ga, As_hi + rb * 32);
      gload_lds16(Alo + ga, As_lo + rb * 32);
      gload_lds16(Bthi + gb, Bs_hi + rb * 32);
      gload_lds16(Btlo + gb, Bs_lo + rb * 32);
    }
    __syncthreads();

    bf16x8 ah[4], al[4];
#pragma unroll
    for (int i = 0; i < 4; ++i) {
      int rowa = wr * 64 + i * 16 + (lane & 15);
      int offa = rowa * 32 + ((((lane >> 4) ^ ((rowa >> 1) & 3))) * 8);
      ah[i] = *(const bf16x8*)(As_hi + offa);
      al[i] = *(const bf16x8*)(As_lo + offa);
    }
#pragma unroll
    for (int j = 0; j < 4; ++j) {
      int rowb = wc * 64 + j * 16 + (lane & 15);
      int offb = rowb * 32 + ((((lane >> 4) ^ ((rowb >> 1) & 3))) * 8);
      bf16x8 bh = *(const bf16x8*)(Bs_hi + offb);
      bf16x8 bl = *(const bf16x8*)(Bs_lo + offb);
#pragma unroll
      for (int i = 0; i < 4; ++i) {
        acc[i][j] = __builtin_amdgcn_mfma_f32_16x16x32_bf16(ah[i], bh, acc[i][j], 0, 0, 0);
        acc[i][j] = __builtin_amdgcn_mfma_f32_16x16x32_bf16(ah[i], bl, acc[i][j], 0, 0, 0);
        acc[i][j] = __builtin_amdgcn_mfma_f32_16x16x32_bf16(al[i], bh, acc[i][j], 0, 0, 0);
      }
    }
  }

  float as_v[4], ad_v[4];
#pragma unroll
  for (int j = 0; j < 4; ++j) {
    int c = n0 + wc * 64 + j * 16 + (lane & 15);
    as_v[j] = att_s[c];
    ad_v[j] = att_d[c];
  }

#pragma unroll
  for (int i = 0; i < 4; ++i) {
#pragma unroll
    for (int r = 0; r < 4; ++r) {
      float sA = 0.f, sD = 0.f;
#pragma unroll
      for (int j = 0; j < 4; ++j) {
        sA = fmaf(acc[i][j][r], as_v[j], sA);
        sD = fmaf(acc[i][j][r], ad_v[j], sD);
      }
#pragma unroll
      for (int mask = 1; mask <= 8; mask <<= 1) {
        sA += __shfl_xor(sA, mask);
        sD += __shfl_xor(sD, mask);
      }
      if ((lane & 15) == 0) {
        int ml = wr * 64 + i * 16 + (lane >> 4) * 4 + r;
        redS[ml][wc] = sA;
        redD[ml][wc] = sD;
      }
      int m = m0 + wr * 64 + i * 16 + (lane >> 4) * 4 + r;
      if (m < M) {
#pragma unroll
        for (int j = 0; j < 4; ++j) {
          int n = n0 + wc * 64 + j * 16 + (lane & 15);
          Cbf[(size_t)m * 1024 + n] = f2bf_rn(acc[i][j][r]);
        }
      }
    }
  }
  __syncthreads();
  if (t < 128) {
    int m = m0 + t;
    if (m < M) {
      a_s[(size_t)m * 8 + hb] = redS[t][0] + redS[t][1];
      a_d[(size_t)m * 8 + hb] = redD[t][0] + redD[t][1];
    }
  }
}

// ---------------- GEMM2: 2-product, 3-buffer pipelined -----------------------
// buf[k%3] read; buf[(k+2)%3] staged; vmcnt(6) + raw s_barrier per K-step.

__global__ __launch_bounds__(256) void gemm_a1b2_pipe_kernel(
    const unsigned short* __restrict__ Abf,
    const unsigned short* __restrict__ Bthi, const unsigned short* __restrict__ Btlo,
    unsigned short* __restrict__ Cbf, float* __restrict__ a_s, float* __restrict__ a_d,
    const float* __restrict__ att_s, const float* __restrict__ att_d, int M, int K) {
  __shared__ __align__(16) unsigned short lds[3 * 12288];  // 3 bufs x (A|Bhi|Blo) 8KB each
  __shared__ float redS[128][2];
  __shared__ float redD[128][2];
  const int t = threadIdx.x;
  const int lane = t & 63;
  const int wid = t >> 6;
  const int wr = wid >> 1, wc = wid & 1;
  const int m0 = blockIdx.y * 128;
  const int n0 = blockIdx.x * 128;
  const int hb = blockIdx.x;
  const int srow = lane >> 2;
  const int sg = lane & 3;
  const int nk = K >> 5;

  f32x4 acc[4][4] = {};

  // per-wave staging of one 32-K-step tile set into buffer b (6 gload_lds)
  auto stage = [&](int b, int k) {
    unsigned short* L = lds + b * 12288;
    int k0 = k * 32;
#pragma unroll
    for (int q = 0; q < 2; ++q) {
      int rb = wid * 32 + q * 16;
      int row = rb + srow;
      int gsrc = sg ^ ((row >> 1) & 3);
      size_t ga = (size_t)(m0 + row) * K + k0 + gsrc * 8;
      size_t gb = (size_t)(n0 + row) * K + k0 + gsrc * 8;
      gload_lds16(Abf + ga, L + rb * 32);
      gload_lds16(Bthi + gb, L + 4096 + rb * 32);
      gload_lds16(Btlo + gb, L + 8192 + rb * 32);
    }
  };

  // fragment LDS offsets (swizzled)
  int offa[4], offb[4];
#pragma unroll
  for (int i = 0; i < 4; ++i) {
    int rowa = wr * 64 + i * 16 + (lane & 15);
    offa[i] = rowa * 32 + (((lane >> 4) ^ ((rowa >> 1) & 3)) * 8);
    int rowb = wc * 64 + i * 16 + (lane & 15);
    offb[i] = rowb * 32 + (((lane >> 4) ^ ((rowb >> 1) & 3)) * 8);
  }

  // prologue: stage tiles 0 and 1; wait for tile 0 (6 newest stay in flight)
  stage(0, 0);
  stage(1, 1);
  asm volatile("s_waitcnt vmcnt(6)" ::: "memory");
  __builtin_amdgcn_s_barrier();
  __builtin_amdgcn_sched_barrier(0);

  int bcur = 0;
  for (int k = 0; k < nk; ++k) {
    unsigned short* L = lds + bcur * 12288;
    bf16x8 ah[4], bh[4], bl[4];
#pragma unroll
    for (int i = 0; i < 4; ++i) ah[i] = *(const bf16x8*)(L + offa[i]);
#pragma unroll
    for (int j = 0; j < 4; ++j) {
      bh[j] = *(const bf16x8*)(L + 4096 + offb[j]);
      bl[j] = *(const bf16x8*)(L + 8192 + offb[j]);
    }
    if (k + 2 < nk) {
      int bst = bcur + 2; if (bst >= 3) bst -= 3;
      stage(bst, k + 2);
    }
#pragma unroll
    for (int j = 0; j < 4; ++j)
#pragma unroll
      for (int i = 0; i < 4; ++i) {
        acc[i][j] = __builtin_amdgcn_mfma_f32_16x16x32_bf16(ah[i], bh[j], acc[i][j], 0, 0, 0);
        acc[i][j] = __builtin_amdgcn_mfma_f32_16x16x32_bf16(ah[i], bl[j], acc[i][j], 0, 0, 0);
      }
    if (k + 1 < nk) {
      if (k + 2 < nk) {
        asm volatile("s_waitcnt vmcnt(6)" ::: "memory");  // tile k+1 landed; k+2 in flight
      } else {
        asm volatile("s_waitcnt vmcnt(0)" ::: "memory");  // tail: drain
      }
      __builtin_amdgcn_s_barrier();
      __builtin_amdgcn_sched_barrier(0);
    }
    bcur = (bcur + 1 == 3) ? 0 : bcur + 1;
  }

  float as_v[4], ad_v[4];
#pragma unroll
  for (int j = 0; j < 4; ++j) {
    int c = n0 + wc * 64 + j * 16 + (lane & 15);
    as_v[j] = att_s[c];
    ad_v[j] = att_d[c];
  }

#pragma unroll
  for (int i = 0; i < 4; ++i) {
#pragma unroll
    for (int r = 0; r < 4; ++r) {
      float sA = 0.f, sD = 0.f;
#pragma unroll
      for (int j = 0; j < 4; ++j) {
        sA = fmaf(acc[i][j][r], as_v[j], sA);
        sD = fmaf(acc[i][j][r], ad_v[j], sD);
      }
#pragma unroll
      for (int mask = 1; mask <= 8; mask <<= 1) {
        sA += __shfl_xor(sA, mask);
        sD += __shfl_xor(sD, mask);
      }
      if ((lane & 15) == 0) {
        int ml = wr * 64 + i * 16 + (lane >> 4) * 4 + r;
        redS[ml][wc] = sA;
        redD[ml][wc] = sD;
      }
      int m = m0 + wr * 64 + i * 16 + (lane >> 4) * 4 + r;
      if (m < M) {
#pragma unroll
        for (int j = 0; j < 4; ++j) {
          int n = n0 + wc * 64 + j * 16 + (lane & 15);
          Cbf[(size_t)m * 1024 + n] = f2bf_rn(acc[i][j][r]);
        }
      }
    }
  }
  __syncthreads();
  if (t < 128) {
    int m = m0 + t;
    if (m < M) {
      a_s[(size_t)m * 8 + hb] = redS[t][0] + redS[t][1];
      a_d[(size_t)m * 8 + hb] = redD[t][0] + redD[t][1];
    }
  }
}

// ---------------- attention scalars ----------------

__global__ void ve_kernel(const float* __restrict__ We, const float* __restrict__ att_e,
                          float* __restrict__ Ve) {
  int t = threadIdx.x;  // 256
  int d = t >> 3, h = t & 7;
  float s = 0.f;
  for (int c = 0; c < 128; ++c) s = fmaf(We[d * 1024 + h * 128 + c], att_e[h * 128 + c], s);
  Ve[t] = s;
}

// raw alpha (leaky_relu) in CSR order; self-loop alphas separate.
__global__ __launch_bounds__(256) void edge_alpha_kernel(
    const int* __restrict__ csr_src, const int* __restrict__ csr_dst,
    const float* __restrict__ ea_csr, const float* __restrict__ loop_attr,
    const float* __restrict__ a_s, const float* __restrict__ a_d,
    const float* __restrict__ Ve,
    float* __restrict__ alpha_csr, float* __restrict__ alpha_self, int E, int n) {
  __shared__ float sVe[EDD][8];
  int t = threadIdx.x;
  sVe[t >> 3][t & 7] = Ve[t];
  __syncthreads();
  int idx = blockIdx.x * 256 + t;
  if (idx >= E + n) return;
  int s, d;
  const float* ea;
  float* outp;
  if (idx < E) {
    s = csr_src[idx]; d = csr_dst[idx];
    ea = ea_csr + (size_t)idx * EDD;
    outp = alpha_csr + (size_t)idx * 8;
  } else {
    s = d = idx - E;
    ea = loop_attr + (size_t)(idx - E) * EDD;
    outp = alpha_self + (size_t)(idx - E) * 8;
  }
  float ae[8] = {0.f, 0.f, 0.f, 0.f, 0.f, 0.f, 0.f, 0.f};
#pragma unroll
  for (int k = 0; k < EDD; k += 4) {
    float4 v = *(const float4*)&ea[k];
#pragma unroll
    for (int h = 0; h < 8; ++h) {
      ae[h] = fmaf(v.x, sVe[k][h], ae[h]);
      ae[h] = fmaf(v.y, sVe[k + 1][h], ae[h]);
      ae[h] = fmaf(v.z, sVe[k + 2][h], ae[h]);
      ae[h] = fmaf(v.w, sVe[k + 3][h], ae[h]);
    }
  }
#pragma unroll
  for (int h = 0; h < 8; ++h) {
    float a = a_s[(size_t)s * 8 + h] + a_d[(size_t)d * 8 + h] + ae[h];
    outp[h] = (a > 0.f) ? a : 0.2f * a;
  }
}

// ---------------- softmax weights (in-place over alpha_csr) ----------------

__global__ __launch_bounds__(256) void sm_weights_kernel(
    float* __restrict__ alpha_csr, const float* __restrict__ alpha_self,
    float* __restrict__ pself, const int* __restrict__ rowptr, int N) {
  int n = blockIdx.x * 4 + (threadIdx.x >> 6);
  int lane = threadIdx.x & 63;
  if (n >= N) return;
  int r0 = rowptr[n], deg = rowptr[n + 1] - r0;
  int h = lane & 7, slot = lane >> 3;
  float m = -1e30f, s = 0.f;
  for (int i = slot; i < deg; i += 8) {
    float a = alpha_csr[(size_t)(r0 + i) * 8 + h];
    if (a <= m) {
      s += __expf(a - m);
    } else {
      s = s * __expf(m - a) + 1.f;
      m = a;
    }
  }
#pragma unroll
  for (int mask = 8; mask < 64; mask <<= 1) {
    float mo = __shfl_xor(m, mask);
    float so = __shfl_xor(s, mask);
    float mn = fmaxf(m, mo);
    s = s * __expf(m - mn) + so * __expf(mo - mn);
    m = mn;
  }
  float aself = alpha_self[(size_t)n * 8 + h];
  float mn = fmaxf(m, aself);
  s = s * __expf(m - mn) + __expf(aself - mn);
  float inv = 1.f / (s + 1e-16f);
  if (lane < 8) pself[(size_t)n * 8 + lane] = __expf(aself - mn) * inv;
  for (int idx = lane; idx < deg * 8; idx += 64) {
    size_t p = (size_t)(r0 + (idx >> 3)) * 8 + h;
    alpha_csr[p] = __expf(alpha_csr[p] - mn) * inv;
  }
}

// ---------------- aggregation: block-per-node, bf16 row gather --------------
// LAYER==1: write relu(agg+b1) as single bf16 (feeds 2-product GEMM2)
// LAYER==2: write mean_h(agg)+b2 to f32 out

template <int LAYER>
__global__ __launch_bounds__(256) void agg_gather_kernel(
    const unsigned short* __restrict__ xbf, const float* __restrict__ pw,
    const float* __restrict__ pself, const int* __restrict__ rowptr,
    const int* __restrict__ csr_src, const float* __restrict__ bias,
    unsigned short* __restrict__ obf, float* __restrict__ outp, int N) {
  int n = blockIdx.x;
  int t = threadIdx.x;
  int h = t >> 5;
  __shared__ int ls[64];
  __shared__ float pws[64 * 8];
  __shared__ float red[256][4];
  int r0 = rowptr[n];
  int deg = rowptr[n + 1] - r0;
  const ushort4* xv = (const ushort4*)xbf;
  float wself = pself[(size_t)n * 8 + h];
  ushort4 sv = xv[(size_t)n * 256 + t];
  float ax = wself * bf2f(sv.x), ay = wself * bf2f(sv.y);
  float az = wself * bf2f(sv.z), aw = wself * bf2f(sv.w);
  for (int base = 0; base < deg; base += 64) {
    int cnt = min(64, deg - base);
    if (t < cnt) ls[t] = csr_src[r0 + base + t];
    for (int idx = t; idx < cnt * 8; idx += 256)
      pws[idx] = pw[(size_t)(r0 + base) * 8 + idx];
    __syncthreads();
#pragma unroll 4
    for (int j = 0; j < cnt; ++j) {
      float w = pws[j * 8 + h];
      ushort4 u = xv[(size_t)ls[j] * 256 + t];
      ax = fmaf(w, bf2f(u.x), ax);
      ay = fmaf(w, bf2f(u.y), ay);
      az = fmaf(w, bf2f(u.z), az);
      aw = fmaf(w, bf2f(u.w), aw);
    }
    __syncthreads();
  }
  if (LAYER == 1) {
    float4 b = ((const float4*)bias)[t];
    ushort4 o4;
    o4.x = f2bf_rn(fmaxf(ax + b.x, 0.f));
    o4.y = f2bf_rn(fmaxf(ay + b.y, 0.f));
    o4.z = f2bf_rn(fmaxf(az + b.z, 0.f));
    o4.w = f2bf_rn(fmaxf(aw + b.w, 0.f));
    ((ushort4*)obf)[(size_t)n * 256 + t] = o4;
  } else {
    red[t][0] = ax; red[t][1] = ay; red[t][2] = az; red[t][3] = aw;
    __syncthreads();
    if (t < 32) {
      float sx = 0.f, sy = 0.f, sz = 0.f, sw = 0.f;
#pragma unroll
      for (int k = 0; k < 8; ++k) {
        sx += red[t + 32 * k][0];
        sy += red[t + 32 * k][1];
        sz += red[t + 32 * k][2];
        sw += red[t + 32 * k][3];
      }
      float4 b = ((const float4*)bias)[t];
      float4 o;
      o.x = sx * 0.125f + b.x;
      o.y = sy * 0.125f + b.y;
      o.z = sz * 0.125f + b.z;
      o.w = sw * 0.125f + b.w;
      ((float4*)outp)[(size_t)n * 32 + t] = o;
    }
  }
}

// ---------------- launch ----------------

extern "C" void kernel_launch(void* const* d_in, const int* in_sizes, int n_in,
                              void* d_out, int out_size, void* d_ws, size_t ws_size,
                              hipStream_t stream) {
  const float* x        = (const float*)d_in[0];
  const int*   ei       = (const int*)d_in[1];
  const float* edge_attr= (const float*)d_in[2];
  const float* W1       = (const float*)d_in[3];
  const float* We1      = (const float*)d_in[4];
  const float* as1      = (const float*)d_in[5];
  const float* ad1      = (const float*)d_in[6];
  const float* ae1      = (const float*)d_in[7];
  const float* b1       = (const float*)d_in[8];
  const float* W2       = (const float*)d_in[9];
  const float* We2      = (const float*)d_in[10];
  const float* as2      = (const float*)d_in[11];
  const float* ad2      = (const float*)d_in[12];
  const float* ae2      = (const float*)d_in[13];
  const float* b2       = (const float*)d_in[14];
  float* out = (float*)d_out;

  const int N = in_sizes[0] / 128;   // 10000 nodes
  const int E = in_sizes[2] / EDD;   // 160000 edges
  const int Mpad = ((N + 127) / 128) * 128;  // 10112

  char* ws = (char*)d_ws;
  size_t off = 0;
  auto alloc = [&](size_t bytes) -> void* {
    void* p = ws + off;
    off = (off + bytes + 255) & ~(size_t)255;
    return p;
  };
  int*   deg       = (int*)alloc((size_t)N * 4);
  int*   rowptr    = (int*)alloc((size_t)(N + 1) * 4);
  int*   cursor    = (int*)alloc((size_t)N * 4);
  int*   csr_src   = (int*)alloc((size_t)E * 4);
  int*   csr_dst   = (int*)alloc((size_t)E * 4);
  int*   csr_eid   = (int*)alloc((size_t)E * 4);
  float* ea_csr    = (float*)alloc((size_t)E * EDD * 4);
  float* loop_attr = (float*)alloc((size_t)N * EDD * 4);
  float* a_s       = (float*)alloc((size_t)N * 8 * 4);
  float* a_d       = (float*)alloc((size_t)N * 8 * 4);
  float* Ve        = (float*)alloc(256 * 4);
  float* alpha_csr = (float*)alloc((size_t)E * 8 * 4);   // becomes pw after sm_weights
  float* alpha_self= (float*)alloc((size_t)N * 8 * 4);
  float* pself     = (float*)alloc((size_t)N * 8 * 4);
  unsigned short* xh1bf = (unsigned short*)alloc((size_t)N * 1024 * 2);
  unsigned short* xh2bf = (unsigned short*)alloc((size_t)N * 1024 * 2);
  unsigned short* xhi   = (unsigned short*)alloc((size_t)Mpad * 128 * 2);
  unsigned short* xlo   = (unsigned short*)alloc((size_t)Mpad * 128 * 2);
  unsigned short* Bt1hi = (unsigned short*)alloc((size_t)1024 * 128 * 2);
  unsigned short* Bt1lo = (unsigned short*)alloc((size_t)1024 * 128 * 2);
  unsigned short* Bt2hi = (unsigned short*)alloc((size_t)1024 * 1024 * 2);
  unsigned short* Bt2lo = (unsigned short*)alloc((size_t)1024 * 1024 * 2);
  unsigned short* h1bf  = (unsigned short*)alloc((size_t)Mpad * 1024 * 2);
  (void)ws_size; (void)n_in; (void)out_size;

  hipMemsetAsync(deg, 0, (size_t)N * 4, stream);

  int gE = (E + 255) / 256;
  deg_count_kernel<<<gE, 256, 0, stream>>>(ei, deg, E);
  scan_kernel<<<1, 1024, 0, stream>>>(deg, rowptr, cursor, N);
  scatter_kernel<<<gE, 256, 0, stream>>>(ei, cursor, csr_src, csr_dst, csr_eid, E);
  permute_ea_kernel<<<(E * 8 + 255) / 256, 256, 0, stream>>>(csr_eid, edge_attr, ea_csr, E);
  loop_attr_kernel<<<(N + 7) / 8, 256, 0, stream>>>(rowptr, ea_csr, loop_attr, N);

  split_f32_kernel<<<(N * 128 / 4 + 255) / 256, 256, 0, stream>>>(x, xhi, xlo, N * 128 / 4);
  split_transpose_kernel<<<dim3(32, 4), 256, 0, stream>>>(W1, Bt1hi, Bt1lo, 128);
  split_transpose_kernel<<<dim3(32, 32), 256, 0, stream>>>(W2, Bt2hi, Bt2lo, 1024);

  dim3 ggrid(8, Mpad / 128);
  int gEA = (E + N + 255) / 256;
  int gSM = (N + 3) / 4;

  // ---- layer 1 ----
  gemm_mfma_split_kernel<<<ggrid, 256, 0, stream>>>(xhi, xlo, Bt1hi, Bt1lo, xh1bf,
                                                    a_s, a_d, as1, ad1, N, 128);
  ve_kernel<<<1, 256, 0, stream>>>(We1, ae1, Ve);
  edge_alpha_kernel<<<gEA, 256, 0, stream>>>(csr_src, csr_dst, ea_csr, loop_attr,
                                             a_s, a_d, Ve, alpha_csr, alpha_self, E, N);
  sm_weights_kernel<<<gSM, 256, 0, stream>>>(alpha_csr, alpha_self, pself, rowptr, N);
  agg_gather_kernel<1><<<N, 256, 0, stream>>>(xh1bf, alpha_csr, pself, rowptr, csr_src,
                                              b1, h1bf, nullptr, N);

  // ---- layer 2 ----
  gemm_a1b2_pipe_kernel<<<ggrid, 256, 0, stream>>>(h1bf, Bt2hi, Bt2lo, xh2bf,
                                                   a_s, a_d, as2, ad2, N, 1024);
  ve_kernel<<<1, 256, 0, stream>>>(We2, ae2, Ve);
  edge_alpha_kernel<<<gEA, 256, 0, stream>>>(csr_src, csr_dst, ea_csr, loop_attr,
                                             a_s, a_d, Ve, alpha_csr, alpha_self, E, N);
  sm_weights_kernel<<<gSM, 256, 0, stream>>>(alpha_csr, alpha_self, pself, rowptr, N);
  agg_gather_kernel<2><<<N, 256, 0, stream>>>(xh2bf, alpha_csr, pself, rowptr, csr_src,
                                              b2, nullptr, out, N);
}

// Round 8
// 287.198 us; speedup vs baseline: 2.1295x; 1.0430x over previous
//
#include <hip/hip_runtime.h>
#include <hip/hip_bf16.h>
#include <cstdint>
#include <cstddef>

// TwoLayerGAT on MI355X — round 8:
//  - GEMM1: full-K single-stage (stage all 4 K-tiles into 128KB LDS, ONE barrier,
//    then 4x48 MFMA barrier-free). Same proven tile/swizzle geometry.
//  - GEMM2: 2-phase double-buffer (stage k+1 at top of step k, one __syncthreads
//    per step, 50KB LDS -> 3 blocks/CU).
//  - softmax stats+weights fused into the aggregation kernel (sm_weights gone).

#define EDD 32

typedef __attribute__((ext_vector_type(4))) float f32x4;
typedef __attribute__((ext_vector_type(8))) short bf16x8;

__device__ inline unsigned short f2bf_rn(float f) {
  uint32_t u = __float_as_uint(f);
  return (unsigned short)((u + 0x7FFFu + ((u >> 16) & 1u)) >> 16);
}

__device__ inline void split2(float x, unsigned short& h, unsigned short& l) {
  uint32_t u = __float_as_uint(x);
  h = (unsigned short)(u >> 16);                       // truncated hi
  float r = x - __uint_as_float(u & 0xFFFF0000u);      // exact residual
  l = f2bf_rn(r);
}

__device__ inline float bf2f(unsigned short b) {
  return __uint_as_float(((uint32_t)b) << 16);
}

__device__ inline void gload_lds16(const void* g, void* l) {
  __builtin_amdgcn_global_load_lds((const __attribute__((address_space(1))) void*)g,
                                   (__attribute__((address_space(3))) void*)l, 16, 0, 0);
}

// ---------------- graph prep ----------------

__global__ void deg_count_kernel(const int* __restrict__ ei, int* __restrict__ deg, int E) {
  int e = blockIdx.x * 256 + threadIdx.x;
  if (e < E) atomicAdd(&deg[ei[E + e]], 1);
}

// single block, 1024 threads: exclusive scan of deg -> rowptr, cursor
__global__ void scan_kernel(const int* __restrict__ deg, int* __restrict__ rowptr,
                            int* __restrict__ cursor, int n) {
  __shared__ int wsum[16];
  int t = threadIdx.x;
  int chunk = (n + 1023) >> 10;
  int lo = min(t * chunk, n), hi = min(lo + chunk, n);
  int s = 0;
  for (int i = lo; i < hi; ++i) s += deg[i];
  int lane = t & 63, w = t >> 6;
  int v = s;
#pragma unroll
  for (int off = 1; off < 64; off <<= 1) {
    int u = __shfl_up(v, off);
    if (lane >= off) v += u;
  }
  if (lane == 63) wsum[w] = v;
  __syncthreads();
  if (t == 0) {
    int acc = 0;
#pragma unroll
    for (int i = 0; i < 16; ++i) { int x = wsum[i]; wsum[i] = acc; acc += x; }
  }
  __syncthreads();
  int excl = v - s + wsum[w];
  for (int i = lo; i < hi; ++i) {
    rowptr[i] = excl; cursor[i] = excl; excl += deg[i];
  }
  if (t == 1023) rowptr[n] = excl;
}

__global__ void scatter_kernel(const int* __restrict__ ei, int* __restrict__ cursor,
                               int* __restrict__ csr_src, int* __restrict__ csr_dst,
                               int* __restrict__ csr_eid, int E) {
  int e = blockIdx.x * 256 + threadIdx.x;
  if (e >= E) return;
  int d = ei[E + e];
  int pos = atomicAdd(&cursor[d], 1);
  csr_src[pos] = ei[e];
  csr_dst[pos] = d;
  csr_eid[pos] = e;
}

// edge_attr -> CSR order (one float4 per thread)
__global__ void permute_ea_kernel(const int* __restrict__ csr_eid,
                                  const float* __restrict__ edge_attr,
                                  float* __restrict__ ea_csr, int E) {
  int gid = blockIdx.x * 256 + threadIdx.x;
  if (gid >= E * 8) return;
  int p = gid >> 3, q = gid & 7;
  int e = csr_eid[p];
  ((float4*)ea_csr)[(size_t)p * 8 + q] = ((const float4*)edge_attr)[(size_t)e * 8 + q];
}

// loop_attr[n][d] = mean over incoming edges (contiguous CSR reads)
__global__ void loop_attr_kernel(const int* __restrict__ rowptr,
                                 const float* __restrict__ ea_csr,
                                 float* __restrict__ loop_attr, int N) {
  int n = blockIdx.x * 8 + (threadIdx.x >> 5);
  int lane = threadIdx.x & 31;
  if (n >= N) return;
  int r0 = rowptr[n], r1 = rowptr[n + 1];
  float s = 0.f;
  for (int p = r0; p < r1; ++p)
    s += ea_csr[(size_t)p * EDD + lane];
  float dv = fmaxf((float)(r1 - r0), 1.f);
  loop_attr[(size_t)n * EDD + lane] = s / dv;
}

// ---------------- conversions ----------------

__global__ void split_f32_kernel(const float* __restrict__ in, unsigned short* __restrict__ hi,
                                 unsigned short* __restrict__ lo, int n4) {
  int i = blockIdx.x * 256 + threadIdx.x;
  if (i >= n4) return;
  float4 v = ((const float4*)in)[i];
  ushort4 h, l;
  split2(v.x, h.x, l.x); split2(v.y, h.y, l.y);
  split2(v.z, h.z, l.z); split2(v.w, h.w, l.w);
  ((ushort4*)hi)[i] = h;
  ((ushort4*)lo)[i] = l;
}

// W [K][1024] f32 -> Bt_hi/lo [1024][K] bf16 (transposed, K-contiguous)
__global__ void split_transpose_kernel(const float* __restrict__ W,
                                       unsigned short* __restrict__ Bthi,
                                       unsigned short* __restrict__ Btlo, int K) {
  __shared__ float tile[32][33];
  int bn = blockIdx.x * 32;
  int bk = blockIdx.y * 32;
  int tx = threadIdx.x & 31, ty = threadIdx.x >> 5;
  for (int r = ty; r < 32; r += 8)
    tile[r][tx] = W[(size_t)(bk + r) * 1024 + bn + tx];
  __syncthreads();
  for (int r = ty; r < 32; r += 8) {
    float v = tile[tx][r];
    unsigned short h, l;
    split2(v, h, l);
    Bthi[(size_t)(bn + r) * K + bk + tx] = h;
    Btlo[(size_t)(bn + r) * K + bk + tx] = l;
  }
}

// ---------------- GEMM1: 3-product, full-K staged, one barrier ---------------
// K = 128. LDS: 4 step-buffers x (Ahi|Alo|Bhi|Blo) of 128x32 each = 128KB.

__global__ __launch_bounds__(256) void gemm1_fullk_kernel(
    const unsigned short* __restrict__ Ahi, const unsigned short* __restrict__ Alo,
    const unsigned short* __restrict__ Bthi, const unsigned short* __restrict__ Btlo,
    unsigned short* __restrict__ Cbf, float* __restrict__ a_s, float* __restrict__ a_d,
    const float* __restrict__ att_s, const float* __restrict__ att_d, int M) {
  __shared__ __align__(16) unsigned short lds[4 * 16384];  // 128KB
  __shared__ float redS[128][2];
  __shared__ float redD[128][2];
  const int t = threadIdx.x;
  const int lane = t & 63;
  const int wid = t >> 6;
  const int wr = wid >> 1, wc = wid & 1;
  const int m0 = blockIdx.y * 128;
  const int n0 = blockIdx.x * 128;
  const int hb = blockIdx.x;
  const int srow = lane >> 2;
  const int sg = lane & 3;

  // stage all 4 K-step tiles
#pragma unroll
  for (int s = 0; s < 4; ++s) {
    unsigned short* L = lds + s * 16384;
    int k0 = s * 32;
#pragma unroll
    for (int q = 0; q < 2; ++q) {
      int rb = wid * 32 + q * 16;
      int row = rb + srow;
      int gsrc = sg ^ ((row >> 1) & 3);
      size_t ga = (size_t)(m0 + row) * 128 + k0 + gsrc * 8;
      size_t gb = (size_t)(n0 + row) * 128 + k0 + gsrc * 8;
      gload_lds16(Ahi + ga, L + rb * 32);
      gload_lds16(Alo + ga, L + 4096 + rb * 32);
      gload_lds16(Bthi + gb, L + 8192 + rb * 32);
      gload_lds16(Btlo + gb, L + 12288 + rb * 32);
    }
  }
  __syncthreads();

  int offa[4], offb[4];
#pragma unroll
  for (int i = 0; i < 4; ++i) {
    int rowa = wr * 64 + i * 16 + (lane & 15);
    offa[i] = rowa * 32 + (((lane >> 4) ^ ((rowa >> 1) & 3)) * 8);
    int rowb = wc * 64 + i * 16 + (lane & 15);
    offb[i] = rowb * 32 + (((lane >> 4) ^ ((rowb >> 1) & 3)) * 8);
  }

  f32x4 acc[4][4] = {};
#pragma unroll
  for (int s = 0; s < 4; ++s) {
    unsigned short* L = lds + s * 16384;
    bf16x8 ah[4], al[4];
#pragma unroll
    for (int i = 0; i < 4; ++i) {
      ah[i] = *(const bf16x8*)(L + offa[i]);
      al[i] = *(const bf16x8*)(L + 4096 + offa[i]);
    }
#pragma unroll
    for (int j = 0; j < 4; ++j) {
      bf16x8 bh = *(const bf16x8*)(L + 8192 + offb[j]);
      bf16x8 bl = *(const bf16x8*)(L + 12288 + offb[j]);
#pragma unroll
      for (int i = 0; i < 4; ++i) {
        acc[i][j] = __builtin_amdgcn_mfma_f32_16x16x32_bf16(ah[i], bh, acc[i][j], 0, 0, 0);
        acc[i][j] = __builtin_amdgcn_mfma_f32_16x16x32_bf16(ah[i], bl, acc[i][j], 0, 0, 0);
        acc[i][j] = __builtin_amdgcn_mfma_f32_16x16x32_bf16(al[i], bh, acc[i][j], 0, 0, 0);
      }
    }
  }

  float as_v[4], ad_v[4];
#pragma unroll
  for (int j = 0; j < 4; ++j) {
    int c = n0 + wc * 64 + j * 16 + (lane & 15);
    as_v[j] = att_s[c];
    ad_v[j] = att_d[c];
  }
#pragma unroll
  for (int i = 0; i < 4; ++i) {
#pragma unroll
    for (int r = 0; r < 4; ++r) {
      float sA = 0.f, sD = 0.f;
#pragma unroll
      for (int j = 0; j < 4; ++j) {
        sA = fmaf(acc[i][j][r], as_v[j], sA);
        sD = fmaf(acc[i][j][r], ad_v[j], sD);
      }
#pragma unroll
      for (int mask = 1; mask <= 8; mask <<= 1) {
        sA += __shfl_xor(sA, mask);
        sD += __shfl_xor(sD, mask);
      }
      if ((lane & 15) == 0) {
        int ml = wr * 64 + i * 16 + (lane >> 4) * 4 + r;
        redS[ml][wc] = sA;
        redD[ml][wc] = sD;
      }
      int m = m0 + wr * 64 + i * 16 + (lane >> 4) * 4 + r;
      if (m < M) {
#pragma unroll
        for (int j = 0; j < 4; ++j) {
          int n = n0 + wc * 64 + j * 16 + (lane & 15);
          Cbf[(size_t)m * 1024 + n] = f2bf_rn(acc[i][j][r]);
        }
      }
    }
  }
  __syncthreads();
  if (t < 128) {
    int m = m0 + t;
    if (m < M) {
      a_s[(size_t)m * 8 + hb] = redS[t][0] + redS[t][1];
      a_d[(size_t)m * 8 + hb] = redD[t][0] + redD[t][1];
    }
  }
}

// ---------------- GEMM2: 2-product, 2-phase double-buffer --------------------
// stage(k+1) at top of step k; one __syncthreads per step; 50KB LDS -> 3 blk/CU.

__global__ __launch_bounds__(256) void gemm2_dbuf_kernel(
    const unsigned short* __restrict__ Abf,
    const unsigned short* __restrict__ Bthi, const unsigned short* __restrict__ Btlo,
    unsigned short* __restrict__ Cbf, float* __restrict__ a_s, float* __restrict__ a_d,
    const float* __restrict__ att_s, const float* __restrict__ att_d, int M, int K) {
  __shared__ __align__(16) unsigned short lds[2 * 12288];  // 48KB
  __shared__ float redS[128][2];
  __shared__ float redD[128][2];
  const int t = threadIdx.x;
  const int lane = t & 63;
  const int wid = t >> 6;
  const int wr = wid >> 1, wc = wid & 1;
  const int m0 = blockIdx.y * 128;
  const int n0 = blockIdx.x * 128;
  const int hb = blockIdx.x;
  const int srow = lane >> 2;
  const int sg = lane & 3;
  const int nk = K >> 5;

  auto stage = [&](int b, int k) {
    unsigned short* L = lds + b * 12288;
    int k0 = k * 32;
#pragma unroll
    for (int q = 0; q < 2; ++q) {
      int rb = wid * 32 + q * 16;
      int row = rb + srow;
      int gsrc = sg ^ ((row >> 1) & 3);
      size_t ga = (size_t)(m0 + row) * K + k0 + gsrc * 8;
      size_t gb = (size_t)(n0 + row) * K + k0 + gsrc * 8;
      gload_lds16(Abf + ga, L + rb * 32);
      gload_lds16(Bthi + gb, L + 4096 + rb * 32);
      gload_lds16(Btlo + gb, L + 8192 + rb * 32);
    }
  };

  int offa[4], offb[4];
#pragma unroll
  for (int i = 0; i < 4; ++i) {
    int rowa = wr * 64 + i * 16 + (lane & 15);
    offa[i] = rowa * 32 + (((lane >> 4) ^ ((rowa >> 1) & 3)) * 8);
    int rowb = wc * 64 + i * 16 + (lane & 15);
    offb[i] = rowb * 32 + (((lane >> 4) ^ ((rowb >> 1) & 3)) * 8);
  }

  f32x4 acc[4][4] = {};
  stage(0, 0);
  __syncthreads();

  for (int k = 0; k < nk; ++k) {
    if (k + 1 < nk) stage((k + 1) & 1, k + 1);  // issue next-tile loads FIRST
    unsigned short* L = lds + (k & 1) * 12288;
    bf16x8 ah[4], bh[4], bl[4];
#pragma unroll
    for (int i = 0; i < 4; ++i) ah[i] = *(const bf16x8*)(L + offa[i]);
#pragma unroll
    for (int j = 0; j < 4; ++j) {
      bh[j] = *(const bf16x8*)(L + 4096 + offb[j]);
      bl[j] = *(const bf16x8*)(L + 8192 + offb[j]);
    }
#pragma unroll
    for (int j = 0; j < 4; ++j)
#pragma unroll
      for (int i = 0; i < 4; ++i) {
        acc[i][j] = __builtin_amdgcn_mfma_f32_16x16x32_bf16(ah[i], bh[j], acc[i][j], 0, 0, 0);
        acc[i][j] = __builtin_amdgcn_mfma_f32_16x16x32_bf16(ah[i], bl[j], acc[i][j], 0, 0, 0);
      }
    __syncthreads();  // drains stage(k+1) + all waves done reading buf k
  }

  float as_v[4], ad_v[4];
#pragma unroll
  for (int j = 0; j < 4; ++j) {
    int c = n0 + wc * 64 + j * 16 + (lane & 15);
    as_v[j] = att_s[c];
    ad_v[j] = att_d[c];
  }
#pragma unroll
  for (int i = 0; i < 4; ++i) {
#pragma unroll
    for (int r = 0; r < 4; ++r) {
      float sA = 0.f, sD = 0.f;
#pragma unroll
      for (int j = 0; j < 4; ++j) {
        sA = fmaf(acc[i][j][r], as_v[j], sA);
        sD = fmaf(acc[i][j][r], ad_v[j], sD);
      }
#pragma unroll
      for (int mask = 1; mask <= 8; mask <<= 1) {
        sA += __shfl_xor(sA, mask);
        sD += __shfl_xor(sD, mask);
      }
      if ((lane & 15) == 0) {
        int ml = wr * 64 + i * 16 + (lane >> 4) * 4 + r;
        redS[ml][wc] = sA;
        redD[ml][wc] = sD;
      }
      int m = m0 + wr * 64 + i * 16 + (lane >> 4) * 4 + r;
      if (m < M) {
#pragma unroll
        for (int j = 0; j < 4; ++j) {
          int n = n0 + wc * 64 + j * 16 + (lane & 15);
          Cbf[(size_t)m * 1024 + n] = f2bf_rn(acc[i][j][r]);
        }
      }
    }
  }
  __syncthreads();
  if (t < 128) {
    int m = m0 + t;
    if (m < M) {
      a_s[(size_t)m * 8 + hb] = redS[t][0] + redS[t][1];
      a_d[(size_t)m * 8 + hb] = redD[t][0] + redD[t][1];
    }
  }
}

// ---------------- attention scalars ----------------

__global__ void ve_kernel(const float* __restrict__ We, const float* __restrict__ att_e,
                          float* __restrict__ Ve) {
  int t = threadIdx.x;  // 256
  int d = t >> 3, h = t & 7;
  float s = 0.f;
  for (int c = 0; c < 128; ++c) s = fmaf(We[d * 1024 + h * 128 + c], att_e[h * 128 + c], s);
  Ve[t] = s;
}

// raw alpha (leaky_relu) in CSR order; self-loop alphas separate.
__global__ __launch_bounds__(256) void edge_alpha_kernel(
    const int* __restrict__ csr_src, const int* __restrict__ csr_dst,
    const float* __restrict__ ea_csr, const float* __restrict__ loop_attr,
    const float* __restrict__ a_s, const float* __restrict__ a_d,
    const float* __restrict__ Ve,
    float* __restrict__ alpha_csr, float* __restrict__ alpha_self, int E, int n) {
  __shared__ float sVe[EDD][8];
  int t = threadIdx.x;
  sVe[t >> 3][t & 7] = Ve[t];
  __syncthreads();
  int idx = blockIdx.x * 256 + t;
  if (idx >= E + n) return;
  int s, d;
  const float* ea;
  float* outp;
  if (idx < E) {
    s = csr_src[idx]; d = csr_dst[idx];
    ea = ea_csr + (size_t)idx * EDD;
    outp = alpha_csr + (size_t)idx * 8;
  } else {
    s = d = idx - E;
    ea = loop_attr + (size_t)(idx - E) * EDD;
    outp = alpha_self + (size_t)(idx - E) * 8;
  }
  float ae[8] = {0.f, 0.f, 0.f, 0.f, 0.f, 0.f, 0.f, 0.f};
#pragma unroll
  for (int k = 0; k < EDD; k += 4) {
    float4 v = *(const float4*)&ea[k];
#pragma unroll
    for (int h = 0; h < 8; ++h) {
      ae[h] = fmaf(v.x, sVe[k][h], ae[h]);
      ae[h] = fmaf(v.y, sVe[k + 1][h], ae[h]);
      ae[h] = fmaf(v.z, sVe[k + 2][h], ae[h]);
      ae[h] = fmaf(v.w, sVe[k + 3][h], ae[h]);
    }
  }
#pragma unroll
  for (int h = 0; h < 8; ++h) {
    float a = a_s[(size_t)s * 8 + h] + a_d[(size_t)d * 8 + h] + ae[h];
    outp[h] = (a > 0.f) ? a : 0.2f * a;
  }
}

// ---------------- fused softmax + aggregation: block-per-node ----------------
// stats (32 slots x 8 heads) -> weights computed inline -> bf16 row gather.
// LAYER==1: write relu(agg+b1) as single bf16; LAYER==2: mean_h(agg)+b2 f32.

template <int LAYER>
__global__ __launch_bounds__(256) void agg_fused_kernel(
    const unsigned short* __restrict__ xbf, const float* __restrict__ alpha,
    const float* __restrict__ alpha_self, const int* __restrict__ rowptr,
    const int* __restrict__ csr_src, const float* __restrict__ bias,
    unsigned short* __restrict__ obf, float* __restrict__ outp, int N) {
  int n = blockIdx.x;
  int t = threadIdx.x;
  int lane = t & 63, w = t >> 6;
  __shared__ float wm[4][8], wsm[4][8];
  __shared__ float sm_m[8], sm_inv[8];
  __shared__ int ls[64];
  __shared__ float pws[64 * 8];
  __shared__ float red[256][4];
  int r0 = rowptr[n];
  int deg = rowptr[n + 1] - r0;

  // ---- stats: slot = t>>3 (32 slots), h = t&7 ----
  {
    int h = t & 7, slot = t >> 3;
    float m = -1e30f, s = 0.f;
    for (int i = slot; i < deg; i += 32) {
      float a = alpha[(size_t)(r0 + i) * 8 + h];
      if (a <= m) {
        s += __expf(a - m);
      } else {
        s = s * __expf(m - a) + 1.f;
        m = a;
      }
    }
#pragma unroll
    for (int mask = 8; mask < 64; mask <<= 1) {
      float mo = __shfl_xor(m, mask);
      float so = __shfl_xor(s, mask);
      float mn = fmaxf(m, mo);
      s = s * __expf(m - mn) + so * __expf(mo - mn);
      m = mn;
    }
    if (lane < 8) { wm[w][lane] = m; wsm[w][lane] = s; }
  }
  __syncthreads();
  if (t < 8) {
    float m = wm[0][t], s = wsm[0][t];
#pragma unroll
    for (int k = 1; k < 4; ++k) {
      float mo = wm[k][t], so = wsm[k][t];
      float mn = fmaxf(m, mo);
      s = s * __expf(m - mn) + so * __expf(mo - mn);
      m = mn;
    }
    float aself = alpha_self[(size_t)n * 8 + t];
    float mn = fmaxf(m, aself);
    s = s * __expf(m - mn) + __expf(aself - mn);
    sm_m[t] = mn;
    sm_inv[t] = 1.f / (s + 1e-16f);
  }
  __syncthreads();

  // ---- gather ----
  int h = t >> 5;
  float m_h = sm_m[h], inv_h = sm_inv[h];
  float m_w = sm_m[t & 7], inv_w = sm_inv[t & 7];
  const ushort4* xv = (const ushort4*)xbf;
  float wself = __expf(alpha_self[(size_t)n * 8 + h] - m_h) * inv_h;
  ushort4 sv = xv[(size_t)n * 256 + t];
  float ax = wself * bf2f(sv.x), ay = wself * bf2f(sv.y);
  float az = wself * bf2f(sv.z), aw = wself * bf2f(sv.w);
  for (int base = 0; base < deg; base += 64) {
    int cnt = min(64, deg - base);
    if (t < cnt) ls[t] = csr_src[r0 + base + t];
    for (int idx = t; idx < cnt * 8; idx += 256)
      pws[idx] = __expf(alpha[(size_t)(r0 + base) * 8 + idx] - m_w) * inv_w;
    __syncthreads();
#pragma unroll 4
    for (int j = 0; j < cnt; ++j) {
      float wt = pws[j * 8 + h];
      ushort4 u = xv[(size_t)ls[j] * 256 + t];
      ax = fmaf(wt, bf2f(u.x), ax);
      ay = fmaf(wt, bf2f(u.y), ay);
      az = fmaf(wt, bf2f(u.z), az);
      aw = fmaf(wt, bf2f(u.w), aw);
    }
    __syncthreads();
  }
  if (LAYER == 1) {
    float4 b = ((const float4*)bias)[t];
    ushort4 o4;
    o4.x = f2bf_rn(fmaxf(ax + b.x, 0.f));
    o4.y = f2bf_rn(fmaxf(ay + b.y, 0.f));
    o4.z = f2bf_rn(fmaxf(az + b.z, 0.f));
    o4.w = f2bf_rn(fmaxf(aw + b.w, 0.f));
    ((ushort4*)obf)[(size_t)n * 256 + t] = o4;
  } else {
    red[t][0] = ax; red[t][1] = ay; red[t][2] = az; red[t][3] = aw;
    __syncthreads();
    if (t < 32) {
      float sx = 0.f, sy = 0.f, sz = 0.f, sw = 0.f;
#pragma unroll
      for (int k = 0; k < 8; ++k) {
        sx += red[t + 32 * k][0];
        sy += red[t + 32 * k][1];
        sz += red[t + 32 * k][2];
        sw += red[t + 32 * k][3];
      }
      float4 b = ((const float4*)bias)[t];
      float4 o;
      o.x = sx * 0.125f + b.x;
      o.y = sy * 0.125f + b.y;
      o.z = sz * 0.125f + b.z;
      o.w = sw * 0.125f + b.w;
      ((float4*)outp)[(size_t)n * 32 + t] = o;
    }
  }
}

// ---------------- launch ----------------

extern "C" void kernel_launch(void* const* d_in, const int* in_sizes, int n_in,
                              void* d_out, int out_size, void* d_ws, size_t ws_size,
                              hipStream_t stream) {
  const float* x        = (const float*)d_in[0];
  const int*   ei       = (const int*)d_in[1];
  const float* edge_attr= (const float*)d_in[2];
  const float* W1       = (const float*)d_in[3];
  const float* We1      = (const float*)d_in[4];
  const float* as1      = (const float*)d_in[5];
  const float* ad1      = (const float*)d_in[6];
  const float* ae1      = (const float*)d_in[7];
  const float* b1       = (const float*)d_in[8];
  const float* W2       = (const float*)d_in[9];
  const float* We2      = (const float*)d_in[10];
  const float* as2      = (const float*)d_in[11];
  const float* ad2      = (const float*)d_in[12];
  const float* ae2      = (const float*)d_in[13];
  const float* b2       = (const float*)d_in[14];
  float* out = (float*)d_out;

  const int N = in_sizes[0] / 128;   // 10000 nodes
  const int E = in_sizes[2] / EDD;   // 160000 edges
  const int Mpad = ((N + 127) / 128) * 128;  // 10112

  char* ws = (char*)d_ws;
  size_t off = 0;
  auto alloc = [&](size_t bytes) -> void* {
    void* p = ws + off;
    off = (off + bytes + 255) & ~(size_t)255;
    return p;
  };
  int*   deg       = (int*)alloc((size_t)N * 4);
  int*   rowptr    = (int*)alloc((size_t)(N + 1) * 4);
  int*   cursor    = (int*)alloc((size_t)N * 4);
  int*   csr_src   = (int*)alloc((size_t)E * 4);
  int*   csr_dst   = (int*)alloc((size_t)E * 4);
  int*   csr_eid   = (int*)alloc((size_t)E * 4);
  float* ea_csr    = (float*)alloc((size_t)E * EDD * 4);
  float* loop_attr = (float*)alloc((size_t)N * EDD * 4);
  float* a_s       = (float*)alloc((size_t)N * 8 * 4);
  float* a_d       = (float*)alloc((size_t)N * 8 * 4);
  float* Ve        = (float*)alloc(256 * 4);
  float* alpha_csr = (float*)alloc((size_t)E * 8 * 4);
  float* alpha_self= (float*)alloc((size_t)N * 8 * 4);
  unsigned short* xh1bf = (unsigned short*)alloc((size_t)N * 1024 * 2);
  unsigned short* xh2bf = (unsigned short*)alloc((size_t)N * 1024 * 2);
  unsigned short* xhi   = (unsigned short*)alloc((size_t)Mpad * 128 * 2);
  unsigned short* xlo   = (unsigned short*)alloc((size_t)Mpad * 128 * 2);
  unsigned short* Bt1hi = (unsigned short*)alloc((size_t)1024 * 128 * 2);
  unsigned short* Bt1lo = (unsigned short*)alloc((size_t)1024 * 128 * 2);
  unsigned short* Bt2hi = (unsigned short*)alloc((size_t)1024 * 1024 * 2);
  unsigned short* Bt2lo = (unsigned short*)alloc((size_t)1024 * 1024 * 2);
  unsigned short* h1bf  = (unsigned short*)alloc((size_t)Mpad * 1024 * 2);
  (void)ws_size; (void)n_in; (void)out_size;

  hipMemsetAsync(deg, 0, (size_t)N * 4, stream);

  int gE = (E + 255) / 256;
  deg_count_kernel<<<gE, 256, 0, stream>>>(ei, deg, E);
  scan_kernel<<<1, 1024, 0, stream>>>(deg, rowptr, cursor, N);
  scatter_kernel<<<gE, 256, 0, stream>>>(ei, cursor, csr_src, csr_dst, csr_eid, E);
  permute_ea_kernel<<<(E * 8 + 255) / 256, 256, 0, stream>>>(csr_eid, edge_attr, ea_csr, E);
  loop_attr_kernel<<<(N + 7) / 8, 256, 0, stream>>>(rowptr, ea_csr, loop_attr, N);

  split_f32_kernel<<<(N * 128 / 4 + 255) / 256, 256, 0, stream>>>(x, xhi, xlo, N * 128 / 4);
  split_transpose_kernel<<<dim3(32, 4), 256, 0, stream>>>(W1, Bt1hi, Bt1lo, 128);
  split_transpose_kernel<<<dim3(32, 32), 256, 0, stream>>>(W2, Bt2hi, Bt2lo, 1024);

  dim3 ggrid(8, Mpad / 128);
  int gEA = (E + N + 255) / 256;

  // ---- layer 1 ----
  gemm1_fullk_kernel<<<ggrid, 256, 0, stream>>>(xhi, xlo, Bt1hi, Bt1lo, xh1bf,
                                                a_s, a_d, as1, ad1, N);
  ve_kernel<<<1, 256, 0, stream>>>(We1, ae1, Ve);
  edge_alpha_kernel<<<gEA, 256, 0, stream>>>(csr_src, csr_dst, ea_csr, loop_attr,
                                             a_s, a_d, Ve, alpha_csr, alpha_self, E, N);
  agg_fused_kernel<1><<<N, 256, 0, stream>>>(xh1bf, alpha_csr, alpha_self, rowptr, csr_src,
                                             b1, h1bf, nullptr, N);

  // ---- layer 2 ----
  gemm2_dbuf_kernel<<<ggrid, 256, 0, stream>>>(h1bf, Bt2hi, Bt2lo, xh2bf,
                                               a_s, a_d, as2, ad2, N, 1024);
  ve_kernel<<<1, 256, 0, stream>>>(We2, ae2, Ve);
  edge_alpha_kernel<<<gEA, 256, 0, stream>>>(csr_src, csr_dst, ea_csr, loop_attr,
                                             a_s, a_d, Ve, alpha_csr, alpha_self, E, N);
  agg_fused_kernel<2><<<N, 256, 0, stream>>>(xh2bf, alpha_csr, alpha_self, rowptr, csr_src,
                                             b2, nullptr, out, N);
}

// Round 9
// 246.318 us; speedup vs baseline: 2.4830x; 1.1660x over previous
//
#include <hip/hip_runtime.h>
#include <hip/hip_bf16.h>
#include <cstdint>
#include <cstddef>

// TwoLayerGAT on MI355X — round 9:
//  - Both GEMMs -> plain bf16 1-product (error analysis: all added terms wash
//    by /sqrt(136) neighbor*head averaging; predicted absmax ~1.5e-3 < 4.14e-3).
//  - GEMM2 dbuf buffers 24->16KB => 32KB LDS => 4-5 blocks/CU (TLP lever).
//  - GEMM1 full-K single-barrier at 64KB LDS.
//  - split2 machinery removed; ve1+ve2 and both W-transposes merged (1 dispatch each).

#define EDD 32

typedef __attribute__((ext_vector_type(4))) float f32x4;
typedef __attribute__((ext_vector_type(8))) short bf16x8;

__device__ inline unsigned short f2bf_rn(float f) {
  uint32_t u = __float_as_uint(f);
  return (unsigned short)((u + 0x7FFFu + ((u >> 16) & 1u)) >> 16);
}

__device__ inline float bf2f(unsigned short b) {
  return __uint_as_float(((uint32_t)b) << 16);
}

__device__ inline void gload_lds16(const void* g, void* l) {
  __builtin_amdgcn_global_load_lds((const __attribute__((address_space(1))) void*)g,
                                   (__attribute__((address_space(3))) void*)l, 16, 0, 0);
}

// ---------------- graph prep ----------------

__global__ void deg_count_kernel(const int* __restrict__ ei, int* __restrict__ deg, int E) {
  int e = blockIdx.x * 256 + threadIdx.x;
  if (e < E) atomicAdd(&deg[ei[E + e]], 1);
}

// single block, 1024 threads: exclusive scan of deg -> rowptr, cursor
__global__ void scan_kernel(const int* __restrict__ deg, int* __restrict__ rowptr,
                            int* __restrict__ cursor, int n) {
  __shared__ int wsum[16];
  int t = threadIdx.x;
  int chunk = (n + 1023) >> 10;
  int lo = min(t * chunk, n), hi = min(lo + chunk, n);
  int s = 0;
  for (int i = lo; i < hi; ++i) s += deg[i];
  int lane = t & 63, w = t >> 6;
  int v = s;
#pragma unroll
  for (int off = 1; off < 64; off <<= 1) {
    int u = __shfl_up(v, off);
    if (lane >= off) v += u;
  }
  if (lane == 63) wsum[w] = v;
  __syncthreads();
  if (t == 0) {
    int acc = 0;
#pragma unroll
    for (int i = 0; i < 16; ++i) { int x = wsum[i]; wsum[i] = acc; acc += x; }
  }
  __syncthreads();
  int excl = v - s + wsum[w];
  for (int i = lo; i < hi; ++i) {
    rowptr[i] = excl; cursor[i] = excl; excl += deg[i];
  }
  if (t == 1023) rowptr[n] = excl;
}

__global__ void scatter_kernel(const int* __restrict__ ei, int* __restrict__ cursor,
                               int* __restrict__ csr_src, int* __restrict__ csr_dst,
                               int* __restrict__ csr_eid, int E) {
  int e = blockIdx.x * 256 + threadIdx.x;
  if (e >= E) return;
  int d = ei[E + e];
  int pos = atomicAdd(&cursor[d], 1);
  csr_src[pos] = ei[e];
  csr_dst[pos] = d;
  csr_eid[pos] = e;
}

// edge_attr -> CSR order (one float4 per thread)
__global__ void permute_ea_kernel(const int* __restrict__ csr_eid,
                                  const float* __restrict__ edge_attr,
                                  float* __restrict__ ea_csr, int E) {
  int gid = blockIdx.x * 256 + threadIdx.x;
  if (gid >= E * 8) return;
  int p = gid >> 3, q = gid & 7;
  int e = csr_eid[p];
  ((float4*)ea_csr)[(size_t)p * 8 + q] = ((const float4*)edge_attr)[(size_t)e * 8 + q];
}

// loop_attr[n][d] = mean over incoming edges (contiguous CSR reads)
__global__ void loop_attr_kernel(const int* __restrict__ rowptr,
                                 const float* __restrict__ ea_csr,
                                 float* __restrict__ loop_attr, int N) {
  int n = blockIdx.x * 8 + (threadIdx.x >> 5);
  int lane = threadIdx.x & 31;
  if (n >= N) return;
  int r0 = rowptr[n], r1 = rowptr[n + 1];
  float s = 0.f;
  for (int p = r0; p < r1; ++p)
    s += ea_csr[(size_t)p * EDD + lane];
  float dv = fmaxf((float)(r1 - r0), 1.f);
  loop_attr[(size_t)n * EDD + lane] = s / dv;
}

// ---------------- conversions ----------------

__global__ void cvt_bf16_kernel(const float* __restrict__ in,
                                unsigned short* __restrict__ out, int n4) {
  int i = blockIdx.x * 256 + threadIdx.x;
  if (i >= n4) return;
  float4 v = ((const float4*)in)[i];
  ushort4 o;
  o.x = f2bf_rn(v.x); o.y = f2bf_rn(v.y); o.z = f2bf_rn(v.z); o.w = f2bf_rn(v.w);
  ((ushort4*)out)[i] = o;
}

// W [K][1024] f32 -> Bt [1024][K] bf16 (transposed, K-contiguous); both layers.
__global__ void transpose_both_kernel(const float* __restrict__ W1, unsigned short* __restrict__ Bt1,
                                      const float* __restrict__ W2, unsigned short* __restrict__ Bt2) {
  __shared__ float tile[32][33];
  int by = blockIdx.y;
  const float* W; unsigned short* Bt; int K, bk;
  if (by < 4) { W = W1; Bt = Bt1; K = 128; bk = by * 32; }
  else        { W = W2; Bt = Bt2; K = 1024; bk = (by - 4) * 32; }
  int bn = blockIdx.x * 32;
  int tx = threadIdx.x & 31, ty = threadIdx.x >> 5;
  for (int r = ty; r < 32; r += 8)
    tile[r][tx] = W[(size_t)(bk + r) * 1024 + bn + tx];
  __syncthreads();
  for (int r = ty; r < 32; r += 8)
    Bt[(size_t)(bn + r) * K + bk + tx] = f2bf_rn(tile[tx][r]);
}

// Ve[layer][d*8+h] = sum_c We[d][h*128+c] * att_e[h][c]
__global__ void ve_both_kernel(const float* __restrict__ We1, const float* __restrict__ ae1,
                               const float* __restrict__ We2, const float* __restrict__ ae2,
                               float* __restrict__ Ve) {
  int b = blockIdx.x;
  const float* We = b ? We2 : We1;
  const float* ae = b ? ae2 : ae1;
  int t = threadIdx.x;
  int d = t >> 3, h = t & 7;
  float s = 0.f;
  for (int c = 0; c < 128; ++c) s = fmaf(We[d * 1024 + h * 128 + c], ae[h * 128 + c], s);
  Ve[b * 256 + t] = s;
}

// ---------------- GEMM1: bf16 1-product, full-K staged, one barrier ----------
// K = 128. LDS: 4 step-buffers x (A|B) of 128x32 bf16 each = 64KB.

__global__ __launch_bounds__(256) void gemm1_fullk_kernel(
    const unsigned short* __restrict__ Abf, const unsigned short* __restrict__ Btbf,
    unsigned short* __restrict__ Cbf, float* __restrict__ a_s, float* __restrict__ a_d,
    const float* __restrict__ att_s, const float* __restrict__ att_d, int M) {
  __shared__ __align__(16) unsigned short lds[4 * 8192];  // 64KB
  __shared__ float redS[128][2];
  __shared__ float redD[128][2];
  const int t = threadIdx.x;
  const int lane = t & 63;
  const int wid = t >> 6;
  const int wr = wid >> 1, wc = wid & 1;
  const int m0 = blockIdx.y * 128;
  const int n0 = blockIdx.x * 128;
  const int hb = blockIdx.x;
  const int srow = lane >> 2;
  const int sg = lane & 3;

#pragma unroll
  for (int s = 0; s < 4; ++s) {
    unsigned short* L = lds + s * 8192;
    int k0 = s * 32;
#pragma unroll
    for (int q = 0; q < 2; ++q) {
      int rb = wid * 32 + q * 16;
      int row = rb + srow;
      int gsrc = sg ^ ((row >> 1) & 3);
      size_t ga = (size_t)(m0 + row) * 128 + k0 + gsrc * 8;
      size_t gb = (size_t)(n0 + row) * 128 + k0 + gsrc * 8;
      gload_lds16(Abf + ga, L + rb * 32);
      gload_lds16(Btbf + gb, L + 4096 + rb * 32);
    }
  }
  __syncthreads();

  int offa[4], offb[4];
#pragma unroll
  for (int i = 0; i < 4; ++i) {
    int rowa = wr * 64 + i * 16 + (lane & 15);
    offa[i] = rowa * 32 + (((lane >> 4) ^ ((rowa >> 1) & 3)) * 8);
    int rowb = wc * 64 + i * 16 + (lane & 15);
    offb[i] = rowb * 32 + (((lane >> 4) ^ ((rowb >> 1) & 3)) * 8);
  }

  f32x4 acc[4][4] = {};
#pragma unroll
  for (int s = 0; s < 4; ++s) {
    unsigned short* L = lds + s * 8192;
    bf16x8 ah[4];
#pragma unroll
    for (int i = 0; i < 4; ++i) ah[i] = *(const bf16x8*)(L + offa[i]);
#pragma unroll
    for (int j = 0; j < 4; ++j) {
      bf16x8 bh = *(const bf16x8*)(L + 4096 + offb[j]);
#pragma unroll
      for (int i = 0; i < 4; ++i)
        acc[i][j] = __builtin_amdgcn_mfma_f32_16x16x32_bf16(ah[i], bh, acc[i][j], 0, 0, 0);
    }
  }

  float as_v[4], ad_v[4];
#pragma unroll
  for (int j = 0; j < 4; ++j) {
    int c = n0 + wc * 64 + j * 16 + (lane & 15);
    as_v[j] = att_s[c];
    ad_v[j] = att_d[c];
  }
#pragma unroll
  for (int i = 0; i < 4; ++i) {
#pragma unroll
    for (int r = 0; r < 4; ++r) {
      float sA = 0.f, sD = 0.f;
#pragma unroll
      for (int j = 0; j < 4; ++j) {
        sA = fmaf(acc[i][j][r], as_v[j], sA);
        sD = fmaf(acc[i][j][r], ad_v[j], sD);
      }
#pragma unroll
      for (int mask = 1; mask <= 8; mask <<= 1) {
        sA += __shfl_xor(sA, mask);
        sD += __shfl_xor(sD, mask);
      }
      if ((lane & 15) == 0) {
        int ml = wr * 64 + i * 16 + (lane >> 4) * 4 + r;
        redS[ml][wc] = sA;
        redD[ml][wc] = sD;
      }
      int m = m0 + wr * 64 + i * 16 + (lane >> 4) * 4 + r;
      if (m < M) {
#pragma unroll
        for (int j = 0; j < 4; ++j) {
          int n = n0 + wc * 64 + j * 16 + (lane & 15);
          Cbf[(size_t)m * 1024 + n] = f2bf_rn(acc[i][j][r]);
        }
      }
    }
  }
  __syncthreads();
  if (t < 128) {
    int m = m0 + t;
    if (m < M) {
      a_s[(size_t)m * 8 + hb] = redS[t][0] + redS[t][1];
      a_d[(size_t)m * 8 + hb] = redD[t][0] + redD[t][1];
    }
  }
}

// ---------------- GEMM2: bf16 1-product, 2-phase double-buffer ---------------
// 2 x 16KB buffers = 32KB LDS -> 4-5 blocks/CU.

__global__ __launch_bounds__(256) void gemm2_dbuf_kernel(
    const unsigned short* __restrict__ Abf, const unsigned short* __restrict__ Btbf,
    unsigned short* __restrict__ Cbf, float* __restrict__ a_s, float* __restrict__ a_d,
    const float* __restrict__ att_s, const float* __restrict__ att_d, int M, int K) {
  __shared__ __align__(16) unsigned short lds[2 * 8192];  // 32KB
  __shared__ float redS[128][2];
  __shared__ float redD[128][2];
  const int t = threadIdx.x;
  const int lane = t & 63;
  const int wid = t >> 6;
  const int wr = wid >> 1, wc = wid & 1;
  const int m0 = blockIdx.y * 128;
  const int n0 = blockIdx.x * 128;
  const int hb = blockIdx.x;
  const int srow = lane >> 2;
  const int sg = lane & 3;
  const int nk = K >> 5;

  auto stage = [&](int b, int k) {
    unsigned short* L = lds + b * 8192;
    int k0 = k * 32;
#pragma unroll
    for (int q = 0; q < 2; ++q) {
      int rb = wid * 32 + q * 16;
      int row = rb + srow;
      int gsrc = sg ^ ((row >> 1) & 3);
      size_t ga = (size_t)(m0 + row) * K + k0 + gsrc * 8;
      size_t gb = (size_t)(n0 + row) * K + k0 + gsrc * 8;
      gload_lds16(Abf + ga, L + rb * 32);
      gload_lds16(Btbf + gb, L + 4096 + rb * 32);
    }
  };

  int offa[4], offb[4];
#pragma unroll
  for (int i = 0; i < 4; ++i) {
    int rowa = wr * 64 + i * 16 + (lane & 15);
    offa[i] = rowa * 32 + (((lane >> 4) ^ ((rowa >> 1) & 3)) * 8);
    int rowb = wc * 64 + i * 16 + (lane & 15);
    offb[i] = rowb * 32 + (((lane >> 4) ^ ((rowb >> 1) & 3)) * 8);
  }

  f32x4 acc[4][4] = {};
  stage(0, 0);
  __syncthreads();

  for (int k = 0; k < nk; ++k) {
    if (k + 1 < nk) stage((k + 1) & 1, k + 1);  // issue next-tile loads FIRST
    unsigned short* L = lds + (k & 1) * 8192;
    bf16x8 ah[4], bh[4];
#pragma unroll
    for (int i = 0; i < 4; ++i) ah[i] = *(const bf16x8*)(L + offa[i]);
#pragma unroll
    for (int j = 0; j < 4; ++j) bh[j] = *(const bf16x8*)(L + 4096 + offb[j]);
#pragma unroll
    for (int j = 0; j < 4; ++j)
#pragma unroll
      for (int i = 0; i < 4; ++i)
        acc[i][j] = __builtin_amdgcn_mfma_f32_16x16x32_bf16(ah[i], bh[j], acc[i][j], 0, 0, 0);
    __syncthreads();  // drains stage(k+1) + all waves done reading buf k
  }

  float as_v[4], ad_v[4];
#pragma unroll
  for (int j = 0; j < 4; ++j) {
    int c = n0 + wc * 64 + j * 16 + (lane & 15);
    as_v[j] = att_s[c];
    ad_v[j] = att_d[c];
  }
#pragma unroll
  for (int i = 0; i < 4; ++i) {
#pragma unroll
    for (int r = 0; r < 4; ++r) {
      float sA = 0.f, sD = 0.f;
#pragma unroll
      for (int j = 0; j < 4; ++j) {
        sA = fmaf(acc[i][j][r], as_v[j], sA);
        sD = fmaf(acc[i][j][r], ad_v[j], sD);
      }
#pragma unroll
      for (int mask = 1; mask <= 8; mask <<= 1) {
        sA += __shfl_xor(sA, mask);
        sD += __shfl_xor(sD, mask);
      }
      if ((lane & 15) == 0) {
        int ml = wr * 64 + i * 16 + (lane >> 4) * 4 + r;
        redS[ml][wc] = sA;
        redD[ml][wc] = sD;
      }
      int m = m0 + wr * 64 + i * 16 + (lane >> 4) * 4 + r;
      if (m < M) {
#pragma unroll
        for (int j = 0; j < 4; ++j) {
          int n = n0 + wc * 64 + j * 16 + (lane & 15);
          Cbf[(size_t)m * 1024 + n] = f2bf_rn(acc[i][j][r]);
        }
      }
    }
  }
  __syncthreads();
  if (t < 128) {
    int m = m0 + t;
    if (m < M) {
      a_s[(size_t)m * 8 + hb] = redS[t][0] + redS[t][1];
      a_d[(size_t)m * 8 + hb] = redD[t][0] + redD[t][1];
    }
  }
}

// ---------------- edge alpha ----------------

__global__ __launch_bounds__(256) void edge_alpha_kernel(
    const int* __restrict__ csr_src, const int* __restrict__ csr_dst,
    const float* __restrict__ ea_csr, const float* __restrict__ loop_attr,
    const float* __restrict__ a_s, const float* __restrict__ a_d,
    const float* __restrict__ Ve,
    float* __restrict__ alpha_csr, float* __restrict__ alpha_self, int E, int n) {
  __shared__ float sVe[EDD][8];
  int t = threadIdx.x;
  sVe[t >> 3][t & 7] = Ve[t];
  __syncthreads();
  int idx = blockIdx.x * 256 + t;
  if (idx >= E + n) return;
  int s, d;
  const float* ea;
  float* outp;
  if (idx < E) {
    s = csr_src[idx]; d = csr_dst[idx];
    ea = ea_csr + (size_t)idx * EDD;
    outp = alpha_csr + (size_t)idx * 8;
  } else {
    s = d = idx - E;
    ea = loop_attr + (size_t)(idx - E) * EDD;
    outp = alpha_self + (size_t)(idx - E) * 8;
  }
  float ae[8] = {0.f, 0.f, 0.f, 0.f, 0.f, 0.f, 0.f, 0.f};
#pragma unroll
  for (int k = 0; k < EDD; k += 4) {
    float4 v = *(const float4*)&ea[k];
#pragma unroll
    for (int h = 0; h < 8; ++h) {
      ae[h] = fmaf(v.x, sVe[k][h], ae[h]);
      ae[h] = fmaf(v.y, sVe[k + 1][h], ae[h]);
      ae[h] = fmaf(v.z, sVe[k + 2][h], ae[h]);
      ae[h] = fmaf(v.w, sVe[k + 3][h], ae[h]);
    }
  }
#pragma unroll
  for (int h = 0; h < 8; ++h) {
    float a = a_s[(size_t)s * 8 + h] + a_d[(size_t)d * 8 + h] + ae[h];
    outp[h] = (a > 0.f) ? a : 0.2f * a;
  }
}

// ---------------- fused softmax + aggregation: block-per-node ----------------

template <int LAYER>
__global__ __launch_bounds__(256) void agg_fused_kernel(
    const unsigned short* __restrict__ xbf, const float* __restrict__ alpha,
    const float* __restrict__ alpha_self, const int* __restrict__ rowptr,
    const int* __restrict__ csr_src, const float* __restrict__ bias,
    unsigned short* __restrict__ obf, float* __restrict__ outp, int N) {
  int n = blockIdx.x;
  int t = threadIdx.x;
  int lane = t & 63, w = t >> 6;
  __shared__ float wm[4][8], wsm[4][8];
  __shared__ float sm_m[8], sm_inv[8];
  __shared__ int ls[64];
  __shared__ float pws[64 * 8];
  __shared__ float red[256][4];
  int r0 = rowptr[n];
  int deg = rowptr[n + 1] - r0;

  {
    int h = t & 7, slot = t >> 3;
    float m = -1e30f, s = 0.f;
    for (int i = slot; i < deg; i += 32) {
      float a = alpha[(size_t)(r0 + i) * 8 + h];
      if (a <= m) {
        s += __expf(a - m);
      } else {
        s = s * __expf(m - a) + 1.f;
        m = a;
      }
    }
#pragma unroll
    for (int mask = 8; mask < 64; mask <<= 1) {
      float mo = __shfl_xor(m, mask);
      float so = __shfl_xor(s, mask);
      float mn = fmaxf(m, mo);
      s = s * __expf(m - mn) + so * __expf(mo - mn);
      m = mn;
    }
    if (lane < 8) { wm[w][lane] = m; wsm[w][lane] = s; }
  }
  __syncthreads();
  if (t < 8) {
    float m = wm[0][t], s = wsm[0][t];
#pragma unroll
    for (int k = 1; k < 4; ++k) {
      float mo = wm[k][t], so = wsm[k][t];
      float mn = fmaxf(m, mo);
      s = s * __expf(m - mn) + so * __expf(mo - mn);
      m = mn;
    }
    float aself = alpha_self[(size_t)n * 8 + t];
    float mn = fmaxf(m, aself);
    s = s * __expf(m - mn) + __expf(aself - mn);
    sm_m[t] = mn;
    sm_inv[t] = 1.f / (s + 1e-16f);
  }
  __syncthreads();

  int h = t >> 5;
  float m_h = sm_m[h], inv_h = sm_inv[h];
  float m_w = sm_m[t & 7], inv_w = sm_inv[t & 7];
  const ushort4* xv = (const ushort4*)xbf;
  float wself = __expf(alpha_self[(size_t)n * 8 + h] - m_h) * inv_h;
  ushort4 sv = xv[(size_t)n * 256 + t];
  float ax = wself * bf2f(sv.x), ay = wself * bf2f(sv.y);
  float az = wself * bf2f(sv.z), aw = wself * bf2f(sv.w);
  for (int base = 0; base < deg; base += 64) {
    int cnt = min(64, deg - base);
    if (t < cnt) ls[t] = csr_src[r0 + base + t];
    for (int idx = t; idx < cnt * 8; idx += 256)
      pws[idx] = __expf(alpha[(size_t)(r0 + base) * 8 + idx] - m_w) * inv_w;
    __syncthreads();
#pragma unroll 4
    for (int j = 0; j < cnt; ++j) {
      float wt = pws[j * 8 + h];
      ushort4 u = xv[(size_t)ls[j] * 256 + t];
      ax = fmaf(wt, bf2f(u.x), ax);
      ay = fmaf(wt, bf2f(u.y), ay);
      az = fmaf(wt, bf2f(u.z), az);
      aw = fmaf(wt, bf2f(u.w), aw);
    }
    __syncthreads();
  }
  if (LAYER == 1) {
    float4 b = ((const float4*)bias)[t];
    ushort4 o4;
    o4.x = f2bf_rn(fmaxf(ax + b.x, 0.f));
    o4.y = f2bf_rn(fmaxf(ay + b.y, 0.f));
    o4.z = f2bf_rn(fmaxf(az + b.z, 0.f));
    o4.w = f2bf_rn(fmaxf(aw + b.w, 0.f));
    ((ushort4*)obf)[(size_t)n * 256 + t] = o4;
  } else {
    red[t][0] = ax; red[t][1] = ay; red[t][2] = az; red[t][3] = aw;
    __syncthreads();
    if (t < 32) {
      float sx = 0.f, sy = 0.f, sz = 0.f, sw = 0.f;
#pragma unroll
      for (int k = 0; k < 8; ++k) {
        sx += red[t + 32 * k][0];
        sy += red[t + 32 * k][1];
        sz += red[t + 32 * k][2];
        sw += red[t + 32 * k][3];
      }
      float4 b = ((const float4*)bias)[t];
      float4 o;
      o.x = sx * 0.125f + b.x;
      o.y = sy * 0.125f + b.y;
      o.z = sz * 0.125f + b.z;
      o.w = sw * 0.125f + b.w;
      ((float4*)outp)[(size_t)n * 32 + t] = o;
    }
  }
}

// ---------------- launch ----------------

extern "C" void kernel_launch(void* const* d_in, const int* in_sizes, int n_in,
                              void* d_out, int out_size, void* d_ws, size_t ws_size,
                              hipStream_t stream) {
  const float* x        = (const float*)d_in[0];
  const int*   ei       = (const int*)d_in[1];
  const float* edge_attr= (const float*)d_in[2];
  const float* W1       = (const float*)d_in[3];
  const float* We1      = (const float*)d_in[4];
  const float* as1      = (const float*)d_in[5];
  const float* ad1      = (const float*)d_in[6];
  const float* ae1      = (const float*)d_in[7];
  const float* b1       = (const float*)d_in[8];
  const float* W2       = (const float*)d_in[9];
  const float* We2      = (const float*)d_in[10];
  const float* as2      = (const float*)d_in[11];
  const float* ad2      = (const float*)d_in[12];
  const float* ae2      = (const float*)d_in[13];
  const float* b2       = (const float*)d_in[14];
  float* out = (float*)d_out;

  const int N = in_sizes[0] / 128;   // 10000 nodes
  const int E = in_sizes[2] / EDD;   // 160000 edges
  const int Mpad = ((N + 127) / 128) * 128;  // 10112

  char* ws = (char*)d_ws;
  size_t off = 0;
  auto alloc = [&](size_t bytes) -> void* {
    void* p = ws + off;
    off = (off + bytes + 255) & ~(size_t)255;
    return p;
  };
  int*   deg       = (int*)alloc((size_t)N * 4);
  int*   rowptr    = (int*)alloc((size_t)(N + 1) * 4);
  int*   cursor    = (int*)alloc((size_t)N * 4);
  int*   csr_src   = (int*)alloc((size_t)E * 4);
  int*   csr_dst   = (int*)alloc((size_t)E * 4);
  int*   csr_eid   = (int*)alloc((size_t)E * 4);
  float* ea_csr    = (float*)alloc((size_t)E * EDD * 4);
  float* loop_attr = (float*)alloc((size_t)N * EDD * 4);
  float* a_s       = (float*)alloc((size_t)N * 8 * 4);
  float* a_d       = (float*)alloc((size_t)N * 8 * 4);
  float* Ve        = (float*)alloc(512 * 4);
  float* alpha_csr = (float*)alloc((size_t)E * 8 * 4);
  float* alpha_self= (float*)alloc((size_t)N * 8 * 4);
  unsigned short* xh1bf = (unsigned short*)alloc((size_t)N * 1024 * 2);
  unsigned short* xh2bf = (unsigned short*)alloc((size_t)N * 1024 * 2);
  unsigned short* xbf   = (unsigned short*)alloc((size_t)Mpad * 128 * 2);
  unsigned short* Bt1   = (unsigned short*)alloc((size_t)1024 * 128 * 2);
  unsigned short* Bt2   = (unsigned short*)alloc((size_t)1024 * 1024 * 2);
  unsigned short* h1bf  = (unsigned short*)alloc((size_t)Mpad * 1024 * 2);
  (void)ws_size; (void)n_in; (void)out_size;

  hipMemsetAsync(deg, 0, (size_t)N * 4, stream);

  int gE = (E + 255) / 256;
  deg_count_kernel<<<gE, 256, 0, stream>>>(ei, deg, E);
  scan_kernel<<<1, 1024, 0, stream>>>(deg, rowptr, cursor, N);
  scatter_kernel<<<gE, 256, 0, stream>>>(ei, cursor, csr_src, csr_dst, csr_eid, E);
  permute_ea_kernel<<<(E * 8 + 255) / 256, 256, 0, stream>>>(csr_eid, edge_attr, ea_csr, E);
  loop_attr_kernel<<<(N + 7) / 8, 256, 0, stream>>>(rowptr, ea_csr, loop_attr, N);

  cvt_bf16_kernel<<<(N * 128 / 4 + 255) / 256, 256, 0, stream>>>(x, xbf, N * 128 / 4);
  transpose_both_kernel<<<dim3(32, 36), 256, 0, stream>>>(W1, Bt1, W2, Bt2);
  ve_both_kernel<<<2, 256, 0, stream>>>(We1, ae1, We2, ae2, Ve);

  dim3 ggrid(8, Mpad / 128);
  int gEA = (E + N + 255) / 256;

  // ---- layer 1 ----
  gemm1_fullk_kernel<<<ggrid, 256, 0, stream>>>(xbf, Bt1, xh1bf, a_s, a_d, as1, ad1, N);
  edge_alpha_kernel<<<gEA, 256, 0, stream>>>(csr_src, csr_dst, ea_csr, loop_attr,
                                             a_s, a_d, Ve, alpha_csr, alpha_self, E, N);
  agg_fused_kernel<1><<<N, 256, 0, stream>>>(xh1bf, alpha_csr, alpha_self, rowptr, csr_src,
                                             b1, h1bf, nullptr, N);

  // ---- layer 2 ----
  gemm2_dbuf_kernel<<<ggrid, 256, 0, stream>>>(h1bf, Bt2, xh2bf, a_s, a_d, as2, ad2, N, 1024);
  edge_alpha_kernel<<<gEA, 256, 0, stream>>>(csr_src, csr_dst, ea_csr, loop_attr,
                                             a_s, a_d, Ve + 256, alpha_csr, alpha_self, E, N);
  agg_fused_kernel<2><<<N, 256, 0, stream>>>(xh2bf, alpha_csr, alpha_self, rowptr, csr_src,
                                             b2, nullptr, out, N);
}